// Round 1
// baseline (3687.185 us; speedup 1.0000x reference)
//
#include <hip/hip_runtime.h>
#include <math.h>

// ---------------------------------------------------------------------------
// Generic tiled fp32 GEMM: C[b] = alpha' * A[b](M,K) x B[b](K,N | N,K if TRANSB) + beta*C[b]
// alpha' = alpha * (gate ? sigmoid(gate[gateIdx]) : 1)
// Tiles: 32(M) x 64(N) x 32(K), 256 threads, 8 outputs/thread (8m x 1n).
// As stored transposed [k][m] (pad 36) so the 8 m-reads vectorize to b128.
// ---------------------------------------------------------------------------
template<bool TRANSB>
__launch_bounds__(256)
__global__ void gemm_kernel(const float* __restrict__ A, const float* __restrict__ B,
                            float* __restrict__ C, int M, int N, int K,
                            long sA, long sB, long sC,
                            float alpha, const float* __restrict__ gate, int gateIdx,
                            float beta)
{
    __shared__ float As[32 * 36];
    __shared__ float Bs[TRANSB ? 64 * 33 : 32 * 65];
    const float* Ab = A + (long)blockIdx.z * sA;
    const float* Bb = B + (long)blockIdx.z * sB;
    float* Cb = C + (long)blockIdx.z * sC;
    int m0 = blockIdx.x * 32;
    int n0 = blockIdx.y * 64;
    int t  = threadIdx.x;
    int n  = t & 63;
    int mb = (t >> 6) * 8;
    float acc[8];
#pragma unroll
    for (int i = 0; i < 8; ++i) acc[i] = 0.f;

    for (int k0 = 0; k0 < K; k0 += 32) {
        for (int i = t; i < 32 * 32; i += 256) {
            int m = i >> 5, kk = i & 31;
            As[kk * 36 + m] = Ab[(long)(m0 + m) * K + k0 + kk];
        }
        if (!TRANSB) {
            for (int i = t; i < 32 * 64; i += 256) {
                int kk = i >> 6, nn = i & 63;
                Bs[kk * 65 + nn] = Bb[(long)(k0 + kk) * N + n0 + nn];
            }
        } else {
            for (int i = t; i < 64 * 32; i += 256) {
                int nn = i >> 5, kk = i & 31;
                Bs[nn * 33 + kk] = Bb[(long)(n0 + nn) * K + k0 + kk];
            }
        }
        __syncthreads();
#pragma unroll 8
        for (int kk = 0; kk < 32; ++kk) {
            float bv = TRANSB ? Bs[n * 33 + kk] : Bs[kk * 65 + n];
            const float* ap = &As[kk * 36 + mb];
#pragma unroll
            for (int i = 0; i < 8; ++i) acc[i] += ap[i] * bv;
        }
        __syncthreads();
    }
    float a = alpha;
    if (gate) a *= 1.f / (1.f + expf(-gate[gateIdx]));
#pragma unroll
    for (int i = 0; i < 8; ++i) {
        long off = (long)(m0 + mb + i) * N + n0 + n;
        float v = a * acc[i];
        if (beta != 0.f) v += Cb[off];
        Cb[off] = v;
    }
}

// ---------------------------------------------------------------------------
// Exact top-16 per row (one wave per row), tie-break = lower index (jax.lax.top_k).
// Produces edge coefficients c = sign(v)*softmax(|v|)*softplus(state) and indices.
// CNT = Nd/64 candidates held in registers per lane.
// ---------------------------------------------------------------------------
template<int CNT>
__launch_bounds__(64)
__global__ void topk_coeff_kernel(const float* __restrict__ logits,
                                  const float* __restrict__ state,
                                  int* __restrict__ idx_out, float* __restrict__ c_out,
                                  int Nd)
{
    long row = blockIdx.x;
    int lane = threadIdx.x;
    const float* L = logits + row * Nd;
    float vreg[CNT];
#pragma unroll
    for (int tt = 0; tt < CNT; ++tt) vreg[tt] = L[lane + (tt << 6)];

    float m = 0.f, sum = 0.f;          // online softmax over |v|; |v| >= 0 so m=0 init ok
    float myv = 0.f; int myi = 0;
#pragma unroll
    for (int it = 0; it < 16; ++it) {
        float best = -INFINITY; int bidx = 0x7fffffff;
#pragma unroll
        for (int tt = 0; tt < CNT; ++tt) {
            if (vreg[tt] > best) { best = vreg[tt]; bidx = lane + (tt << 6); }
        }
#pragma unroll
        for (int off = 32; off; off >>= 1) {
            float ov = __shfl_down(best, off);
            int   oi = __shfl_down(bidx, off);
            if (ov > best || (ov == best && oi < bidx)) { best = ov; bidx = oi; }
        }
        best = __shfl(best, 0);
        bidx = __shfl(bidx, 0);
        if (it == lane) { myv = best; myi = bidx; }
        float ab = fabsf(best);
        float nm = fmaxf(m, ab);
        sum = sum * expf(m - nm) + expf(ab - nm);
        m = nm;
#pragma unroll
        for (int tt = 0; tt < CNT; ++tt)
            if (lane + (tt << 6) == bidx) vreg[tt] = -INFINITY;
    }
    if (lane < 16) {
        float st = state[row];
        float sp = fmaxf(st, 0.f) + log1pf(expf(-fabsf(st)));   // softplus, stable
        float sgn = (myv > 0.f) ? 1.f : ((myv < 0.f) ? -1.f : 0.f);
        float w = expf(fabsf(myv) - m) / sum;
        c_out[row * 16 + lane] = sgn * w * sp;
        idx_out[row * 16 + lane] = myi;
    }
}

// ---------------------------------------------------------------------------
// Scatter-add edges: one block per edge, 512-elem value row via atomics.
// ---------------------------------------------------------------------------
__launch_bounds__(256)
__global__ void scatter_kernel(const int* __restrict__ idx, const float* __restrict__ c,
                               const float* __restrict__ src_val,
                               float* __restrict__ ds, float* __restrict__ dv,
                               int Ns, int Nd)
{
    int e = blockIdx.x;
    int b = e / (Ns * 16);
    int s = (e - b * Ns * 16) >> 4;
    int target = idx[e];
    float cv = c[e];
    const float* src = src_val + ((long)(b * Ns + s) << 9);
    float* dst = dv + ((long)(b * Nd + target) << 9);
    int t = threadIdx.x;
    atomicAdd(&dst[t],       cv * src[t]);
    atomicAdd(&dst[t + 256], cv * src[t + 256]);
    if (t == 0) atomicAdd(&ds[b * Nd + target], cv);
}

// ---------------------------------------------------------------------------
// state' = sign(x)*softmax(|x|) over slot axis, x = s + gate*ds. One block per batch.
// ---------------------------------------------------------------------------
__launch_bounds__(256)
__global__ void apply_state_kernel(const float* __restrict__ s_in, const float* __restrict__ ds,
                                   float* __restrict__ s_out, int Nd,
                                   const float* __restrict__ gatePtr, int gateIdx)
{
    __shared__ float sh[1024];
    __shared__ float red[4];
    int b = blockIdx.x, t = threadIdx.x;
    float gate = 1.f;
    if (gatePtr) gate = 1.f / (1.f + expf(-gatePtr[gateIdx]));
    float lmax = 0.f;
    for (int i = t; i < Nd; i += 256) {
        float x = s_in[b * Nd + i] + gate * ds[b * Nd + i];
        sh[i] = x;
        lmax = fmaxf(lmax, fabsf(x));
    }
    for (int off = 32; off; off >>= 1) lmax = fmaxf(lmax, __shfl_down(lmax, off));
    if ((t & 63) == 0) red[t >> 6] = lmax;
    __syncthreads();
    float bmax = fmaxf(fmaxf(red[0], red[1]), fmaxf(red[2], red[3]));
    float lsum = 0.f;
    for (int i = t; i < Nd; i += 256) lsum += expf(fabsf(sh[i]) - bmax);
    for (int off = 32; off; off >>= 1) lsum += __shfl_down(lsum, off);
    __syncthreads();
    if ((t & 63) == 0) red[t >> 6] = lsum;
    __syncthreads();
    float inv = 1.f / (red[0] + red[1] + red[2] + red[3]);
    for (int i = t; i < Nd; i += 256) {
        float x = sh[i];
        float sgn = (x > 0.f) ? 1.f : ((x < 0.f) ? -1.f : 0.f);
        s_out[b * Nd + i] = sgn * expf(fabsf(x) - bmax) * inv;
    }
}

// ---------------------------------------------------------------------------
// val' = LayerNorm(v + gate*dv) * gamma + beta. One block (256 thr) per row of 512.
// ---------------------------------------------------------------------------
__launch_bounds__(256)
__global__ void apply_ln_kernel(const float* __restrict__ v_in, const float* __restrict__ dv,
                                float* __restrict__ v_out, const float* __restrict__ gamma,
                                const float* __restrict__ beta,
                                const float* __restrict__ gatePtr, int gateIdx)
{
    __shared__ float red[4];
    long row = blockIdx.x;
    int t = threadIdx.x;
    float gate = 1.f;
    if (gatePtr) gate = 1.f / (1.f + expf(-gatePtr[gateIdx]));
    const float* vi  = v_in + (row << 9);
    const float* dvi = dv   + (row << 9);
    float x0 = vi[t]       + gate * dvi[t];
    float x1 = vi[t + 256] + gate * dvi[t + 256];
    float s = x0 + x1;
    for (int off = 32; off; off >>= 1) s += __shfl_down(s, off);
    if ((t & 63) == 0) red[t >> 6] = s;
    __syncthreads();
    float mean = (red[0] + red[1] + red[2] + red[3]) * (1.f / 512.f);
    float d0 = x0 - mean, d1 = x1 - mean;
    float ss = d0 * d0 + d1 * d1;
    for (int off = 32; off; off >>= 1) ss += __shfl_down(ss, off);
    __syncthreads();
    if ((t & 63) == 0) red[t >> 6] = ss;
    __syncthreads();
    float var = (red[0] + red[1] + red[2] + red[3]) * (1.f / 512.f);
    float rstd = rsqrtf(var + 1e-5f);
    float* vo = v_out + (row << 9);
    vo[t]       = d0 * rstd * gamma[t]       + beta[t];
    vo[t + 256] = d1 * rstd * gamma[t + 256] + beta[t + 256];
}

// ---------------------------------------------------------------------------
// Plain softmax over rows (read attention), in place.
// ---------------------------------------------------------------------------
__launch_bounds__(256)
__global__ void softmax_rows_kernel(float* __restrict__ logits, int Nd)
{
    __shared__ float red[4];
    long row = blockIdx.x;
    int t = threadIdx.x;
    float* L = logits + row * (long)Nd;
    float lmax = -INFINITY;
    for (int i = t; i < Nd; i += 256) lmax = fmaxf(lmax, L[i]);
    for (int off = 32; off; off >>= 1) lmax = fmaxf(lmax, __shfl_down(lmax, off));
    if ((t & 63) == 0) red[t >> 6] = lmax;
    __syncthreads();
    float bmax = fmaxf(fmaxf(red[0], red[1]), fmaxf(red[2], red[3]));
    float lsum = 0.f;
    for (int i = t; i < Nd; i += 256) lsum += expf(L[i] - bmax);
    for (int off = 32; off; off >>= 1) lsum += __shfl_down(lsum, off);
    __syncthreads();
    if ((t & 63) == 0) red[t >> 6] = lsum;
    __syncthreads();
    float inv = 1.f / (red[0] + red[1] + red[2] + red[3]);
    for (int i = t; i < Nd; i += 256) L[i] = expf(L[i] - bmax) * inv;
}

// ---------------------------------------------------------------------------
extern "C" void kernel_launch(void* const* d_in, const int* in_sizes, int n_in,
                              void* d_out, int out_size, void* d_ws, size_t ws_size,
                              hipStream_t stream)
{
    const int Bn = 4, T = 1024, D = 512, R = 64;
    const int S0 = 1024, S1 = 256, S2 = 64;
    const long RT = (long)D * R;    // one [D,R] route slice

    const float* tok_val    = (const float*)d_in[0];
    const float* tok_state  = (const float*)d_in[1];
    const float* mem_state0 = (const float*)d_in[2];
    const float* mem_val0   = (const float*)d_in[3];
    const float* mem_state1 = (const float*)d_in[4];
    const float* mem_val1   = (const float*)d_in[5];
    const float* mem_state2 = (const float*)d_in[6];
    const float* mem_val2   = (const float*)d_in[7];
    const float* write_route= (const float*)d_in[8];
    const float* prop_route = (const float*)d_in[9];
    const float* level_route= (const float*)d_in[10];
    const float* skip_route = (const float*)d_in[11];
    const float* skip_gates = (const float*)d_in[12];
    const float* ln_gamma   = (const float*)d_in[13];
    const float* ln_beta    = (const float*)d_in[14];
    const float* read_route = (const float*)d_in[15];
    const float* read_proj  = (const float*)d_in[16];
    const float* read_gates = (const float*)d_in[17];
    float* out = (float*)d_out;

    // workspace carve (~47 MB of fp32)
    float* p = (float*)d_ws;
    float* v0 = p;  p += (long)Bn * S0 * D;
    float* s0 = p;  p += Bn * S0;
    float* v1 = p;  p += (long)Bn * S1 * D;
    float* s1 = p;  p += Bn * S1;
    float* v2 = p;  p += (long)Bn * S2 * D;
    float* s2 = p;  p += Bn * S2;
    float* qb = p;  p += (long)Bn * T * R;
    float* kb = p;  p += (long)Bn * S0 * R;
    float* lb = p;  p += (long)Bn * T * S0;
    float* cb = p;  p += (long)Bn * T * 16;
    int*   ib = (int*)p; p += (long)Bn * T * 16;
    float* dsb = p; p += Bn * S0;
    float* dvb = p; p += (long)Bn * S0 * D;
    float* rb = p;  p += (long)Bn * T * D;

    auto trans = [&](const float* sv, const float* ss, const float* dval,
                     const float* W, int Ns, int Nd) {
        gemm_kernel<false><<<dim3(Ns / 32, R / 64, Bn), 256, 0, stream>>>(
            sv, W, qb, Ns, R, D, (long)Ns * D, 0, (long)Ns * R, 1.f, nullptr, 0, 0.f);
        gemm_kernel<false><<<dim3(Nd / 32, R / 64, Bn), 256, 0, stream>>>(
            dval, W + RT, kb, Nd, R, D, (long)Nd * D, 0, (long)Nd * R, 1.f, nullptr, 0, 0.f);
        gemm_kernel<true><<<dim3(Ns / 32, Nd / 64, Bn), 256, 0, stream>>>(
            qb, kb, lb, Ns, Nd, R, (long)Ns * R, (long)Nd * R, (long)Ns * Nd,
            0.125f, nullptr, 0, 0.f);
        if (Nd == 1024)
            topk_coeff_kernel<16><<<Bn * Ns, 64, 0, stream>>>(lb, ss, ib, cb, Nd);
        else if (Nd == 256)
            topk_coeff_kernel<4><<<Bn * Ns, 64, 0, stream>>>(lb, ss, ib, cb, Nd);
        else
            topk_coeff_kernel<1><<<Bn * Ns, 64, 0, stream>>>(lb, ss, ib, cb, Nd);
        hipMemsetAsync(dsb, 0, (size_t)Bn * Nd * sizeof(float), stream);
        hipMemsetAsync(dvb, 0, (size_t)Bn * Nd * D * sizeof(float), stream);
        scatter_kernel<<<Bn * Ns * 16, 256, 0, stream>>>(ib, cb, sv, dsb, dvb, Ns, Nd);
    };
    auto apply = [&](const float* sin, float* sout, const float* vin, float* vout,
                     int Nd, int lvl, const float* gptr, int gidx) {
        apply_state_kernel<<<Bn, 256, 0, stream>>>(sin, dsb, sout, Nd, gptr, gidx);
        apply_ln_kernel<<<Bn * Nd, 256, 0, stream>>>(vin, dvb, vout,
            ln_gamma + lvl * D, ln_beta + lvl * D, gptr, gidx);
    };

    // ---- level 0: token write + propagation ----
    trans(tok_val, tok_state, mem_val0, write_route, T, S0);
    apply(mem_state0, s0, mem_val0, v0, S0, 0, nullptr, 0);
    trans(v0, s0, v0, prop_route + 0 * 2 * RT, S0, S0);
    apply(s0, s0, v0, v0, S0, 0, nullptr, 0);

    // ---- level 1: transition, gated token skip, propagation ----
    trans(v0, s0, mem_val1, level_route + 0 * 2 * RT, S0, S1);
    apply(mem_state1, s1, mem_val1, v1, S1, 1, nullptr, 0);
    trans(tok_val, tok_state, v1, skip_route + 0 * 2 * RT, T, S1);
    apply(s1, s1, v1, v1, S1, 1, skip_gates, 0);
    trans(v1, s1, v1, prop_route + 1 * 2 * RT, S1, S1);
    apply(s1, s1, v1, v1, S1, 1, nullptr, 0);

    // ---- level 2: transition, gated level-0 skip, propagation ----
    trans(v1, s1, mem_val2, level_route + 1 * 2 * RT, S1, S2);
    apply(mem_state2, s2, mem_val2, v2, S2, 2, nullptr, 0);
    trans(v0, s0, v2, skip_route + 1 * 2 * RT, S0, S2);
    apply(s2, s2, v2, v2, S2, 2, skip_gates, 1);
    trans(v2, s2, v2, prop_route + 2 * 2 * RT, S2, S2);
    apply(s2, s2, v2, v2, S2, 2, nullptr, 0);

    // ---- read phase ----
    hipMemcpyAsync(out, tok_val, (size_t)Bn * T * D * sizeof(float),
                   hipMemcpyDeviceToDevice, stream);
    const float* mvs[3] = { v0, v1, v2 };
    const int nds[3] = { S0, S1, S2 };
    for (int l = 0; l < 3; ++l) {
        const float* mv = mvs[l];
        int Nd = nds[l];
        gemm_kernel<false><<<dim3(T / 32, 1, Bn), 256, 0, stream>>>(
            tok_val, read_route + (long)l * 2 * RT, qb, T, R, D,
            (long)T * D, 0, (long)T * R, 1.f, nullptr, 0, 0.f);
        gemm_kernel<false><<<dim3(Nd / 32, 1, Bn), 256, 0, stream>>>(
            mv, read_route + (long)l * 2 * RT + RT, kb, Nd, R, D,
            (long)Nd * D, 0, (long)Nd * R, 1.f, nullptr, 0, 0.f);
        gemm_kernel<true><<<dim3(T / 32, Nd / 64, Bn), 256, 0, stream>>>(
            qb, kb, lb, T, Nd, R, (long)T * R, (long)Nd * R, (long)T * Nd,
            0.125f, nullptr, 0, 0.f);
        softmax_rows_kernel<<<Bn * T, 256, 0, stream>>>(lb, Nd);
        gemm_kernel<false><<<dim3(T / 32, D / 64, Bn), 256, 0, stream>>>(
            lb, mv, rb, T, D, Nd, (long)T * Nd, (long)Nd * D, (long)T * D,
            1.f, nullptr, 0, 0.f);
        gemm_kernel<false><<<dim3(T / 32, D / 64, Bn), 256, 0, stream>>>(
            rb, read_proj + (long)l * D * D, out, T, D, D,
            (long)T * D, 0, (long)T * D, 1.f, read_gates, l, 1.f);
    }
}

// Round 2
// 3557.026 us; speedup vs baseline: 1.0366x; 1.0366x over previous
//
#include <hip/hip_runtime.h>
#include <math.h>

// ---------------------------------------------------------------------------
// Generic tiled fp32 GEMM: C[b] = alpha' * A[b](M,K) x B[b](K,N | N,K if TRANSB) + beta*C[b]
// alpha' = alpha * (gate ? sigmoid(gate[gateIdx]) : 1)
// Tiles: 32(M) x 64(N) x 32(K), 256 threads, 8 outputs/thread (8m x 1n).
// ---------------------------------------------------------------------------
template<bool TRANSB>
__launch_bounds__(256)
__global__ void gemm_kernel(const float* __restrict__ A, const float* __restrict__ B,
                            float* __restrict__ C, int M, int N, int K,
                            long sA, long sB, long sC,
                            float alpha, const float* __restrict__ gate, int gateIdx,
                            float beta)
{
    __shared__ float As[32 * 36];
    __shared__ float Bs[TRANSB ? 64 * 33 : 32 * 65];
    const float* Ab = A + (long)blockIdx.z * sA;
    const float* Bb = B + (long)blockIdx.z * sB;
    float* Cb = C + (long)blockIdx.z * sC;
    int m0 = blockIdx.x * 32;
    int n0 = blockIdx.y * 64;
    int t  = threadIdx.x;
    int n  = t & 63;
    int mb = (t >> 6) * 8;
    float acc[8];
#pragma unroll
    for (int i = 0; i < 8; ++i) acc[i] = 0.f;

    for (int k0 = 0; k0 < K; k0 += 32) {
        for (int i = t; i < 32 * 32; i += 256) {
            int m = i >> 5, kk = i & 31;
            As[kk * 36 + m] = Ab[(long)(m0 + m) * K + k0 + kk];
        }
        if (!TRANSB) {
            for (int i = t; i < 32 * 64; i += 256) {
                int kk = i >> 6, nn = i & 63;
                Bs[kk * 65 + nn] = Bb[(long)(k0 + kk) * N + n0 + nn];
            }
        } else {
            for (int i = t; i < 64 * 32; i += 256) {
                int nn = i >> 5, kk = i & 31;
                Bs[nn * 33 + kk] = Bb[(long)(n0 + nn) * K + k0 + kk];
            }
        }
        __syncthreads();
#pragma unroll 8
        for (int kk = 0; kk < 32; ++kk) {
            float bv = TRANSB ? Bs[n * 33 + kk] : Bs[kk * 65 + n];
            const float* ap = &As[kk * 36 + mb];
#pragma unroll
            for (int i = 0; i < 8; ++i) acc[i] += ap[i] * bv;
        }
        __syncthreads();
    }
    float a = alpha;
    if (gate) a *= 1.f / (1.f + expf(-gate[gateIdx]));
#pragma unroll
    for (int i = 0; i < 8; ++i) {
        long off = (long)(m0 + mb + i) * N + n0 + n;
        float v = a * acc[i];
        if (beta != 0.f) v += Cb[off];
        Cb[off] = v;
    }
}

// ---------------------------------------------------------------------------
// Exact top-16 per row (one wave per row), tie-break = lower index (jax.lax.top_k).
// Produces edge coefficients c = sign(v)*softmax(|v|)*softplus(state) and indices.
// ---------------------------------------------------------------------------
template<int CNT>
__launch_bounds__(64)
__global__ void topk_coeff_kernel(const float* __restrict__ logits,
                                  const float* __restrict__ state,
                                  int* __restrict__ idx_out, float* __restrict__ c_out,
                                  int Nd)
{
    long row = blockIdx.x;
    int lane = threadIdx.x;
    const float* L = logits + row * Nd;
    float vreg[CNT];
#pragma unroll
    for (int tt = 0; tt < CNT; ++tt) vreg[tt] = L[lane + (tt << 6)];

    float m = 0.f, sum = 0.f;
    float myv = 0.f; int myi = 0;
#pragma unroll
    for (int it = 0; it < 16; ++it) {
        float best = -INFINITY; int bidx = 0x7fffffff;
#pragma unroll
        for (int tt = 0; tt < CNT; ++tt) {
            if (vreg[tt] > best) { best = vreg[tt]; bidx = lane + (tt << 6); }
        }
#pragma unroll
        for (int off = 32; off; off >>= 1) {
            float ov = __shfl_down(best, off);
            int   oi = __shfl_down(bidx, off);
            if (ov > best || (ov == best && oi < bidx)) { best = ov; bidx = oi; }
        }
        best = __shfl(best, 0);
        bidx = __shfl(bidx, 0);
        if (it == lane) { myv = best; myi = bidx; }
        float ab = fabsf(best);
        float nm = fmaxf(m, ab);
        sum = sum * expf(m - nm) + expf(ab - nm);
        m = nm;
#pragma unroll
        for (int tt = 0; tt < CNT; ++tt)
            if (lane + (tt << 6) == bidx) vreg[tt] = -INFINITY;
    }
    if (lane < 16) {
        float st = state[row];
        float sp = fmaxf(st, 0.f) + log1pf(expf(-fabsf(st)));
        float sgn = (myv > 0.f) ? 1.f : ((myv < 0.f) ? -1.f : 0.f);
        float w = expf(fabsf(myv) - m) / sum;
        c_out[row * 16 + lane] = sgn * w * sp;
        idx_out[row * 16 + lane] = myi;
    }
}

// ---------------------------------------------------------------------------
// CSR build: count edges per destination, scan, fill edge lists.
// Edge id e in [0, B*Ns*16); b = e >> nsShift (nsShift = log2(Ns)+4).
// ---------------------------------------------------------------------------
__launch_bounds__(256)
__global__ void count_edges_kernel(const int* __restrict__ idx, int* __restrict__ cnt,
                                   int nsShift, int Nd, int E)
{
    int e = blockIdx.x * 256 + threadIdx.x;
    if (e >= E) return;
    int b = e >> nsShift;
    atomicAdd(&cnt[b * Nd + idx[e]], 1);
}

// Single-block exclusive scan over N entries (N multiple of 256, N <= 4096).
__launch_bounds__(256)
__global__ void scan_kernel(const int* __restrict__ cnt, int* __restrict__ offs, int N)
{
    __shared__ int sums[256];
    int t = threadIdx.x;
    int chunk = N >> 8;
    int base = t * chunk;
    int s = 0;
    for (int i = 0; i < chunk; ++i) s += cnt[base + i];
    sums[t] = s;
    __syncthreads();
    for (int off = 1; off < 256; off <<= 1) {
        int v = (t >= off) ? sums[t - off] : 0;
        __syncthreads();
        sums[t] += v;
        __syncthreads();
    }
    int run = sums[t] - s;          // exclusive prefix of this thread's chunk
    for (int i = 0; i < chunk; ++i) {
        offs[base + i] = run;
        run += cnt[base + i];
    }
    if (t == 255) offs[N] = run;
}

__launch_bounds__(256)
__global__ void fill_edges_kernel(const int* __restrict__ idx, const int* __restrict__ offs,
                                  int* __restrict__ cursor, int* __restrict__ elist,
                                  int nsShift, int Nd, int E)
{
    int e = blockIdx.x * 256 + threadIdx.x;
    if (e >= E) return;
    int b = e >> nsShift;
    int d = b * Nd + idx[e];
    int pos = offs[d] + atomicAdd(&cursor[d], 1);
    elist[pos] = e;
}

// ---------------------------------------------------------------------------
// Gather delta-values per destination row: dv[row] = sum_e c[e]*src[src_row(e)].
// One block (256 thr) per destination row of 512. Plain loads, one clean write.
// ---------------------------------------------------------------------------
__launch_bounds__(256)
__global__ void gather_dv_kernel(const float* __restrict__ src_val, const float* __restrict__ c,
                                 const int* __restrict__ elist, const int* __restrict__ offs,
                                 float* __restrict__ dv, int nsShift)
{
    long row = blockIdx.x;
    int t = threadIdx.x;
    int e0 = offs[row], e1 = offs[row + 1];
    float a0 = 0.f, a1 = 0.f;
    int mask = (1 << nsShift) - 1;
    for (int ei = e0; ei < e1; ++ei) {
        int e = elist[ei];
        float cv = c[e];
        int b = e >> nsShift;
        int s = (e & mask) >> 4;
        const float* src = src_val + ((long)((b << (nsShift - 4)) + s) << 9);
        a0 += cv * src[t];
        a1 += cv * src[t + 256];
    }
    dv[(row << 9) + t]       = a0;
    dv[(row << 9) + t + 256] = a1;
}

// ---------------------------------------------------------------------------
// state' = sign(x)*softmax(|x|) over slot axis, x = s + gate*ds, ds gathered
// from the CSR edge lists. One block per batch.
// ---------------------------------------------------------------------------
__launch_bounds__(256)
__global__ void apply_state_kernel(const float* __restrict__ s_in,
                                   const float* __restrict__ c,
                                   const int* __restrict__ elist, const int* __restrict__ offs,
                                   float* __restrict__ s_out, int Nd,
                                   const float* __restrict__ gatePtr, int gateIdx)
{
    __shared__ float sh[1024];
    __shared__ float red[4];
    int b = blockIdx.x, t = threadIdx.x;
    float gate = 1.f;
    if (gatePtr) gate = 1.f / (1.f + expf(-gatePtr[gateIdx]));
    float lmax = 0.f;
    for (int i = t; i < Nd; i += 256) {
        int d = b * Nd + i;
        float ds = 0.f;
        for (int ei = offs[d]; ei < offs[d + 1]; ++ei) ds += c[elist[ei]];
        float x = s_in[d] + gate * ds;
        sh[i] = x;
        lmax = fmaxf(lmax, fabsf(x));
    }
    for (int off = 32; off; off >>= 1) lmax = fmaxf(lmax, __shfl_down(lmax, off));
    if ((t & 63) == 0) red[t >> 6] = lmax;
    __syncthreads();
    float bmax = fmaxf(fmaxf(red[0], red[1]), fmaxf(red[2], red[3]));
    float lsum = 0.f;
    for (int i = t; i < Nd; i += 256) lsum += expf(fabsf(sh[i]) - bmax);
    for (int off = 32; off; off >>= 1) lsum += __shfl_down(lsum, off);
    __syncthreads();
    if ((t & 63) == 0) red[t >> 6] = lsum;
    __syncthreads();
    float inv = 1.f / (red[0] + red[1] + red[2] + red[3]);
    for (int i = t; i < Nd; i += 256) {
        float x = sh[i];
        float sgn = (x > 0.f) ? 1.f : ((x < 0.f) ? -1.f : 0.f);
        s_out[b * Nd + i] = sgn * expf(fabsf(x) - bmax) * inv;
    }
}

// ---------------------------------------------------------------------------
// val' = LayerNorm(v + gate*dv) * gamma + beta. One block (256 thr) per row of 512.
// ---------------------------------------------------------------------------
__launch_bounds__(256)
__global__ void apply_ln_kernel(const float* __restrict__ v_in, const float* __restrict__ dv,
                                float* __restrict__ v_out, const float* __restrict__ gamma,
                                const float* __restrict__ beta,
                                const float* __restrict__ gatePtr, int gateIdx)
{
    __shared__ float red[4];
    long row = blockIdx.x;
    int t = threadIdx.x;
    float gate = 1.f;
    if (gatePtr) gate = 1.f / (1.f + expf(-gatePtr[gateIdx]));
    const float* vi  = v_in + (row << 9);
    const float* dvi = dv   + (row << 9);
    float x0 = vi[t]       + gate * dvi[t];
    float x1 = vi[t + 256] + gate * dvi[t + 256];
    float s = x0 + x1;
    for (int off = 32; off; off >>= 1) s += __shfl_down(s, off);
    if ((t & 63) == 0) red[t >> 6] = s;
    __syncthreads();
    float mean = (red[0] + red[1] + red[2] + red[3]) * (1.f / 512.f);
    float d0 = x0 - mean, d1 = x1 - mean;
    float ss = d0 * d0 + d1 * d1;
    for (int off = 32; off; off >>= 1) ss += __shfl_down(ss, off);
    __syncthreads();
    if ((t & 63) == 0) red[t >> 6] = ss;
    __syncthreads();
    float var = (red[0] + red[1] + red[2] + red[3]) * (1.f / 512.f);
    float rstd = rsqrtf(var + 1e-5f);
    float* vo = v_out + (row << 9);
    vo[t]       = d0 * rstd * gamma[t]       + beta[t];
    vo[t + 256] = d1 * rstd * gamma[t + 256] + beta[t + 256];
}

// ---------------------------------------------------------------------------
// Plain softmax over rows (read attention), in place.
// ---------------------------------------------------------------------------
__launch_bounds__(256)
__global__ void softmax_rows_kernel(float* __restrict__ logits, int Nd)
{
    __shared__ float red[4];
    long row = blockIdx.x;
    int t = threadIdx.x;
    float* L = logits + row * (long)Nd;
    float lmax = -INFINITY;
    for (int i = t; i < Nd; i += 256) lmax = fmaxf(lmax, L[i]);
    for (int off = 32; off; off >>= 1) lmax = fmaxf(lmax, __shfl_down(lmax, off));
    if ((t & 63) == 0) red[t >> 6] = lmax;
    __syncthreads();
    float bmax = fmaxf(fmaxf(red[0], red[1]), fmaxf(red[2], red[3]));
    float lsum = 0.f;
    for (int i = t; i < Nd; i += 256) lsum += expf(L[i] - bmax);
    for (int off = 32; off; off >>= 1) lsum += __shfl_down(lsum, off);
    __syncthreads();
    if ((t & 63) == 0) red[t >> 6] = lsum;
    __syncthreads();
    float inv = 1.f / (red[0] + red[1] + red[2] + red[3]);
    for (int i = t; i < Nd; i += 256) L[i] = expf(L[i] - bmax) * inv;
}

// ---------------------------------------------------------------------------
extern "C" void kernel_launch(void* const* d_in, const int* in_sizes, int n_in,
                              void* d_out, int out_size, void* d_ws, size_t ws_size,
                              hipStream_t stream)
{
    const int Bn = 4, T = 1024, D = 512, R = 64;
    const int S0 = 1024, S1 = 256, S2 = 64;
    const long RT = (long)D * R;

    const float* tok_val    = (const float*)d_in[0];
    const float* tok_state  = (const float*)d_in[1];
    const float* mem_state0 = (const float*)d_in[2];
    const float* mem_val0   = (const float*)d_in[3];
    const float* mem_state1 = (const float*)d_in[4];
    const float* mem_val1   = (const float*)d_in[5];
    const float* mem_state2 = (const float*)d_in[6];
    const float* mem_val2   = (const float*)d_in[7];
    const float* write_route= (const float*)d_in[8];
    const float* prop_route = (const float*)d_in[9];
    const float* level_route= (const float*)d_in[10];
    const float* skip_route = (const float*)d_in[11];
    const float* skip_gates = (const float*)d_in[12];
    const float* ln_gamma   = (const float*)d_in[13];
    const float* ln_beta    = (const float*)d_in[14];
    const float* read_route = (const float*)d_in[15];
    const float* read_proj  = (const float*)d_in[16];
    const float* read_gates = (const float*)d_in[17];
    float* out = (float*)d_out;

    // workspace carve
    float* p = (float*)d_ws;
    float* v0 = p;  p += (long)Bn * S0 * D;
    float* s0 = p;  p += Bn * S0;
    float* v1 = p;  p += (long)Bn * S1 * D;
    float* s1 = p;  p += Bn * S1;
    float* v2 = p;  p += (long)Bn * S2 * D;
    float* s2 = p;  p += Bn * S2;
    float* qb = p;  p += (long)Bn * T * R;
    float* kb = p;  p += (long)Bn * S0 * R;
    float* lb = p;  p += (long)Bn * T * S0;
    float* cb = p;  p += (long)Bn * T * 16;
    int*   ib = (int*)p; p += (long)Bn * T * 16;
    float* dvb = p; p += (long)Bn * S0 * D;
    float* rb = p;  p += (long)Bn * T * D;
    int* cntb  = (int*)p; p += Bn * S0;        // counts  [B*Nd]
    int* curb  = (int*)p; p += Bn * S0;        // cursors [B*Nd] (contiguous after cnt)
    int* offsb = (int*)p; p += Bn * S0 + 1;    // offsets [B*Nd + 1]
    int* elistb= (int*)p; p += (long)Bn * T * 16;

    auto trans = [&](const float* sv, const float* ss, const float* dval,
                     const float* W, int Ns, int Nd) {
        gemm_kernel<false><<<dim3(Ns / 32, R / 64, Bn), 256, 0, stream>>>(
            sv, W, qb, Ns, R, D, (long)Ns * D, 0, (long)Ns * R, 1.f, nullptr, 0, 0.f);
        gemm_kernel<false><<<dim3(Nd / 32, R / 64, Bn), 256, 0, stream>>>(
            dval, W + RT, kb, Nd, R, D, (long)Nd * D, 0, (long)Nd * R, 1.f, nullptr, 0, 0.f);
        gemm_kernel<true><<<dim3(Ns / 32, Nd / 64, Bn), 256, 0, stream>>>(
            qb, kb, lb, Ns, Nd, R, (long)Ns * R, (long)Nd * R, (long)Ns * Nd,
            0.125f, nullptr, 0, 0.f);
        if (Nd == 1024)
            topk_coeff_kernel<16><<<Bn * Ns, 64, 0, stream>>>(lb, ss, ib, cb, Nd);
        else if (Nd == 256)
            topk_coeff_kernel<4><<<Bn * Ns, 64, 0, stream>>>(lb, ss, ib, cb, Nd);
        else
            topk_coeff_kernel<1><<<Bn * Ns, 64, 0, stream>>>(lb, ss, ib, cb, Nd);
        // CSR build + gather (replaces atomic scatter)
        int E = Bn * Ns * 16;
        int nsShift = 31 - __builtin_clz((unsigned)Ns) + 4;   // log2(Ns)+4
        hipMemsetAsync(cntb, 0, (size_t)2 * Bn * S0 * sizeof(int), stream); // cnt+cursor
        count_edges_kernel<<<(E + 255) / 256, 256, 0, stream>>>(ib, cntb, nsShift, Nd, E);
        scan_kernel<<<1, 256, 0, stream>>>(cntb, offsb, Bn * Nd);
        fill_edges_kernel<<<(E + 255) / 256, 256, 0, stream>>>(ib, offsb, curb, elistb,
                                                               nsShift, Nd, E);
        gather_dv_kernel<<<Bn * Nd, 256, 0, stream>>>(sv, cb, elistb, offsb, dvb, nsShift);
    };
    auto apply = [&](const float* sin, float* sout, const float* vin, float* vout,
                     int Nd, int lvl, const float* gptr, int gidx) {
        apply_state_kernel<<<Bn, 256, 0, stream>>>(sin, cb, elistb, offsb, sout, Nd,
                                                   gptr, gidx);
        apply_ln_kernel<<<Bn * Nd, 256, 0, stream>>>(vin, dvb, vout,
            ln_gamma + lvl * D, ln_beta + lvl * D, gptr, gidx);
    };

    // ---- level 0: token write + propagation ----
    trans(tok_val, tok_state, mem_val0, write_route, T, S0);
    apply(mem_state0, s0, mem_val0, v0, S0, 0, nullptr, 0);
    trans(v0, s0, v0, prop_route + 0 * 2 * RT, S0, S0);
    apply(s0, s0, v0, v0, S0, 0, nullptr, 0);

    // ---- level 1: transition, gated token skip, propagation ----
    trans(v0, s0, mem_val1, level_route + 0 * 2 * RT, S0, S1);
    apply(mem_state1, s1, mem_val1, v1, S1, 1, nullptr, 0);
    trans(tok_val, tok_state, v1, skip_route + 0 * 2 * RT, T, S1);
    apply(s1, s1, v1, v1, S1, 1, skip_gates, 0);
    trans(v1, s1, v1, prop_route + 1 * 2 * RT, S1, S1);
    apply(s1, s1, v1, v1, S1, 1, nullptr, 0);

    // ---- level 2: transition, gated level-0 skip, propagation ----
    trans(v1, s1, mem_val2, level_route + 1 * 2 * RT, S1, S2);
    apply(mem_state2, s2, mem_val2, v2, S2, 2, nullptr, 0);
    trans(v0, s0, v2, skip_route + 1 * 2 * RT, S0, S2);
    apply(s2, s2, v2, v2, S2, 2, skip_gates, 1);
    trans(v2, s2, v2, prop_route + 2 * 2 * RT, S2, S2);
    apply(s2, s2, v2, v2, S2, 2, nullptr, 0);

    // ---- read phase ----
    hipMemcpyAsync(out, tok_val, (size_t)Bn * T * D * sizeof(float),
                   hipMemcpyDeviceToDevice, stream);
    const float* mvs[3] = { v0, v1, v2 };
    const int nds[3] = { S0, S1, S2 };
    for (int l = 0; l < 3; ++l) {
        const float* mv = mvs[l];
        int Nd = nds[l];
        gemm_kernel<false><<<dim3(T / 32, 1, Bn), 256, 0, stream>>>(
            tok_val, read_route + (long)l * 2 * RT, qb, T, R, D,
            (long)T * D, 0, (long)T * R, 1.f, nullptr, 0, 0.f);
        gemm_kernel<false><<<dim3(Nd / 32, 1, Bn), 256, 0, stream>>>(
            mv, read_route + (long)l * 2 * RT + RT, kb, Nd, R, D,
            (long)Nd * D, 0, (long)Nd * R, 1.f, nullptr, 0, 0.f);
        gemm_kernel<true><<<dim3(T / 32, Nd / 64, Bn), 256, 0, stream>>>(
            qb, kb, lb, T, Nd, R, (long)T * R, (long)Nd * R, (long)T * Nd,
            0.125f, nullptr, 0, 0.f);
        softmax_rows_kernel<<<Bn * T, 256, 0, stream>>>(lb, Nd);
        gemm_kernel<false><<<dim3(T / 32, D / 64, Bn), 256, 0, stream>>>(
            lb, mv, rb, T, D, Nd, (long)T * Nd, (long)Nd * D, (long)T * D,
            1.f, nullptr, 0, 0.f);
        gemm_kernel<false><<<dim3(T / 32, D / 64, Bn), 256, 0, stream>>>(
            rb, read_proj + (long)l * D * D, out, T, D, D,
            (long)T * D, 0, (long)T * D, 1.f, read_gates, l, 1.f);
    }
}

// Round 3
// 3111.925 us; speedup vs baseline: 1.1849x; 1.1430x over previous
//
#include <hip/hip_runtime.h>
#include <math.h>

// ---------------------------------------------------------------------------
// Generic tiled fp32 GEMM: C[b] = alpha' * A[b](M,K) x B[b](K,N | N,K if TRANSB) + beta*C[b]
// alpha' = alpha * (gate ? sigmoid(gate[gateIdx]) : 1)
// Tiles: 32(M) x 64(N) x 32(K), 256 threads, 8 outputs/thread (8m x 1n).
// ---------------------------------------------------------------------------
template<bool TRANSB>
__launch_bounds__(256)
__global__ void gemm_kernel(const float* __restrict__ A, const float* __restrict__ B,
                            float* __restrict__ C, int M, int N, int K,
                            long sA, long sB, long sC,
                            float alpha, const float* __restrict__ gate, int gateIdx,
                            float beta)
{
    __shared__ float As[32 * 36];
    __shared__ float Bs[TRANSB ? 64 * 33 : 32 * 65];
    const float* Ab = A + (long)blockIdx.z * sA;
    const float* Bb = B + (long)blockIdx.z * sB;
    float* Cb = C + (long)blockIdx.z * sC;
    int m0 = blockIdx.x * 32;
    int n0 = blockIdx.y * 64;
    int t  = threadIdx.x;
    int n  = t & 63;
    int mb = (t >> 6) * 8;
    float acc[8];
#pragma unroll
    for (int i = 0; i < 8; ++i) acc[i] = 0.f;

    for (int k0 = 0; k0 < K; k0 += 32) {
        for (int i = t; i < 32 * 32; i += 256) {
            int m = i >> 5, kk = i & 31;
            As[kk * 36 + m] = Ab[(long)(m0 + m) * K + k0 + kk];
        }
        if (!TRANSB) {
            for (int i = t; i < 32 * 64; i += 256) {
                int kk = i >> 6, nn = i & 63;
                Bs[kk * 65 + nn] = Bb[(long)(k0 + kk) * N + n0 + nn];
            }
        } else {
            for (int i = t; i < 64 * 32; i += 256) {
                int nn = i >> 5, kk = i & 31;
                Bs[nn * 33 + kk] = Bb[(long)(n0 + nn) * K + k0 + kk];
            }
        }
        __syncthreads();
#pragma unroll 8
        for (int kk = 0; kk < 32; ++kk) {
            float bv = TRANSB ? Bs[n * 33 + kk] : Bs[kk * 65 + n];
            const float* ap = &As[kk * 36 + mb];
#pragma unroll
            for (int i = 0; i < 8; ++i) acc[i] += ap[i] * bv;
        }
        __syncthreads();
    }
    float a = alpha;
    if (gate) a *= 1.f / (1.f + expf(-gate[gateIdx]));
#pragma unroll
    for (int i = 0; i < 8; ++i) {
        long off = (long)(m0 + mb + i) * N + n0 + n;
        float v = a * acc[i];
        if (beta != 0.f) v += Cb[off];
        Cb[off] = v;
    }
}

// ---------------------------------------------------------------------------
// Exact top-16 per row (one wave per row), tie-break = lower index (jax.lax.top_k).
// Produces edge coefficients c = sign(v)*softmax(|v|)*softplus(state) and indices.
// ---------------------------------------------------------------------------
template<int CNT>
__launch_bounds__(64)
__global__ void topk_coeff_kernel(const float* __restrict__ logits,
                                  const float* __restrict__ state,
                                  int* __restrict__ idx_out, float* __restrict__ c_out,
                                  int Nd)
{
    long row = blockIdx.x;
    int lane = threadIdx.x;
    const float* L = logits + row * Nd;
    float vreg[CNT];
#pragma unroll
    for (int tt = 0; tt < CNT; ++tt) vreg[tt] = L[lane + (tt << 6)];

    float m = 0.f, sum = 0.f;
    float myv = 0.f; int myi = 0;
#pragma unroll
    for (int it = 0; it < 16; ++it) {
        float best = -INFINITY; int bidx = 0x7fffffff;
#pragma unroll
        for (int tt = 0; tt < CNT; ++tt) {
            if (vreg[tt] > best) { best = vreg[tt]; bidx = lane + (tt << 6); }
        }
#pragma unroll
        for (int off = 32; off; off >>= 1) {
            float ov = __shfl_down(best, off);
            int   oi = __shfl_down(bidx, off);
            if (ov > best || (ov == best && oi < bidx)) { best = ov; bidx = oi; }
        }
        best = __shfl(best, 0);
        bidx = __shfl(bidx, 0);
        if (it == lane) { myv = best; myi = bidx; }
        float ab = fabsf(best);
        float nm = fmaxf(m, ab);
        sum = sum * expf(m - nm) + expf(ab - nm);
        m = nm;
#pragma unroll
        for (int tt = 0; tt < CNT; ++tt)
            if (lane + (tt << 6) == bidx) vreg[tt] = -INFINITY;
    }
    if (lane < 16) {
        float st = state[row];
        float sp = fmaxf(st, 0.f) + log1pf(expf(-fabsf(st)));
        float sgn = (myv > 0.f) ? 1.f : ((myv < 0.f) ? -1.f : 0.f);
        float w = expf(fabsf(myv) - m) / sum;
        c_out[row * 16 + lane] = sgn * w * sp;
        idx_out[row * 16 + lane] = myi;
    }
}

// ---------------------------------------------------------------------------
// CSR build: count edges per destination, scan, fill edge lists.
// ---------------------------------------------------------------------------
__launch_bounds__(256)
__global__ void count_edges_kernel(const int* __restrict__ idx, int* __restrict__ cnt,
                                   int nsShift, int Nd, int E)
{
    int e = blockIdx.x * 256 + threadIdx.x;
    if (e >= E) return;
    int b = e >> nsShift;
    atomicAdd(&cnt[b * Nd + idx[e]], 1);
}

// Single-block exclusive scan over N entries (N multiple of 256, N <= 4096).
__launch_bounds__(256)
__global__ void scan_kernel(const int* __restrict__ cnt, int* __restrict__ offs, int N)
{
    __shared__ int sums[256];
    int t = threadIdx.x;
    int chunk = N >> 8;
    int base = t * chunk;
    int s = 0;
    for (int i = 0; i < chunk; ++i) s += cnt[base + i];
    sums[t] = s;
    __syncthreads();
    for (int off = 1; off < 256; off <<= 1) {
        int v = (t >= off) ? sums[t - off] : 0;
        __syncthreads();
        sums[t] += v;
        __syncthreads();
    }
    int run = sums[t] - s;
    for (int i = 0; i < chunk; ++i) {
        offs[base + i] = run;
        run += cnt[base + i];
    }
    if (t == 255) offs[N] = run;
}

__launch_bounds__(256)
__global__ void fill_edges_kernel(const int* __restrict__ idx, const int* __restrict__ offs,
                                  int* __restrict__ cursor, int* __restrict__ elist,
                                  int nsShift, int Nd, int E)
{
    int e = blockIdx.x * 256 + threadIdx.x;
    if (e >= E) return;
    int b = e >> nsShift;
    int d = b * Nd + idx[e];
    int pos = offs[d] + atomicAdd(&cursor[d], 1);
    elist[pos] = e;
}

// ---------------------------------------------------------------------------
// Gather delta-values per destination row: dv[row] = sum_e c[e]*src[src_row(e)],
// and ds[row] = sum_e c[e] (computed redundantly by all threads, written by t0).
// One block (256 thr) per destination row of 512.
// ---------------------------------------------------------------------------
__launch_bounds__(256)
__global__ void gather_dv_kernel(const float* __restrict__ src_val, const float* __restrict__ c,
                                 const int* __restrict__ elist, const int* __restrict__ offs,
                                 float* __restrict__ dv, float* __restrict__ ds, int nsShift)
{
    long row = blockIdx.x;
    int t = threadIdx.x;
    int e0 = offs[row], e1 = offs[row + 1];
    float a0 = 0.f, a1 = 0.f, cs = 0.f;
    int mask = (1 << nsShift) - 1;
    for (int ei = e0; ei < e1; ++ei) {
        int e = elist[ei];
        float cv = c[e];
        cs += cv;
        int b = e >> nsShift;
        int s = (e & mask) >> 4;
        const float* src = src_val + ((long)((b << (nsShift - 4)) + s) << 9);
        a0 += cv * src[t];
        a1 += cv * src[t + 256];
    }
    dv[(row << 9) + t]       = a0;
    dv[(row << 9) + t + 256] = a1;
    if (t == 0) ds[row] = cs;
}

// ---------------------------------------------------------------------------
// state' = sign(x)*softmax(|x|) over slot axis, x = s + gate*ds. One block per batch.
// ---------------------------------------------------------------------------
__launch_bounds__(256)
__global__ void apply_state_kernel(const float* __restrict__ s_in, const float* __restrict__ ds,
                                   float* __restrict__ s_out, int Nd,
                                   const float* __restrict__ gatePtr, int gateIdx)
{
    __shared__ float sh[1024];
    __shared__ float red[4];
    int b = blockIdx.x, t = threadIdx.x;
    float gate = 1.f;
    if (gatePtr) gate = 1.f / (1.f + expf(-gatePtr[gateIdx]));
    float lmax = 0.f;
    for (int i = t; i < Nd; i += 256) {
        float x = s_in[b * Nd + i] + gate * ds[b * Nd + i];
        sh[i] = x;
        lmax = fmaxf(lmax, fabsf(x));
    }
    for (int off = 32; off; off >>= 1) lmax = fmaxf(lmax, __shfl_down(lmax, off));
    if ((t & 63) == 0) red[t >> 6] = lmax;
    __syncthreads();
    float bmax = fmaxf(fmaxf(red[0], red[1]), fmaxf(red[2], red[3]));
    float lsum = 0.f;
    for (int i = t; i < Nd; i += 256) lsum += expf(fabsf(sh[i]) - bmax);
    for (int off = 32; off; off >>= 1) lsum += __shfl_down(lsum, off);
    __syncthreads();
    if ((t & 63) == 0) red[t >> 6] = lsum;
    __syncthreads();
    float inv = 1.f / (red[0] + red[1] + red[2] + red[3]);
    for (int i = t; i < Nd; i += 256) {
        float x = sh[i];
        float sgn = (x > 0.f) ? 1.f : ((x < 0.f) ? -1.f : 0.f);
        s_out[b * Nd + i] = sgn * expf(fabsf(x) - bmax) * inv;
    }
}

// ---------------------------------------------------------------------------
// val' = LayerNorm(v + gate*dv) * gamma + beta. One block (256 thr) per row of 512.
// ---------------------------------------------------------------------------
__launch_bounds__(256)
__global__ void apply_ln_kernel(const float* __restrict__ v_in, const float* __restrict__ dv,
                                float* __restrict__ v_out, const float* __restrict__ gamma,
                                const float* __restrict__ beta,
                                const float* __restrict__ gatePtr, int gateIdx)
{
    __shared__ float red[4];
    long row = blockIdx.x;
    int t = threadIdx.x;
    float gate = 1.f;
    if (gatePtr) gate = 1.f / (1.f + expf(-gatePtr[gateIdx]));
    const float* vi  = v_in + (row << 9);
    const float* dvi = dv   + (row << 9);
    float x0 = vi[t]       + gate * dvi[t];
    float x1 = vi[t + 256] + gate * dvi[t + 256];
    float s = x0 + x1;
    for (int off = 32; off; off >>= 1) s += __shfl_down(s, off);
    if ((t & 63) == 0) red[t >> 6] = s;
    __syncthreads();
    float mean = (red[0] + red[1] + red[2] + red[3]) * (1.f / 512.f);
    float d0 = x0 - mean, d1 = x1 - mean;
    float ss = d0 * d0 + d1 * d1;
    for (int off = 32; off; off >>= 1) ss += __shfl_down(ss, off);
    __syncthreads();
    if ((t & 63) == 0) red[t >> 6] = ss;
    __syncthreads();
    float var = (red[0] + red[1] + red[2] + red[3]) * (1.f / 512.f);
    float rstd = rsqrtf(var + 1e-5f);
    float* vo = v_out + (row << 9);
    vo[t]       = d0 * rstd * gamma[t]       + beta[t];
    vo[t + 256] = d1 * rstd * gamma[t + 256] + beta[t + 256];
}

// ---------------------------------------------------------------------------
// Plain softmax over rows (read attention), in place.
// ---------------------------------------------------------------------------
__launch_bounds__(256)
__global__ void softmax_rows_kernel(float* __restrict__ logits, int Nd)
{
    __shared__ float red[4];
    long row = blockIdx.x;
    int t = threadIdx.x;
    float* L = logits + row * (long)Nd;
    float lmax = -INFINITY;
    for (int i = t; i < Nd; i += 256) lmax = fmaxf(lmax, L[i]);
    for (int off = 32; off; off >>= 1) lmax = fmaxf(lmax, __shfl_down(lmax, off));
    if ((t & 63) == 0) red[t >> 6] = lmax;
    __syncthreads();
    float bmax = fmaxf(fmaxf(red[0], red[1]), fmaxf(red[2], red[3]));
    float lsum = 0.f;
    for (int i = t; i < Nd; i += 256) lsum += expf(L[i] - bmax);
    for (int off = 32; off; off >>= 1) lsum += __shfl_down(lsum, off);
    __syncthreads();
    if ((t & 63) == 0) red[t >> 6] = lsum;
    __syncthreads();
    float inv = 1.f / (red[0] + red[1] + red[2] + red[3]);
    for (int i = t; i < Nd; i += 256) L[i] = expf(L[i] - bmax) * inv;
}

// ---------------------------------------------------------------------------
extern "C" void kernel_launch(void* const* d_in, const int* in_sizes, int n_in,
                              void* d_out, int out_size, void* d_ws, size_t ws_size,
                              hipStream_t stream)
{
    const int Bn = 4, T = 1024, D = 512, R = 64;
    const int S0 = 1024, S1 = 256, S2 = 64;
    const long RT = (long)D * R;

    const float* tok_val    = (const float*)d_in[0];
    const float* tok_state  = (const float*)d_in[1];
    const float* mem_state0 = (const float*)d_in[2];
    const float* mem_val0   = (const float*)d_in[3];
    const float* mem_state1 = (const float*)d_in[4];
    const float* mem_val1   = (const float*)d_in[5];
    const float* mem_state2 = (const float*)d_in[6];
    const float* mem_val2   = (const float*)d_in[7];
    const float* write_route= (const float*)d_in[8];
    const float* prop_route = (const float*)d_in[9];
    const float* level_route= (const float*)d_in[10];
    const float* skip_route = (const float*)d_in[11];
    const float* skip_gates = (const float*)d_in[12];
    const float* ln_gamma   = (const float*)d_in[13];
    const float* ln_beta    = (const float*)d_in[14];
    const float* read_route = (const float*)d_in[15];
    const float* read_proj  = (const float*)d_in[16];
    const float* read_gates = (const float*)d_in[17];
    float* out = (float*)d_out;

    // workspace carve
    float* p = (float*)d_ws;
    float* v0 = p;  p += (long)Bn * S0 * D;
    float* s0 = p;  p += Bn * S0;
    float* v1 = p;  p += (long)Bn * S1 * D;
    float* s1 = p;  p += Bn * S1;
    float* v2 = p;  p += (long)Bn * S2 * D;
    float* s2 = p;  p += Bn * S2;
    float* qb = p;  p += (long)Bn * T * R;
    float* kb = p;  p += (long)Bn * S0 * R;
    float* lb = p;  p += (long)Bn * T * S0;
    float* cb = p;  p += (long)Bn * T * 16;
    int*   ib = (int*)p; p += (long)Bn * T * 16;
    float* dvb = p; p += (long)Bn * S0 * D;
    float* dsb = p; p += Bn * S0;
    float* rb = p;  p += (long)Bn * T * D;
    int* cntb  = (int*)p; p += Bn * S0;        // counts  [B*Nd]
    int* curb  = (int*)p; p += Bn * S0;        // cursors [B*Nd] (contiguous after cnt)
    int* offsb = (int*)p; p += Bn * S0 + 1;    // offsets [B*Nd + 1]
    int* elistb= (int*)p; p += (long)Bn * T * 16;

    auto trans = [&](const float* sv, const float* ss, const float* dval,
                     const float* W, int Ns, int Nd) {
        gemm_kernel<false><<<dim3(Ns / 32, R / 64, Bn), 256, 0, stream>>>(
            sv, W, qb, Ns, R, D, (long)Ns * D, 0, (long)Ns * R, 1.f, nullptr, 0, 0.f);
        gemm_kernel<false><<<dim3(Nd / 32, R / 64, Bn), 256, 0, stream>>>(
            dval, W + RT, kb, Nd, R, D, (long)Nd * D, 0, (long)Nd * R, 1.f, nullptr, 0, 0.f);
        gemm_kernel<true><<<dim3(Ns / 32, Nd / 64, Bn), 256, 0, stream>>>(
            qb, kb, lb, Ns, Nd, R, (long)Ns * R, (long)Nd * R, (long)Ns * Nd,
            0.125f, nullptr, 0, 0.f);
        if (Nd == 1024)
            topk_coeff_kernel<16><<<Bn * Ns, 64, 0, stream>>>(lb, ss, ib, cb, Nd);
        else if (Nd == 256)
            topk_coeff_kernel<4><<<Bn * Ns, 64, 0, stream>>>(lb, ss, ib, cb, Nd);
        else
            topk_coeff_kernel<1><<<Bn * Ns, 64, 0, stream>>>(lb, ss, ib, cb, Nd);
        // CSR build + gather (replaces atomic scatter)
        int E = Bn * Ns * 16;
        int nsShift = 31 - __builtin_clz((unsigned)Ns) + 4;   // log2(Ns)+4
        hipMemsetAsync(cntb, 0, (size_t)2 * Bn * S0 * sizeof(int), stream); // cnt+cursor
        count_edges_kernel<<<(E + 255) / 256, 256, 0, stream>>>(ib, cntb, nsShift, Nd, E);
        scan_kernel<<<1, 256, 0, stream>>>(cntb, offsb, Bn * Nd);
        fill_edges_kernel<<<(E + 255) / 256, 256, 0, stream>>>(ib, offsb, curb, elistb,
                                                               nsShift, Nd, E);
        gather_dv_kernel<<<Bn * Nd, 256, 0, stream>>>(sv, cb, elistb, offsb, dvb, dsb,
                                                      nsShift);
    };
    auto apply = [&](const float* sin, float* sout, const float* vin, float* vout,
                     int Nd, int lvl, const float* gptr, int gidx) {
        apply_state_kernel<<<Bn, 256, 0, stream>>>(sin, dsb, sout, Nd, gptr, gidx);
        apply_ln_kernel<<<Bn * Nd, 256, 0, stream>>>(vin, dvb, vout,
            ln_gamma + lvl * D, ln_beta + lvl * D, gptr, gidx);
    };

    // ---- level 0: token write + propagation ----
    trans(tok_val, tok_state, mem_val0, write_route, T, S0);
    apply(mem_state0, s0, mem_val0, v0, S0, 0, nullptr, 0);
    trans(v0, s0, v0, prop_route + 0 * 2 * RT, S0, S0);
    apply(s0, s0, v0, v0, S0, 0, nullptr, 0);

    // ---- level 1: transition, gated token skip, propagation ----
    trans(v0, s0, mem_val1, level_route + 0 * 2 * RT, S0, S1);
    apply(mem_state1, s1, mem_val1, v1, S1, 1, nullptr, 0);
    trans(tok_val, tok_state, v1, skip_route + 0 * 2 * RT, T, S1);
    apply(s1, s1, v1, v1, S1, 1, skip_gates, 0);
    trans(v1, s1, v1, prop_route + 1 * 2 * RT, S1, S1);
    apply(s1, s1, v1, v1, S1, 1, nullptr, 0);

    // ---- level 2: transition, gated level-0 skip, propagation ----
    trans(v1, s1, mem_val2, level_route + 1 * 2 * RT, S1, S2);
    apply(mem_state2, s2, mem_val2, v2, S2, 2, nullptr, 0);
    trans(v0, s0, v2, skip_route + 1 * 2 * RT, S0, S2);
    apply(s2, s2, v2, v2, S2, 2, skip_gates, 1);
    trans(v2, s2, v2, prop_route + 2 * 2 * RT, S2, S2);
    apply(s2, s2, v2, v2, S2, 2, nullptr, 0);

    // ---- read phase ----
    hipMemcpyAsync(out, tok_val, (size_t)Bn * T * D * sizeof(float),
                   hipMemcpyDeviceToDevice, stream);
    const float* mvs[3] = { v0, v1, v2 };
    const int nds[3] = { S0, S1, S2 };
    for (int l = 0; l < 3; ++l) {
        const float* mv = mvs[l];
        int Nd = nds[l];
        gemm_kernel<false><<<dim3(T / 32, 1, Bn), 256, 0, stream>>>(
            tok_val, read_route + (long)l * 2 * RT, qb, T, R, D,
            (long)T * D, 0, (long)T * R, 1.f, nullptr, 0, 0.f);
        gemm_kernel<false><<<dim3(Nd / 32, 1, Bn), 256, 0, stream>>>(
            mv, read_route + (long)l * 2 * RT + RT, kb, Nd, R, D,
            (long)Nd * D, 0, (long)Nd * R, 1.f, nullptr, 0, 0.f);
        gemm_kernel<true><<<dim3(T / 32, Nd / 64, Bn), 256, 0, stream>>>(
            qb, kb, lb, T, Nd, R, (long)T * R, (long)Nd * R, (long)T * Nd,
            0.125f, nullptr, 0, 0.f);
        softmax_rows_kernel<<<Bn * T, 256, 0, stream>>>(lb, Nd);
        gemm_kernel<false><<<dim3(T / 32, D / 64, Bn), 256, 0, stream>>>(
            lb, mv, rb, T, D, Nd, (long)T * Nd, (long)Nd * D, (long)T * D,
            1.f, nullptr, 0, 0.f);
        gemm_kernel<false><<<dim3(T / 32, D / 64, Bn), 256, 0, stream>>>(
            rb, read_proj + (long)l * D * D, out, T, D, D,
            (long)T * D, 0, (long)T * D, 1.f, read_gates, l, 1.f);
    }
}

// Round 4
// 1949.489 us; speedup vs baseline: 1.8914x; 1.5963x over previous
//
#include <hip/hip_runtime.h>
#include <math.h>

typedef __attribute__((ext_vector_type(8))) short short8;
typedef __attribute__((ext_vector_type(4))) float floatx4;

static __device__ __forceinline__ short f2bf(float f) {
    union { float f; unsigned u; } c; c.f = f;
    unsigned r = c.u + 0x7FFF + ((c.u >> 16) & 1);   // RNE
    return (short)(r >> 16);
}

// ---------------------------------------------------------------------------
// fp32 GEMM v2: C[b] = alpha * A[b](M,K) x B[b](K,N | N,K if TRANSB)
// 64x64 tile, 256 thr, 4x4 micro-tile (16 acc), K-step 32.
// M,N multiples of 64; K multiple of 32. Used for q/k proj + logits (fp32-exact
// path: top-k selection must match the fp32 numpy reference).
// ---------------------------------------------------------------------------
template<bool TRANSB>
__launch_bounds__(256)
__global__ void gemm_f32_kernel(const float* __restrict__ A, const float* __restrict__ B,
                                float* __restrict__ C, int M, int N, int K,
                                long sA, long sB, long sC, float alpha)
{
    __shared__ float As[32][68];   // [k][m]
    __shared__ float Bs[32][68];   // [k][n]
    const float* Ab = A + (long)blockIdx.z * sA;
    const float* Bb = B + (long)blockIdx.z * sB;
    float* Cb = C + (long)blockIdx.z * sC;
    int m0 = blockIdx.x * 64, n0 = blockIdx.y * 64;
    int t = threadIdx.x;
    int tx = t & 15, ty = t >> 4;
    float acc[4][4] = {};

    for (int k0 = 0; k0 < K; k0 += 32) {
        {   // A: [m][k] -> As[k][m]
            int m = t >> 3;
            int kk = (t & 7) * 4;
#pragma unroll
            for (int h = 0; h < 2; ++h) {
                float4 v = *(const float4*)&Ab[(long)(m0 + m + 32 * h) * K + k0 + kk];
                As[kk + 0][m + 32 * h] = v.x; As[kk + 1][m + 32 * h] = v.y;
                As[kk + 2][m + 32 * h] = v.z; As[kk + 3][m + 32 * h] = v.w;
            }
        }
        if (!TRANSB) {   // B: [k][n] -> Bs[k][n]
            int kk = t >> 3;
            int nn = (t & 7) * 8;
            float4 v0 = *(const float4*)&Bb[(long)(k0 + kk) * N + n0 + nn];
            float4 v1 = *(const float4*)&Bb[(long)(k0 + kk) * N + n0 + nn + 4];
            *(float4*)&Bs[kk][nn] = v0;
            *(float4*)&Bs[kk][nn + 4] = v1;
        } else {         // B: [n][k] -> Bs[k][n]
            int n = t >> 3;
            int kk = (t & 7) * 4;
#pragma unroll
            for (int h = 0; h < 2; ++h) {
                float4 v = *(const float4*)&Bb[(long)(n0 + n + 32 * h) * K + k0 + kk];
                Bs[kk + 0][n + 32 * h] = v.x; Bs[kk + 1][n + 32 * h] = v.y;
                Bs[kk + 2][n + 32 * h] = v.z; Bs[kk + 3][n + 32 * h] = v.w;
            }
        }
        __syncthreads();
#pragma unroll 4
        for (int k = 0; k < 32; ++k) {
            float4 a = *(const float4*)&As[k][ty * 4];
            float4 b = *(const float4*)&Bs[k][tx * 4];
            float av[4] = { a.x, a.y, a.z, a.w };
            float bv[4] = { b.x, b.y, b.z, b.w };
#pragma unroll
            for (int i = 0; i < 4; ++i)
#pragma unroll
                for (int j = 0; j < 4; ++j) acc[i][j] += av[i] * bv[j];
        }
        __syncthreads();
    }
#pragma unroll
    for (int i = 0; i < 4; ++i) {
        float4 r;
        r.x = alpha * acc[i][0]; r.y = alpha * acc[i][1];
        r.z = alpha * acc[i][2]; r.w = alpha * acc[i][3];
        *(float4*)&Cb[(long)(m0 + ty * 4 + i) * N + n0 + tx * 4] = r;
    }
}

// ---------------------------------------------------------------------------
// bf16 MFMA GEMM: C[b](M,N) = alpha' * A[b](M,K,fp32) x Bt[b](N,K,bf16) + beta*C
// alpha' = alpha * (gate ? sigmoid(gate[gateIdx]) : 1).
// 64x64 tile, 4 waves, each wave: one 16-col strip, 4x mfma_f32_16x16x32_bf16.
// A converted fp32->bf16 in-register during staging; LDS in frag-order so all
// fragment reads are contiguous conflict-free ds_read_b128.
// M,N multiples of 64; K multiple of 32.
// ---------------------------------------------------------------------------
__launch_bounds__(256)
__global__ void gemm_mfma_kernel(const float* __restrict__ A, const unsigned short* __restrict__ Bt,
                                 float* __restrict__ C, int M, int N, int K,
                                 long sA, long sBt, long sC,
                                 float alpha, const float* __restrict__ gate, int gateIdx,
                                 float beta)
{
    __shared__ short As[2048];   // [mt*64+lane]*8 bf16, frag order
    __shared__ short Bs[2048];   // [nt*64+lane]*8 bf16, frag order
    const float* Ab = A + (long)blockIdx.z * sA;
    const unsigned short* Bb = Bt + (long)blockIdx.z * sBt;
    float* Cb = C + (long)blockIdx.z * sC;
    int m0 = blockIdx.x * 64, n0 = blockIdx.y * 64;
    int t = threadIdx.x, wave = t >> 6, lane = t & 63;
    int sr = wave * 16 + (lane & 15);        // staging row (m or n)
    int sk = (lane >> 4) * 8;                // staging k offset within 32-tile
    floatx4 acc[4] = {};

    for (int k0 = 0; k0 < K; k0 += 32) {
        const float* ap = &Ab[(long)(m0 + sr) * K + k0 + sk];
        float4 f0 = *(const float4*)ap;
        float4 f1 = *(const float4*)(ap + 4);
        short8 av;
        av[0] = f2bf(f0.x); av[1] = f2bf(f0.y); av[2] = f2bf(f0.z); av[3] = f2bf(f0.w);
        av[4] = f2bf(f1.x); av[5] = f2bf(f1.y); av[6] = f2bf(f1.z); av[7] = f2bf(f1.w);
        short8 bv = *(const short8*)&Bb[(long)(n0 + sr) * K + k0 + sk];
        ((short8*)As)[t] = av;
        ((short8*)Bs)[t] = bv;
        __syncthreads();
        short8 bf = ((short8*)Bs)[wave * 64 + lane];
#pragma unroll
        for (int mt = 0; mt < 4; ++mt) {
            short8 af = ((short8*)As)[mt * 64 + lane];
            acc[mt] = __builtin_amdgcn_mfma_f32_16x16x32_bf16(af, bf, acc[mt], 0, 0, 0);
        }
        __syncthreads();
    }
    float a = alpha;
    if (gate) a *= 1.f / (1.f + expf(-gate[gateIdx]));
    int col = n0 + wave * 16 + (lane & 15);
#pragma unroll
    for (int mt = 0; mt < 4; ++mt) {
#pragma unroll
        for (int r = 0; r < 4; ++r) {
            int row = m0 + mt * 16 + (lane >> 4) * 4 + r;
            long off = (long)row * N + col;
            float v = a * acc[mt][r];
            if (beta != 0.f) v += Cb[off];
            Cb[off] = v;
        }
    }
}

// ---------------------------------------------------------------------------
// Transpose + bf16 convert: out[c][r] = bf16(in[r][c]). 32x32 tiles, (32,8) thr.
// ---------------------------------------------------------------------------
__global__ void transpose_bf16_kernel(const float* __restrict__ in, unsigned short* __restrict__ out,
                                      int Rr, int Cc, long sIn, long sOut)
{
    __shared__ float tile[32][33];
    const float* I = in + (long)blockIdx.z * sIn;
    unsigned short* O = out + (long)blockIdx.z * sOut;
    int c0 = blockIdx.x * 32, r0 = blockIdx.y * 32;
    int tx = threadIdx.x, ty = threadIdx.y;
#pragma unroll
    for (int i = 0; i < 32; i += 8)
        tile[ty + i][tx] = I[(long)(r0 + ty + i) * Cc + c0 + tx];
    __syncthreads();
#pragma unroll
    for (int i = 0; i < 32; i += 8)
        O[(long)(c0 + ty + i) * Rr + r0 + tx] = (unsigned short)f2bf(tile[tx][ty + i]);
}

// ---------------------------------------------------------------------------
// Exact top-16 per row (one wave per row), tie-break = lower index (jax.lax.top_k).
// ---------------------------------------------------------------------------
template<int CNT>
__launch_bounds__(64)
__global__ void topk_coeff_kernel(const float* __restrict__ logits,
                                  const float* __restrict__ state,
                                  int* __restrict__ idx_out, float* __restrict__ c_out,
                                  int Nd)
{
    long row = blockIdx.x;
    int lane = threadIdx.x;
    const float* L = logits + row * Nd;
    float vreg[CNT];
#pragma unroll
    for (int tt = 0; tt < CNT; ++tt) vreg[tt] = L[lane + (tt << 6)];

    float m = 0.f, sum = 0.f;
    float myv = 0.f; int myi = 0;
#pragma unroll
    for (int it = 0; it < 16; ++it) {
        float best = -INFINITY; int bidx = 0x7fffffff;
#pragma unroll
        for (int tt = 0; tt < CNT; ++tt) {
            if (vreg[tt] > best) { best = vreg[tt]; bidx = lane + (tt << 6); }
        }
#pragma unroll
        for (int off = 32; off; off >>= 1) {
            float ov = __shfl_down(best, off);
            int   oi = __shfl_down(bidx, off);
            if (ov > best || (ov == best && oi < bidx)) { best = ov; bidx = oi; }
        }
        best = __shfl(best, 0);
        bidx = __shfl(bidx, 0);
        if (it == lane) { myv = best; myi = bidx; }
        float ab = fabsf(best);
        float nm = fmaxf(m, ab);
        sum = sum * expf(m - nm) + expf(ab - nm);
        m = nm;
#pragma unroll
        for (int tt = 0; tt < CNT; ++tt)
            if (lane + (tt << 6) == bidx) vreg[tt] = -INFINITY;
    }
    if (lane < 16) {
        float st = state[row];
        float sp = fmaxf(st, 0.f) + log1pf(expf(-fabsf(st)));
        float sgn = (myv > 0.f) ? 1.f : ((myv < 0.f) ? -1.f : 0.f);
        float w = expf(fabsf(myv) - m) / sum;
        c_out[row * 16 + lane] = sgn * w * sp;
        idx_out[row * 16 + lane] = myi;
    }
}

// ---------------------------------------------------------------------------
// CSR build: count edges per destination, scan, fill edge lists.
// ---------------------------------------------------------------------------
__launch_bounds__(256)
__global__ void count_edges_kernel(const int* __restrict__ idx, int* __restrict__ cnt,
                                   int nsShift, int Nd, int E)
{
    int e = blockIdx.x * 256 + threadIdx.x;
    if (e >= E) return;
    int b = e >> nsShift;
    atomicAdd(&cnt[b * Nd + idx[e]], 1);
}

__launch_bounds__(256)
__global__ void scan_kernel(const int* __restrict__ cnt, int* __restrict__ offs, int N)
{
    __shared__ int sums[256];
    int t = threadIdx.x;
    int chunk = N >> 8;
    int base = t * chunk;
    int s = 0;
    for (int i = 0; i < chunk; ++i) s += cnt[base + i];
    sums[t] = s;
    __syncthreads();
    for (int off = 1; off < 256; off <<= 1) {
        int v = (t >= off) ? sums[t - off] : 0;
        __syncthreads();
        sums[t] += v;
        __syncthreads();
    }
    int run = sums[t] - s;
    for (int i = 0; i < chunk; ++i) {
        offs[base + i] = run;
        run += cnt[base + i];
    }
    if (t == 255) offs[N] = run;
}

__launch_bounds__(256)
__global__ void fill_edges_kernel(const int* __restrict__ idx, const int* __restrict__ offs,
                                  int* __restrict__ cursor, int* __restrict__ elist,
                                  int nsShift, int Nd, int E)
{
    int e = blockIdx.x * 256 + threadIdx.x;
    if (e >= E) return;
    int b = e >> nsShift;
    int d = b * Nd + idx[e];
    int pos = offs[d] + atomicAdd(&cursor[d], 1);
    elist[pos] = e;
}

// ---------------------------------------------------------------------------
// Gather dv[row] = sum_e c[e]*src[src_row(e)]; ds[row] = sum_e c[e].
// ---------------------------------------------------------------------------
__launch_bounds__(256)
__global__ void gather_dv_kernel(const float* __restrict__ src_val, const float* __restrict__ c,
                                 const int* __restrict__ elist, const int* __restrict__ offs,
                                 float* __restrict__ dv, float* __restrict__ ds, int nsShift)
{
    long row = blockIdx.x;
    int t = threadIdx.x;
    int e0 = offs[row], e1 = offs[row + 1];
    float a0 = 0.f, a1 = 0.f, cs = 0.f;
    int mask = (1 << nsShift) - 1;
    for (int ei = e0; ei < e1; ++ei) {
        int e = elist[ei];
        float cv = c[e];
        cs += cv;
        int b = e >> nsShift;
        int s = (e & mask) >> 4;
        const float* src = src_val + ((long)((b << (nsShift - 4)) + s) << 9);
        a0 += cv * src[t];
        a1 += cv * src[t + 256];
    }
    dv[(row << 9) + t]       = a0;
    dv[(row << 9) + t + 256] = a1;
    if (t == 0) ds[row] = cs;
}

// ---------------------------------------------------------------------------
// state' = sign(x)*softmax(|x|), x = s + gate*ds. One block per batch.
// ---------------------------------------------------------------------------
__launch_bounds__(256)
__global__ void apply_state_kernel(const float* __restrict__ s_in, const float* __restrict__ ds,
                                   float* __restrict__ s_out, int Nd,
                                   const float* __restrict__ gatePtr, int gateIdx)
{
    __shared__ float sh[1024];
    __shared__ float red[4];
    int b = blockIdx.x, t = threadIdx.x;
    float gate = 1.f;
    if (gatePtr) gate = 1.f / (1.f + expf(-gatePtr[gateIdx]));
    float lmax = 0.f;
    for (int i = t; i < Nd; i += 256) {
        float x = s_in[b * Nd + i] + gate * ds[b * Nd + i];
        sh[i] = x;
        lmax = fmaxf(lmax, fabsf(x));
    }
    for (int off = 32; off; off >>= 1) lmax = fmaxf(lmax, __shfl_down(lmax, off));
    if ((t & 63) == 0) red[t >> 6] = lmax;
    __syncthreads();
    float bmax = fmaxf(fmaxf(red[0], red[1]), fmaxf(red[2], red[3]));
    float lsum = 0.f;
    for (int i = t; i < Nd; i += 256) lsum += expf(fabsf(sh[i]) - bmax);
    for (int off = 32; off; off >>= 1) lsum += __shfl_down(lsum, off);
    __syncthreads();
    if ((t & 63) == 0) red[t >> 6] = lsum;
    __syncthreads();
    float inv = 1.f / (red[0] + red[1] + red[2] + red[3]);
    for (int i = t; i < Nd; i += 256) {
        float x = sh[i];
        float sgn = (x > 0.f) ? 1.f : ((x < 0.f) ? -1.f : 0.f);
        s_out[b * Nd + i] = sgn * expf(fabsf(x) - bmax) * inv;
    }
}

// ---------------------------------------------------------------------------
// val' = LayerNorm(v + gate*dv) * gamma + beta.
// ---------------------------------------------------------------------------
__launch_bounds__(256)
__global__ void apply_ln_kernel(const float* __restrict__ v_in, const float* __restrict__ dv,
                                float* __restrict__ v_out, const float* __restrict__ gamma,
                                const float* __restrict__ beta,
                                const float* __restrict__ gatePtr, int gateIdx)
{
    __shared__ float red[4];
    long row = blockIdx.x;
    int t = threadIdx.x;
    float gate = 1.f;
    if (gatePtr) gate = 1.f / (1.f + expf(-gatePtr[gateIdx]));
    const float* vi  = v_in + (row << 9);
    const float* dvi = dv   + (row << 9);
    float x0 = vi[t]       + gate * dvi[t];
    float x1 = vi[t + 256] + gate * dvi[t + 256];
    float s = x0 + x1;
    for (int off = 32; off; off >>= 1) s += __shfl_down(s, off);
    if ((t & 63) == 0) red[t >> 6] = s;
    __syncthreads();
    float mean = (red[0] + red[1] + red[2] + red[3]) * (1.f / 512.f);
    float d0 = x0 - mean, d1 = x1 - mean;
    float ss = d0 * d0 + d1 * d1;
    for (int off = 32; off; off >>= 1) ss += __shfl_down(ss, off);
    __syncthreads();
    if ((t & 63) == 0) red[t >> 6] = ss;
    __syncthreads();
    float var = (red[0] + red[1] + red[2] + red[3]) * (1.f / 512.f);
    float rstd = rsqrtf(var + 1e-5f);
    float* vo = v_out + (row << 9);
    vo[t]       = d0 * rstd * gamma[t]       + beta[t];
    vo[t + 256] = d1 * rstd * gamma[t + 256] + beta[t + 256];
}

// ---------------------------------------------------------------------------
// Plain softmax over rows, in place.
// ---------------------------------------------------------------------------
__launch_bounds__(256)
__global__ void softmax_rows_kernel(float* __restrict__ logits, int Nd)
{
    __shared__ float red[4];
    long row = blockIdx.x;
    int t = threadIdx.x;
    float* L = logits + row * (long)Nd;
    float lmax = -INFINITY;
    for (int i = t; i < Nd; i += 256) lmax = fmaxf(lmax, L[i]);
    for (int off = 32; off; off >>= 1) lmax = fmaxf(lmax, __shfl_down(lmax, off));
    if ((t & 63) == 0) red[t >> 6] = lmax;
    __syncthreads();
    float bmax = fmaxf(fmaxf(red[0], red[1]), fmaxf(red[2], red[3]));
    float lsum = 0.f;
    for (int i = t; i < Nd; i += 256) lsum += expf(L[i] - bmax);
    for (int off = 32; off; off >>= 1) lsum += __shfl_down(lsum, off);
    __syncthreads();
    if ((t & 63) == 0) red[t >> 6] = lsum;
    __syncthreads();
    float inv = 1.f / (red[0] + red[1] + red[2] + red[3]);
    for (int i = t; i < Nd; i += 256) L[i] = expf(L[i] - bmax) * inv;
}

// ---------------------------------------------------------------------------
extern "C" void kernel_launch(void* const* d_in, const int* in_sizes, int n_in,
                              void* d_out, int out_size, void* d_ws, size_t ws_size,
                              hipStream_t stream)
{
    const int Bn = 4, T = 1024, D = 512, R = 64;
    const int S0 = 1024, S1 = 256, S2 = 64;
    const long RT = (long)D * R;

    const float* tok_val    = (const float*)d_in[0];
    const float* tok_state  = (const float*)d_in[1];
    const float* mem_state0 = (const float*)d_in[2];
    const float* mem_val0   = (const float*)d_in[3];
    const float* mem_state1 = (const float*)d_in[4];
    const float* mem_val1   = (const float*)d_in[5];
    const float* mem_state2 = (const float*)d_in[6];
    const float* mem_val2   = (const float*)d_in[7];
    const float* write_route= (const float*)d_in[8];
    const float* prop_route = (const float*)d_in[9];
    const float* level_route= (const float*)d_in[10];
    const float* skip_route = (const float*)d_in[11];
    const float* skip_gates = (const float*)d_in[12];
    const float* ln_gamma   = (const float*)d_in[13];
    const float* ln_beta    = (const float*)d_in[14];
    const float* read_route = (const float*)d_in[15];
    const float* read_proj  = (const float*)d_in[16];
    const float* read_gates = (const float*)d_in[17];
    float* out = (float*)d_out;

    // workspace carve
    float* p = (float*)d_ws;
    float* v0 = p;  p += (long)Bn * S0 * D;
    float* s0 = p;  p += Bn * S0;
    float* v1 = p;  p += (long)Bn * S1 * D;
    float* s1 = p;  p += Bn * S1;
    float* v2 = p;  p += (long)Bn * S2 * D;
    float* s2 = p;  p += Bn * S2;
    float* qb = p;  p += (long)Bn * T * R;
    float* kb = p;  p += (long)Bn * S0 * R;
    float* lb = p;  p += (long)Bn * T * S0;
    float* cb = p;  p += (long)Bn * T * 16;
    int*   ib = (int*)p; p += (long)Bn * T * 16;
    float* dvb = p; p += (long)Bn * S0 * D;
    float* dsb = p; p += Bn * S0;
    float* rb = p;  p += (long)Bn * T * D;
    int* cntb  = (int*)p; p += Bn * S0;
    int* curb  = (int*)p; p += Bn * S0;
    int* offsb = (int*)p; p += Bn * S0 + 1;
    int* elistb= (int*)p; p += (long)Bn * T * 16;
    unsigned short* projT = (unsigned short*)p; p += (3 * (long)D * D) / 2 + 4;
    // mvT reuses dvb (free during read phase): Bn*D*S0 bf16 = 4 MB <= 8 MB
    unsigned short* mvT = (unsigned short*)dvb;

    auto trans = [&](const float* sv, const float* ss, const float* dval,
                     const float* W, int Ns, int Nd) {
        gemm_f32_kernel<false><<<dim3(Ns / 64, 1, Bn), 256, 0, stream>>>(
            sv, W, qb, Ns, R, D, (long)Ns * D, 0, (long)Ns * R, 1.f);
        gemm_f32_kernel<false><<<dim3(Nd / 64, 1, Bn), 256, 0, stream>>>(
            dval, W + RT, kb, Nd, R, D, (long)Nd * D, 0, (long)Nd * R, 1.f);
        gemm_f32_kernel<true><<<dim3(Ns / 64, Nd / 64, Bn), 256, 0, stream>>>(
            qb, kb, lb, Ns, Nd, R, (long)Ns * R, (long)Nd * R, (long)Ns * Nd, 0.125f);
        if (Nd == 1024)
            topk_coeff_kernel<16><<<Bn * Ns, 64, 0, stream>>>(lb, ss, ib, cb, Nd);
        else if (Nd == 256)
            topk_coeff_kernel<4><<<Bn * Ns, 64, 0, stream>>>(lb, ss, ib, cb, Nd);
        else
            topk_coeff_kernel<1><<<Bn * Ns, 64, 0, stream>>>(lb, ss, ib, cb, Nd);
        int E = Bn * Ns * 16;
        int nsShift = 31 - __builtin_clz((unsigned)Ns) + 4;
        hipMemsetAsync(cntb, 0, (size_t)2 * Bn * S0 * sizeof(int), stream);
        count_edges_kernel<<<(E + 255) / 256, 256, 0, stream>>>(ib, cntb, nsShift, Nd, E);
        scan_kernel<<<1, 256, 0, stream>>>(cntb, offsb, Bn * Nd);
        fill_edges_kernel<<<(E + 255) / 256, 256, 0, stream>>>(ib, offsb, curb, elistb,
                                                               nsShift, Nd, E);
        gather_dv_kernel<<<Bn * Nd, 256, 0, stream>>>(sv, cb, elistb, offsb, dvb, dsb,
                                                      nsShift);
    };
    auto apply = [&](const float* sin, float* sout, const float* vin, float* vout,
                     int Nd, int lvl, const float* gptr, int gidx) {
        apply_state_kernel<<<Bn, 256, 0, stream>>>(sin, dsb, sout, Nd, gptr, gidx);
        apply_ln_kernel<<<Bn * Nd, 256, 0, stream>>>(vin, dvb, vout,
            ln_gamma + lvl * D, ln_beta + lvl * D, gptr, gidx);
    };

    // ---- level 0 ----
    trans(tok_val, tok_state, mem_val0, write_route, T, S0);
    apply(mem_state0, s0, mem_val0, v0, S0, 0, nullptr, 0);
    trans(v0, s0, v0, prop_route + 0 * 2 * RT, S0, S0);
    apply(s0, s0, v0, v0, S0, 0, nullptr, 0);

    // ---- level 1 ----
    trans(v0, s0, mem_val1, level_route + 0 * 2 * RT, S0, S1);
    apply(mem_state1, s1, mem_val1, v1, S1, 1, nullptr, 0);
    trans(tok_val, tok_state, v1, skip_route + 0 * 2 * RT, T, S1);
    apply(s1, s1, v1, v1, S1, 1, skip_gates, 0);
    trans(v1, s1, v1, prop_route + 1 * 2 * RT, S1, S1);
    apply(s1, s1, v1, v1, S1, 1, nullptr, 0);

    // ---- level 2 ----
    trans(v1, s1, mem_val2, level_route + 1 * 2 * RT, S1, S2);
    apply(mem_state2, s2, mem_val2, v2, S2, 2, nullptr, 0);
    trans(v0, s0, v2, skip_route + 1 * 2 * RT, S0, S2);
    apply(s2, s2, v2, v2, S2, 2, skip_gates, 1);
    trans(v2, s2, v2, prop_route + 2 * 2 * RT, S2, S2);
    apply(s2, s2, v2, v2, S2, 2, nullptr, 0);

    // ---- read phase ----
    hipMemcpyAsync(out, tok_val, (size_t)Bn * T * D * sizeof(float),
                   hipMemcpyDeviceToDevice, stream);
    // read_proj^T (bf16), batched over the 3 levels
    transpose_bf16_kernel<<<dim3(D / 32, D / 32, 3), dim3(32, 8), 0, stream>>>(
        read_proj, projT, D, D, (long)D * D, (long)D * D);
    const float* mvs[3] = { v0, v1, v2 };
    const int nds[3] = { S0, S1, S2 };
    for (int l = 0; l < 3; ++l) {
        const float* mv = mvs[l];
        int Nd = nds[l];
        gemm_f32_kernel<false><<<dim3(T / 64, 1, Bn), 256, 0, stream>>>(
            tok_val, read_route + (long)l * 2 * RT, qb, T, R, D,
            (long)T * D, 0, (long)T * R, 1.f);
        gemm_f32_kernel<false><<<dim3(Nd / 64, 1, Bn), 256, 0, stream>>>(
            mv, read_route + (long)l * 2 * RT + RT, kb, Nd, R, D,
            (long)Nd * D, 0, (long)Nd * R, 1.f);
        gemm_f32_kernel<true><<<dim3(T / 64, Nd / 64, Bn), 256, 0, stream>>>(
            qb, kb, lb, T, Nd, R, (long)T * R, (long)Nd * R, (long)T * Nd, 0.125f);
        softmax_rows_kernel<<<Bn * T, 256, 0, stream>>>(lb, Nd);
        // mv^T (bf16): [Nd][D] -> [D][Nd]
        transpose_bf16_kernel<<<dim3(D / 32, Nd / 32, Bn), dim3(32, 8), 0, stream>>>(
            mv, mvT, Nd, D, (long)Nd * D, (long)D * Nd);
        // r = attn x mv  (MFMA: A=lb fp32, Bt=mvT bf16)
        gemm_mfma_kernel<<<dim3(T / 64, D / 64, Bn), 256, 0, stream>>>(
            lb, mvT, rb, T, D, Nd, (long)T * Nd, (long)D * Nd, (long)T * D,
            1.f, nullptr, 0, 0.f);
        // out += sigmoid(gate) * r x proj  (MFMA: Bt=projT, shared across batch)
        gemm_mfma_kernel<<<dim3(T / 64, D / 64, Bn), 256, 0, stream>>>(
            rb, projT + (long)l * D * D, out, T, D, D,
            (long)T * D, 0, (long)T * D, 1.f, read_gates, l, 1.f);
    }
}

// Round 5
// 1639.196 us; speedup vs baseline: 2.2494x; 1.1893x over previous
//
#include <hip/hip_runtime.h>
#include <math.h>

typedef __attribute__((ext_vector_type(8))) short short8;
typedef __attribute__((ext_vector_type(4))) float floatx4;

static __device__ __forceinline__ short f2bf(float f) {
    union { float f; unsigned u; } c; c.f = f;
    unsigned r = c.u + 0x7FFF + ((c.u >> 16) & 1);   // RNE
    return (short)(r >> 16);
}

// ---------------------------------------------------------------------------
// fp32 GEMM v2: C[b] = alpha * A[b](M,K) x B[b](K,N | N,K if TRANSB)
// 64x64 tile, 256 thr, 4x4 micro-tile, K-step 32. fp32-exact path (top-k).
// ---------------------------------------------------------------------------
template<bool TRANSB>
__launch_bounds__(256)
__global__ void gemm_f32_kernel(const float* __restrict__ A, const float* __restrict__ B,
                                float* __restrict__ C, int M, int N, int K,
                                long sA, long sB, long sC, float alpha)
{
    __shared__ float As[32][68];   // [k][m]
    __shared__ float Bs[32][68];   // [k][n]
    const float* Ab = A + (long)blockIdx.z * sA;
    const float* Bb = B + (long)blockIdx.z * sB;
    float* Cb = C + (long)blockIdx.z * sC;
    int m0 = blockIdx.x * 64, n0 = blockIdx.y * 64;
    int t = threadIdx.x;
    int tx = t & 15, ty = t >> 4;
    float acc[4][4] = {};

    for (int k0 = 0; k0 < K; k0 += 32) {
        {   // A: [m][k] -> As[k][m]
            int m = t >> 3;
            int kk = (t & 7) * 4;
#pragma unroll
            for (int h = 0; h < 2; ++h) {
                float4 v = *(const float4*)&Ab[(long)(m0 + m + 32 * h) * K + k0 + kk];
                As[kk + 0][m + 32 * h] = v.x; As[kk + 1][m + 32 * h] = v.y;
                As[kk + 2][m + 32 * h] = v.z; As[kk + 3][m + 32 * h] = v.w;
            }
        }
        if (!TRANSB) {
            int kk = t >> 3;
            int nn = (t & 7) * 8;
            float4 v0 = *(const float4*)&Bb[(long)(k0 + kk) * N + n0 + nn];
            float4 v1 = *(const float4*)&Bb[(long)(k0 + kk) * N + n0 + nn + 4];
            *(float4*)&Bs[kk][nn] = v0;
            *(float4*)&Bs[kk][nn + 4] = v1;
        } else {
            int n = t >> 3;
            int kk = (t & 7) * 4;
#pragma unroll
            for (int h = 0; h < 2; ++h) {
                float4 v = *(const float4*)&Bb[(long)(n0 + n + 32 * h) * K + k0 + kk];
                Bs[kk + 0][n + 32 * h] = v.x; Bs[kk + 1][n + 32 * h] = v.y;
                Bs[kk + 2][n + 32 * h] = v.z; Bs[kk + 3][n + 32 * h] = v.w;
            }
        }
        __syncthreads();
#pragma unroll 4
        for (int k = 0; k < 32; ++k) {
            float4 a = *(const float4*)&As[k][ty * 4];
            float4 b = *(const float4*)&Bs[k][tx * 4];
            float av[4] = { a.x, a.y, a.z, a.w };
            float bv[4] = { b.x, b.y, b.z, b.w };
#pragma unroll
            for (int i = 0; i < 4; ++i)
#pragma unroll
                for (int j = 0; j < 4; ++j) acc[i][j] += av[i] * bv[j];
        }
        __syncthreads();
    }
#pragma unroll
    for (int i = 0; i < 4; ++i) {
        float4 r;
        r.x = alpha * acc[i][0]; r.y = alpha * acc[i][1];
        r.z = alpha * acc[i][2]; r.w = alpha * acc[i][3];
        *(float4*)&Cb[(long)(m0 + ty * 4 + i) * N + n0 + tx * 4] = r;
    }
}

// ---------------------------------------------------------------------------
// bf16 MFMA GEMM: C[b](M,N) = alpha' * A[b](M,K,fp32) x Bt[b](N,K,bf16) + beta*C
// ---------------------------------------------------------------------------
__launch_bounds__(256)
__global__ void gemm_mfma_kernel(const float* __restrict__ A, const unsigned short* __restrict__ Bt,
                                 float* __restrict__ C, int M, int N, int K,
                                 long sA, long sBt, long sC,
                                 float alpha, const float* __restrict__ gate, int gateIdx,
                                 float beta)
{
    __shared__ short As[2048];
    __shared__ short Bs[2048];
    const float* Ab = A + (long)blockIdx.z * sA;
    const unsigned short* Bb = Bt + (long)blockIdx.z * sBt;
    float* Cb = C + (long)blockIdx.z * sC;
    int m0 = blockIdx.x * 64, n0 = blockIdx.y * 64;
    int t = threadIdx.x, wave = t >> 6, lane = t & 63;
    int sr = wave * 16 + (lane & 15);
    int sk = (lane >> 4) * 8;
    floatx4 acc[4] = {};

    for (int k0 = 0; k0 < K; k0 += 32) {
        const float* ap = &Ab[(long)(m0 + sr) * K + k0 + sk];
        float4 f0 = *(const float4*)ap;
        float4 f1 = *(const float4*)(ap + 4);
        short8 av;
        av[0] = f2bf(f0.x); av[1] = f2bf(f0.y); av[2] = f2bf(f0.z); av[3] = f2bf(f0.w);
        av[4] = f2bf(f1.x); av[5] = f2bf(f1.y); av[6] = f2bf(f1.z); av[7] = f2bf(f1.w);
        short8 bv = *(const short8*)&Bb[(long)(n0 + sr) * K + k0 + sk];
        ((short8*)As)[t] = av;
        ((short8*)Bs)[t] = bv;
        __syncthreads();
        short8 bf = ((short8*)Bs)[wave * 64 + lane];
#pragma unroll
        for (int mt = 0; mt < 4; ++mt) {
            short8 af = ((short8*)As)[mt * 64 + lane];
            acc[mt] = __builtin_amdgcn_mfma_f32_16x16x32_bf16(af, bf, acc[mt], 0, 0, 0);
        }
        __syncthreads();
    }
    float a = alpha;
    if (gate) a *= 1.f / (1.f + expf(-gate[gateIdx]));
    int col = n0 + wave * 16 + (lane & 15);
#pragma unroll
    for (int mt = 0; mt < 4; ++mt) {
#pragma unroll
        for (int r = 0; r < 4; ++r) {
            int row = m0 + mt * 16 + (lane >> 4) * 4 + r;
            long off = (long)row * N + col;
            float v = a * acc[mt][r];
            if (beta != 0.f) v += Cb[off];
            Cb[off] = v;
        }
    }
}

// ---------------------------------------------------------------------------
// Transpose + bf16 convert: out[c][r] = bf16(in[r][c]).
// ---------------------------------------------------------------------------
__global__ void transpose_bf16_kernel(const float* __restrict__ in, unsigned short* __restrict__ out,
                                      int Rr, int Cc, long sIn, long sOut)
{
    __shared__ float tile[32][33];
    const float* I = in + (long)blockIdx.z * sIn;
    unsigned short* O = out + (long)blockIdx.z * sOut;
    int c0 = blockIdx.x * 32, r0 = blockIdx.y * 32;
    int tx = threadIdx.x, ty = threadIdx.y;
#pragma unroll
    for (int i = 0; i < 32; i += 8)
        tile[ty + i][tx] = I[(long)(r0 + ty + i) * Cc + c0 + tx];
    __syncthreads();
#pragma unroll
    for (int i = 0; i < 32; i += 8)
        O[(long)(c0 + ty + i) * Rr + r0 + tx] = (unsigned short)f2bf(tile[tx][ty + i]);
}

// ---------------------------------------------------------------------------
// Exact top-16 per row + edge-count accumulation (fused CSR count).
// ---------------------------------------------------------------------------
template<int CNT>
__launch_bounds__(64)
__global__ void topk_coeff_kernel(const float* __restrict__ logits,
                                  const float* __restrict__ state,
                                  int* __restrict__ idx_out, float* __restrict__ c_out,
                                  int* __restrict__ cnt, int nsLog, int Nd)
{
    long row = blockIdx.x;
    int lane = threadIdx.x;
    const float* L = logits + row * Nd;
    float vreg[CNT];
#pragma unroll
    for (int tt = 0; tt < CNT; ++tt) vreg[tt] = L[lane + (tt << 6)];

    float m = 0.f, sum = 0.f;
    float myv = 0.f; int myi = 0;
#pragma unroll
    for (int it = 0; it < 16; ++it) {
        float best = -INFINITY; int bidx = 0x7fffffff;
#pragma unroll
        for (int tt = 0; tt < CNT; ++tt) {
            if (vreg[tt] > best) { best = vreg[tt]; bidx = lane + (tt << 6); }
        }
#pragma unroll
        for (int off = 32; off; off >>= 1) {
            float ov = __shfl_down(best, off);
            int   oi = __shfl_down(bidx, off);
            if (ov > best || (ov == best && oi < bidx)) { best = ov; bidx = oi; }
        }
        best = __shfl(best, 0);
        bidx = __shfl(bidx, 0);
        if (it == lane) { myv = best; myi = bidx; }
        float ab = fabsf(best);
        float nm = fmaxf(m, ab);
        sum = sum * expf(m - nm) + expf(ab - nm);
        m = nm;
#pragma unroll
        for (int tt = 0; tt < CNT; ++tt)
            if (lane + (tt << 6) == bidx) vreg[tt] = -INFINITY;
    }
    if (lane < 16) {
        float st = state[row];
        float sp = fmaxf(st, 0.f) + log1pf(expf(-fabsf(st)));
        float sgn = (myv > 0.f) ? 1.f : ((myv < 0.f) ? -1.f : 0.f);
        float w = expf(fabsf(myv) - m) / sum;
        c_out[row * 16 + lane] = sgn * w * sp;
        idx_out[row * 16 + lane] = myi;
        int b = (int)(row >> nsLog);
        atomicAdd(&cnt[b * Nd + myi], 1);
    }
}

// Single-block exclusive scan over N entries (N multiple of 256, N <= 4096).
__launch_bounds__(256)
__global__ void scan_kernel(const int* __restrict__ cnt, int* __restrict__ offs, int N)
{
    __shared__ int sums[256];
    int t = threadIdx.x;
    int chunk = N >> 8;
    int base = t * chunk;
    int s = 0;
    for (int i = 0; i < chunk; ++i) s += cnt[base + i];
    sums[t] = s;
    __syncthreads();
    for (int off = 1; off < 256; off <<= 1) {
        int v = (t >= off) ? sums[t - off] : 0;
        __syncthreads();
        sums[t] += v;
        __syncthreads();
    }
    int run = sums[t] - s;
    for (int i = 0; i < chunk; ++i) {
        offs[base + i] = run;
        run += cnt[base + i];
    }
    if (t == 255) offs[N] = run;
}

__launch_bounds__(256)
__global__ void fill_edges_kernel(const int* __restrict__ idx, const int* __restrict__ offs,
                                  int* __restrict__ cursor, int* __restrict__ elist,
                                  int nsShift, int Nd, int E)
{
    int e = blockIdx.x * 256 + threadIdx.x;
    if (e >= E) return;
    int b = e >> nsShift;
    int d = b * Nd + idx[e];
    int pos = offs[d] + atomicAdd(&cursor[d], 1);
    elist[pos] = e;
}

// ---------------------------------------------------------------------------
// Gather dv[row] = sum_e c[e]*src[src_row(e)]; ds[row] = sum_e c[e].
// One block per dst row. Phase A: 256 threads resolve (c, src_row) for a
// chunk of <=512 edges into LDS (parallel, one latency round). Phase B: the
// 4 waves split the chunk's edges (stride-4, unroll 4), each wave covering
// the full 512-col row (8 floats/lane) -> ~16 src-row loads in flight.
// Phase C: LDS reduction of the 4 wave partials, one clean write.
// ---------------------------------------------------------------------------
#define ECHUNK 512
__launch_bounds__(256)
__global__ void gather_dv_kernel(const float* __restrict__ src_val, const float* __restrict__ c,
                                 const int* __restrict__ elist, const int* __restrict__ offs,
                                 float* __restrict__ dv, float* __restrict__ ds, int nsShift)
{
    __shared__ float sc[ECHUNK];
    __shared__ int   srow[ECHUNK];
    __shared__ float part[4][512];
    __shared__ float pcs[4];
    long row = blockIdx.x;
    int t = threadIdx.x, w = t >> 6, lane = t & 63;
    int e0 = offs[row], e1 = offs[row + 1];
    int mask = (1 << nsShift) - 1;
    int cb = lane * 8;                      // column base for this lane
    float a[8] = {};
    float cs = 0.f;

    for (int cstart = e0; cstart < e1; cstart += ECHUNK) {
        int cnt = min(e1 - cstart, ECHUNK);
        for (int i = t; i < cnt; i += 256) {
            int e = elist[cstart + i];
            sc[i] = c[e];
            int b = e >> nsShift;
            int s = (e & mask) >> 4;
            srow[i] = (b << (nsShift - 4)) + s;
        }
        __syncthreads();
        int j = w;
        for (; j + 12 < cnt; j += 16) {
            float c0 = sc[j], c1 = sc[j + 4], c2 = sc[j + 8], c3 = sc[j + 12];
            const float* p0 = src_val + ((long)srow[j]      << 9) + cb;
            const float* p1 = src_val + ((long)srow[j + 4]  << 9) + cb;
            const float* p2 = src_val + ((long)srow[j + 8]  << 9) + cb;
            const float* p3 = src_val + ((long)srow[j + 12] << 9) + cb;
            float4 x00 = *(const float4*)p0,       x01 = *(const float4*)(p0 + 4);
            float4 x10 = *(const float4*)p1,       x11 = *(const float4*)(p1 + 4);
            float4 x20 = *(const float4*)p2,       x21 = *(const float4*)(p2 + 4);
            float4 x30 = *(const float4*)p3,       x31 = *(const float4*)(p3 + 4);
            a[0] += c0 * x00.x + c1 * x10.x + c2 * x20.x + c3 * x30.x;
            a[1] += c0 * x00.y + c1 * x10.y + c2 * x20.y + c3 * x30.y;
            a[2] += c0 * x00.z + c1 * x10.z + c2 * x20.z + c3 * x30.z;
            a[3] += c0 * x00.w + c1 * x10.w + c2 * x20.w + c3 * x30.w;
            a[4] += c0 * x01.x + c1 * x11.x + c2 * x21.x + c3 * x31.x;
            a[5] += c0 * x01.y + c1 * x11.y + c2 * x21.y + c3 * x31.y;
            a[6] += c0 * x01.z + c1 * x11.z + c2 * x21.z + c3 * x31.z;
            a[7] += c0 * x01.w + c1 * x11.w + c2 * x21.w + c3 * x31.w;
            cs += c0 + c1 + c2 + c3;
        }
        for (; j < cnt; j += 4) {
            float cv = sc[j];
            const float* p = src_val + ((long)srow[j] << 9) + cb;
            float4 x0 = *(const float4*)p, x1 = *(const float4*)(p + 4);
            a[0] += cv * x0.x; a[1] += cv * x0.y; a[2] += cv * x0.z; a[3] += cv * x0.w;
            a[4] += cv * x1.x; a[5] += cv * x1.y; a[6] += cv * x1.z; a[7] += cv * x1.w;
            cs += cv;
        }
        __syncthreads();
    }
#pragma unroll
    for (int i = 0; i < 8; ++i) part[w][cb + i] = a[i];
    if (lane == 0) pcs[w] = cs;
    __syncthreads();
    float r0 = part[0][t] + part[1][t] + part[2][t] + part[3][t];
    float r1 = part[0][t + 256] + part[1][t + 256] + part[2][t + 256] + part[3][t + 256];
    dv[(row << 9) + t]       = r0;
    dv[(row << 9) + t + 256] = r1;
    if (t == 0) ds[row] = pcs[0] + pcs[1] + pcs[2] + pcs[3];
}

// ---------------------------------------------------------------------------
// state' = sign(x)*softmax(|x|), x = s + gate*ds. One block per batch.
// ---------------------------------------------------------------------------
__launch_bounds__(256)
__global__ void apply_state_kernel(const float* __restrict__ s_in, const float* __restrict__ ds,
                                   float* __restrict__ s_out, int Nd,
                                   const float* __restrict__ gatePtr, int gateIdx)
{
    __shared__ float sh[1024];
    __shared__ float red[4];
    int b = blockIdx.x, t = threadIdx.x;
    float gate = 1.f;
    if (gatePtr) gate = 1.f / (1.f + expf(-gatePtr[gateIdx]));
    float lmax = 0.f;
    for (int i = t; i < Nd; i += 256) {
        float x = s_in[b * Nd + i] + gate * ds[b * Nd + i];
        sh[i] = x;
        lmax = fmaxf(lmax, fabsf(x));
    }
    for (int off = 32; off; off >>= 1) lmax = fmaxf(lmax, __shfl_down(lmax, off));
    if ((t & 63) == 0) red[t >> 6] = lmax;
    __syncthreads();
    float bmax = fmaxf(fmaxf(red[0], red[1]), fmaxf(red[2], red[3]));
    float lsum = 0.f;
    for (int i = t; i < Nd; i += 256) lsum += expf(fabsf(sh[i]) - bmax);
    for (int off = 32; off; off >>= 1) lsum += __shfl_down(lsum, off);
    __syncthreads();
    if ((t & 63) == 0) red[t >> 6] = lsum;
    __syncthreads();
    float inv = 1.f / (red[0] + red[1] + red[2] + red[3]);
    for (int i = t; i < Nd; i += 256) {
        float x = sh[i];
        float sgn = (x > 0.f) ? 1.f : ((x < 0.f) ? -1.f : 0.f);
        s_out[b * Nd + i] = sgn * expf(fabsf(x) - bmax) * inv;
    }
}

// ---------------------------------------------------------------------------
// val' = LayerNorm(v + gate*dv) * gamma + beta.
// ---------------------------------------------------------------------------
__launch_bounds__(256)
__global__ void apply_ln_kernel(const float* __restrict__ v_in, const float* __restrict__ dv,
                                float* __restrict__ v_out, const float* __restrict__ gamma,
                                const float* __restrict__ beta,
                                const float* __restrict__ gatePtr, int gateIdx)
{
    __shared__ float red[4];
    long row = blockIdx.x;
    int t = threadIdx.x;
    float gate = 1.f;
    if (gatePtr) gate = 1.f / (1.f + expf(-gatePtr[gateIdx]));
    const float* vi  = v_in + (row << 9);
    const float* dvi = dv   + (row << 9);
    float x0 = vi[t]       + gate * dvi[t];
    float x1 = vi[t + 256] + gate * dvi[t + 256];
    float s = x0 + x1;
    for (int off = 32; off; off >>= 1) s += __shfl_down(s, off);
    if ((t & 63) == 0) red[t >> 6] = s;
    __syncthreads();
    float mean = (red[0] + red[1] + red[2] + red[3]) * (1.f / 512.f);
    float d0 = x0 - mean, d1 = x1 - mean;
    float ss = d0 * d0 + d1 * d1;
    for (int off = 32; off; off >>= 1) ss += __shfl_down(ss, off);
    __syncthreads();
    if ((t & 63) == 0) red[t >> 6] = ss;
    __syncthreads();
    float var = (red[0] + red[1] + red[2] + red[3]) * (1.f / 512.f);
    float rstd = rsqrtf(var + 1e-5f);
    float* vo = v_out + (row << 9);
    vo[t]       = d0 * rstd * gamma[t]       + beta[t];
    vo[t + 256] = d1 * rstd * gamma[t + 256] + beta[t + 256];
}

// ---------------------------------------------------------------------------
// Plain softmax over rows, in place.
// ---------------------------------------------------------------------------
__launch_bounds__(256)
__global__ void softmax_rows_kernel(float* __restrict__ logits, int Nd)
{
    __shared__ float red[4];
    long row = blockIdx.x;
    int t = threadIdx.x;
    float* L = logits + row * (long)Nd;
    float lmax = -INFINITY;
    for (int i = t; i < Nd; i += 256) lmax = fmaxf(lmax, L[i]);
    for (int off = 32; off; off >>= 1) lmax = fmaxf(lmax, __shfl_down(lmax, off));
    if ((t & 63) == 0) red[t >> 6] = lmax;
    __syncthreads();
    float bmax = fmaxf(fmaxf(red[0], red[1]), fmaxf(red[2], red[3]));
    float lsum = 0.f;
    for (int i = t; i < Nd; i += 256) lsum += expf(L[i] - bmax);
    for (int off = 32; off; off >>= 1) lsum += __shfl_down(lsum, off);
    __syncthreads();
    if ((t & 63) == 0) red[t >> 6] = lsum;
    __syncthreads();
    float inv = 1.f / (red[0] + red[1] + red[2] + red[3]);
    for (int i = t; i < Nd; i += 256) L[i] = expf(L[i] - bmax) * inv;
}

// ---------------------------------------------------------------------------
extern "C" void kernel_launch(void* const* d_in, const int* in_sizes, int n_in,
                              void* d_out, int out_size, void* d_ws, size_t ws_size,
                              hipStream_t stream)
{
    const int Bn = 4, T = 1024, D = 512, R = 64;
    const int S0 = 1024, S1 = 256, S2 = 64;
    const long RT = (long)D * R;

    const float* tok_val    = (const float*)d_in[0];
    const float* tok_state  = (const float*)d_in[1];
    const float* mem_state0 = (const float*)d_in[2];
    const float* mem_val0   = (const float*)d_in[3];
    const float* mem_state1 = (const float*)d_in[4];
    const float* mem_val1   = (const float*)d_in[5];
    const float* mem_state2 = (const float*)d_in[6];
    const float* mem_val2   = (const float*)d_in[7];
    const float* write_route= (const float*)d_in[8];
    const float* prop_route = (const float*)d_in[9];
    const float* level_route= (const float*)d_in[10];
    const float* skip_route = (const float*)d_in[11];
    const float* skip_gates = (const float*)d_in[12];
    const float* ln_gamma   = (const float*)d_in[13];
    const float* ln_beta    = (const float*)d_in[14];
    const float* read_route = (const float*)d_in[15];
    const float* read_proj  = (const float*)d_in[16];
    const float* read_gates = (const float*)d_in[17];
    float* out = (float*)d_out;

    // workspace carve
    float* p = (float*)d_ws;
    float* v0 = p;  p += (long)Bn * S0 * D;
    float* s0 = p;  p += Bn * S0;
    float* v1 = p;  p += (long)Bn * S1 * D;
    float* s1 = p;  p += Bn * S1;
    float* v2 = p;  p += (long)Bn * S2 * D;
    float* s2 = p;  p += Bn * S2;
    float* qb = p;  p += (long)Bn * T * R;
    float* kb = p;  p += (long)Bn * S0 * R;
    float* lb = p;  p += (long)Bn * T * S0;
    float* cb = p;  p += (long)Bn * T * 16;
    int*   ib = (int*)p; p += (long)Bn * T * 16;
    float* dvb = p; p += (long)Bn * S0 * D;
    float* dsb = p; p += Bn * S0;
    float* rb = p;  p += (long)Bn * T * D;
    int* cntb  = (int*)p; p += Bn * S0;
    int* curb  = (int*)p; p += Bn * S0;
    int* offsb = (int*)p; p += Bn * S0 + 1;
    int* elistb= (int*)p; p += (long)Bn * T * 16;
    unsigned short* projT = (unsigned short*)p; p += (3 * (long)D * D) / 2 + 4;
    unsigned short* mvT = (unsigned short*)dvb;   // reuse dvb in read phase

    auto trans = [&](const float* sv, const float* ss, const float* dval,
                     const float* W, int Ns, int Nd) {
        gemm_f32_kernel<false><<<dim3(Ns / 64, 1, Bn), 256, 0, stream>>>(
            sv, W, qb, Ns, R, D, (long)Ns * D, 0, (long)Ns * R, 1.f);
        gemm_f32_kernel<false><<<dim3(Nd / 64, 1, Bn), 256, 0, stream>>>(
            dval, W + RT, kb, Nd, R, D, (long)Nd * D, 0, (long)Nd * R, 1.f);
        gemm_f32_kernel<true><<<dim3(Ns / 64, Nd / 64, Bn), 256, 0, stream>>>(
            qb, kb, lb, Ns, Nd, R, (long)Ns * R, (long)Nd * R, (long)Ns * Nd, 0.125f);
        int nsLog = 31 - __builtin_clz((unsigned)Ns);
        int nsShift = nsLog + 4;
        hipMemsetAsync(cntb, 0, (size_t)2 * Bn * S0 * sizeof(int), stream); // cnt+cursor
        if (Nd == 1024)
            topk_coeff_kernel<16><<<Bn * Ns, 64, 0, stream>>>(lb, ss, ib, cb, cntb, nsLog, Nd);
        else if (Nd == 256)
            topk_coeff_kernel<4><<<Bn * Ns, 64, 0, stream>>>(lb, ss, ib, cb, cntb, nsLog, Nd);
        else
            topk_coeff_kernel<1><<<Bn * Ns, 64, 0, stream>>>(lb, ss, ib, cb, cntb, nsLog, Nd);
        int E = Bn * Ns * 16;
        scan_kernel<<<1, 256, 0, stream>>>(cntb, offsb, Bn * Nd);
        fill_edges_kernel<<<(E + 255) / 256, 256, 0, stream>>>(ib, offsb, curb, elistb,
                                                               nsShift, Nd, E);
        gather_dv_kernel<<<Bn * Nd, 256, 0, stream>>>(sv, cb, elistb, offsb, dvb, dsb,
                                                      nsShift);
    };
    auto apply = [&](const float* sin, float* sout, const float* vin, float* vout,
                     int Nd, int lvl, const float* gptr, int gidx) {
        apply_state_kernel<<<Bn, 256, 0, stream>>>(sin, dsb, sout, Nd, gptr, gidx);
        apply_ln_kernel<<<Bn * Nd, 256, 0, stream>>>(vin, dvb, vout,
            ln_gamma + lvl * D, ln_beta + lvl * D, gptr, gidx);
    };

    // ---- level 0 ----
    trans(tok_val, tok_state, mem_val0, write_route, T, S0);
    apply(mem_state0, s0, mem_val0, v0, S0, 0, nullptr, 0);
    trans(v0, s0, v0, prop_route + 0 * 2 * RT, S0, S0);
    apply(s0, s0, v0, v0, S0, 0, nullptr, 0);

    // ---- level 1 ----
    trans(v0, s0, mem_val1, level_route + 0 * 2 * RT, S0, S1);
    apply(mem_state1, s1, mem_val1, v1, S1, 1, nullptr, 0);
    trans(tok_val, tok_state, v1, skip_route + 0 * 2 * RT, T, S1);
    apply(s1, s1, v1, v1, S1, 1, skip_gates, 0);
    trans(v1, s1, v1, prop_route + 1 * 2 * RT, S1, S1);
    apply(s1, s1, v1, v1, S1, 1, nullptr, 0);

    // ---- level 2 ----
    trans(v1, s1, mem_val2, level_route + 1 * 2 * RT, S1, S2);
    apply(mem_state2, s2, mem_val2, v2, S2, 2, nullptr, 0);
    trans(v0, s0, v2, skip_route + 1 * 2 * RT, S0, S2);
    apply(s2, s2, v2, v2, S2, 2, skip_gates, 1);
    trans(v2, s2, v2, prop_route + 2 * 2 * RT, S2, S2);
    apply(s2, s2, v2, v2, S2, 2, nullptr, 0);

    // ---- read phase ----
    hipMemcpyAsync(out, tok_val, (size_t)Bn * T * D * sizeof(float),
                   hipMemcpyDeviceToDevice, stream);
    transpose_bf16_kernel<<<dim3(D / 32, D / 32, 3), dim3(32, 8), 0, stream>>>(
        read_proj, projT, D, D, (long)D * D, (long)D * D);
    const float* mvs[3] = { v0, v1, v2 };
    const int nds[3] = { S0, S1, S2 };
    for (int l = 0; l < 3; ++l) {
        const float* mv = mvs[l];
        int Nd = nds[l];
        gemm_f32_kernel<false><<<dim3(T / 64, 1, Bn), 256, 0, stream>>>(
            tok_val, read_route + (long)l * 2 * RT, qb, T, R, D,
            (long)T * D, 0, (long)T * R, 1.f);
        gemm_f32_kernel<false><<<dim3(Nd / 64, 1, Bn), 256, 0, stream>>>(
            mv, read_route + (long)l * 2 * RT + RT, kb, Nd, R, D,
            (long)Nd * D, 0, (long)Nd * R, 1.f);
        gemm_f32_kernel<true><<<dim3(T / 64, Nd / 64, Bn), 256, 0, stream>>>(
            qb, kb, lb, T, Nd, R, (long)T * R, (long)Nd * R, (long)T * Nd, 0.125f);
        softmax_rows_kernel<<<Bn * T, 256, 0, stream>>>(lb, Nd);
        transpose_bf16_kernel<<<dim3(D / 32, Nd / 32, Bn), dim3(32, 8), 0, stream>>>(
            mv, mvT, Nd, D, (long)Nd * D, (long)D * Nd);
        gemm_mfma_kernel<<<dim3(T / 64, D / 64, Bn), 256, 0, stream>>>(
            lb, mvT, rb, T, D, Nd, (long)T * Nd, (long)D * Nd, (long)T * D,
            1.f, nullptr, 0, 0.f);
        gemm_mfma_kernel<<<dim3(T / 64, D / 64, Bn), 256, 0, stream>>>(
            rb, projT + (long)l * D * D, out, T, D, D,
            (long)T * D, 0, (long)T * D, 1.f, read_gates, l, 1.f);
    }
}

// Round 6
// 1004.164 us; speedup vs baseline: 3.6719x; 1.6324x over previous
//
#include <hip/hip_runtime.h>
#include <math.h>

typedef __attribute__((ext_vector_type(8))) short short8;
typedef __attribute__((ext_vector_type(4))) float floatx4;

static __device__ __forceinline__ short f2bf(float f) {
    union { float f; unsigned u; } c; c.f = f;
    unsigned r = c.u + 0x7FFF + ((c.u >> 16) & 1);   // RNE
    return (short)(r >> 16);
}

// ---------------------------------------------------------------------------
// fp32 GEMM v2: C[b] = alpha * A[b](M,K) x B[b](K,N | N,K if TRANSB)
// 64x64 tile, 256 thr, 4x4 micro-tile, K-step 32. fp32-exact path (logits).
// ---------------------------------------------------------------------------
template<bool TRANSB>
__launch_bounds__(256)
__global__ void gemm_f32_kernel(const float* __restrict__ A, const float* __restrict__ B,
                                float* __restrict__ C, int M, int N, int K,
                                long sA, long sB, long sC, float alpha)
{
    __shared__ float As[32][68];   // [k][m]
    __shared__ float Bs[32][68];   // [k][n]
    const float* Ab = A + (long)blockIdx.z * sA;
    const float* Bb = B + (long)blockIdx.z * sB;
    float* Cb = C + (long)blockIdx.z * sC;
    int m0 = blockIdx.x * 64, n0 = blockIdx.y * 64;
    int t = threadIdx.x;
    int tx = t & 15, ty = t >> 4;
    float acc[4][4] = {};

    for (int k0 = 0; k0 < K; k0 += 32) {
        {   // A: [m][k] -> As[k][m]
            int m = t >> 3;
            int kk = (t & 7) * 4;
#pragma unroll
            for (int h = 0; h < 2; ++h) {
                float4 v = *(const float4*)&Ab[(long)(m0 + m + 32 * h) * K + k0 + kk];
                As[kk + 0][m + 32 * h] = v.x; As[kk + 1][m + 32 * h] = v.y;
                As[kk + 2][m + 32 * h] = v.z; As[kk + 3][m + 32 * h] = v.w;
            }
        }
        if (!TRANSB) {
            int kk = t >> 3;
            int nn = (t & 7) * 8;
            float4 v0 = *(const float4*)&Bb[(long)(k0 + kk) * N + n0 + nn];
            float4 v1 = *(const float4*)&Bb[(long)(k0 + kk) * N + n0 + nn + 4];
            *(float4*)&Bs[kk][nn] = v0;
            *(float4*)&Bs[kk][nn + 4] = v1;
        } else {
            int n = t >> 3;
            int kk = (t & 7) * 4;
#pragma unroll
            for (int h = 0; h < 2; ++h) {
                float4 v = *(const float4*)&Bb[(long)(n0 + n + 32 * h) * K + k0 + kk];
                Bs[kk + 0][n + 32 * h] = v.x; Bs[kk + 1][n + 32 * h] = v.y;
                Bs[kk + 2][n + 32 * h] = v.z; Bs[kk + 3][n + 32 * h] = v.w;
            }
        }
        __syncthreads();
#pragma unroll 4
        for (int k = 0; k < 32; ++k) {
            float4 a = *(const float4*)&As[k][ty * 4];
            float4 b = *(const float4*)&Bs[k][tx * 4];
            float av[4] = { a.x, a.y, a.z, a.w };
            float bv[4] = { b.x, b.y, b.z, b.w };
#pragma unroll
            for (int i = 0; i < 4; ++i)
#pragma unroll
                for (int j = 0; j < 4; ++j) acc[i][j] += av[i] * bv[j];
        }
        __syncthreads();
    }
#pragma unroll
    for (int i = 0; i < 4; ++i) {
        float4 r;
        r.x = alpha * acc[i][0]; r.y = alpha * acc[i][1];
        r.z = alpha * acc[i][2]; r.w = alpha * acc[i][3];
        *(float4*)&Cb[(long)(m0 + ty * 4 + i) * N + n0 + tx * 4] = r;
    }
}

// ---------------------------------------------------------------------------
// Split-K q/k projection, fused: computes partials for BOTH
//   q = Aq(Mq,512) x Wq(512,64)  and  k = Ak(Mk,512) x Wk(512,64)
// grid: ( (Mq+Mk)/64, 8, Bn ), block 256, each block one 64x64 tile over a
// 64-wide K slice. part[((s*Bn+b)*(Mq+Mk)+row)*64+c]. Deterministic reduce after.
// ---------------------------------------------------------------------------
__launch_bounds__(256)
__global__ void proj_splitk_kernel(const float* __restrict__ Aq, const float* __restrict__ Ak,
                                   const float* __restrict__ Wq, const float* __restrict__ Wk,
                                   float* __restrict__ part,
                                   int Mq, int Mk, long sAq, long sAk, int Bn)
{
    __shared__ float As[32][68];   // [k][m]
    __shared__ float Bs[32][68];   // [k][c] (64 cols used)
    int mqT = Mq >> 6;
    int xt = blockIdx.x, s = blockIdx.y, b = blockIdx.z;
    const float* A; const float* W; int row0, orow;
    if (xt < mqT) { A = Aq + (long)b * sAq; W = Wq; row0 = xt * 64; orow = row0; }
    else { A = Ak + (long)b * sAk; W = Wk; row0 = (xt - mqT) * 64; orow = Mq + row0; }
    int t = threadIdx.x, tx = t & 15, ty = t >> 4;
    float acc[4][4] = {};
    int kbase = s * 64;

    for (int k0 = kbase; k0 < kbase + 64; k0 += 32) {
        {
            int m = t >> 3;
            int kk = (t & 7) * 4;
#pragma unroll
            for (int h = 0; h < 2; ++h) {
                float4 v = *(const float4*)&A[(long)(row0 + m + 32 * h) * 512 + k0 + kk];
                As[kk + 0][m + 32 * h] = v.x; As[kk + 1][m + 32 * h] = v.y;
                As[kk + 2][m + 32 * h] = v.z; As[kk + 3][m + 32 * h] = v.w;
            }
        }
        {
            int kk = t >> 3;
            int nn = (t & 7) * 8;
            float4 v0 = *(const float4*)&W[(long)(k0 + kk) * 64 + nn];
            float4 v1 = *(const float4*)&W[(long)(k0 + kk) * 64 + nn + 4];
            *(float4*)&Bs[kk][nn] = v0;
            *(float4*)&Bs[kk][nn + 4] = v1;
        }
        __syncthreads();
#pragma unroll 4
        for (int k = 0; k < 32; ++k) {
            float4 a = *(const float4*)&As[k][ty * 4];
            float4 b2 = *(const float4*)&Bs[k][tx * 4];
            float av[4] = { a.x, a.y, a.z, a.w };
            float bv[4] = { b2.x, b2.y, b2.z, b2.w };
#pragma unroll
            for (int i = 0; i < 4; ++i)
#pragma unroll
                for (int j = 0; j < 4; ++j) acc[i][j] += av[i] * bv[j];
        }
        __syncthreads();
    }
    long base = ((long)(s * Bn + b) * (Mq + Mk) + orow) * 64;
#pragma unroll
    for (int i = 0; i < 4; ++i)
        *(float4*)&part[base + (long)(ty * 4 + i) * 64 + tx * 4] =
            make_float4(acc[i][0], acc[i][1], acc[i][2], acc[i][3]);
}

// Reduce 8 split-K partials -> qout (Mq rows) and kout (Mk rows). float4 lanes.
__launch_bounds__(256)
__global__ void proj_reduce_kernel(const float* __restrict__ part,
                                   float* __restrict__ qout, float* __restrict__ kout,
                                   int Mq, int Mk, int Bn)
{
    int idx = blockIdx.x * 256 + threadIdx.x;          // float4 index
    int size4b = (Mq + Mk) * 16;                       // float4 per batch
    int total4 = Bn * size4b;
    if (idx >= total4) return;
    const float4* p4 = (const float4*)part;
    long stride4 = (long)total4;
    float4 s = p4[idx];
#pragma unroll
    for (int ss = 1; ss < 8; ++ss) {
        float4 v = p4[ss * stride4 + idx];
        s.x += v.x; s.y += v.y; s.z += v.z; s.w += v.w;
    }
    int b = idx / size4b;
    int rem = idx - b * size4b;
    int r = rem >> 4;
    int c4 = rem & 15;
    if (r < Mq) ((float4*)qout)[((long)b * Mq + r) * 16 + c4] = s;
    else        ((float4*)kout)[((long)b * Mk + (r - Mq)) * 16 + c4] = s;
}

// ---------------------------------------------------------------------------
// bf16 MFMA GEMM: C[b](M,N) = alpha' * A[b](M,K,fp32) x Bt[b](N,K,bf16) + beta*C
// ---------------------------------------------------------------------------
__launch_bounds__(256)
__global__ void gemm_mfma_kernel(const float* __restrict__ A, const unsigned short* __restrict__ Bt,
                                 float* __restrict__ C, int M, int N, int K,
                                 long sA, long sBt, long sC,
                                 float alpha, const float* __restrict__ gate, int gateIdx,
                                 float beta)
{
    __shared__ short As[2048];
    __shared__ short Bs[2048];
    const float* Ab = A + (long)blockIdx.z * sA;
    const unsigned short* Bb = Bt + (long)blockIdx.z * sBt;
    float* Cb = C + (long)blockIdx.z * sC;
    int m0 = blockIdx.x * 64, n0 = blockIdx.y * 64;
    int t = threadIdx.x, wave = t >> 6, lane = t & 63;
    int sr = wave * 16 + (lane & 15);
    int sk = (lane >> 4) * 8;
    floatx4 acc[4] = {};

    for (int k0 = 0; k0 < K; k0 += 32) {
        const float* ap = &Ab[(long)(m0 + sr) * K + k0 + sk];
        float4 f0 = *(const float4*)ap;
        float4 f1 = *(const float4*)(ap + 4);
        short8 av;
        av[0] = f2bf(f0.x); av[1] = f2bf(f0.y); av[2] = f2bf(f0.z); av[3] = f2bf(f0.w);
        av[4] = f2bf(f1.x); av[5] = f2bf(f1.y); av[6] = f2bf(f1.z); av[7] = f2bf(f1.w);
        short8 bv = *(const short8*)&Bb[(long)(n0 + sr) * K + k0 + sk];
        ((short8*)As)[t] = av;
        ((short8*)Bs)[t] = bv;
        __syncthreads();
        short8 bf = ((short8*)Bs)[wave * 64 + lane];
#pragma unroll
        for (int mt = 0; mt < 4; ++mt) {
            short8 af = ((short8*)As)[mt * 64 + lane];
            acc[mt] = __builtin_amdgcn_mfma_f32_16x16x32_bf16(af, bf, acc[mt], 0, 0, 0);
        }
        __syncthreads();
    }
    float a = alpha;
    if (gate) a *= 1.f / (1.f + expf(-gate[gateIdx]));
    int col = n0 + wave * 16 + (lane & 15);
#pragma unroll
    for (int mt = 0; mt < 4; ++mt) {
#pragma unroll
        for (int r = 0; r < 4; ++r) {
            int row = m0 + mt * 16 + (lane >> 4) * 4 + r;
            long off = (long)row * N + col;
            float v = a * acc[mt][r];
            if (beta != 0.f) v += Cb[off];
            Cb[off] = v;
        }
    }
}

// ---------------------------------------------------------------------------
// Transpose + bf16 convert: out[c][r] = bf16(in[r][c]).
// ---------------------------------------------------------------------------
__global__ void transpose_bf16_kernel(const float* __restrict__ in, unsigned short* __restrict__ out,
                                      int Rr, int Cc, long sIn, long sOut)
{
    __shared__ float tile[32][33];
    const float* I = in + (long)blockIdx.z * sIn;
    unsigned short* O = out + (long)blockIdx.z * sOut;
    int c0 = blockIdx.x * 32, r0 = blockIdx.y * 32;
    int tx = threadIdx.x, ty = threadIdx.y;
#pragma unroll
    for (int i = 0; i < 32; i += 8)
        tile[ty + i][tx] = I[(long)(r0 + ty + i) * Cc + c0 + tx];
    __syncthreads();
#pragma unroll
    for (int i = 0; i < 32; i += 8)
        O[(long)(c0 + ty + i) * Rr + r0 + tx] = (unsigned short)f2bf(tile[tx][ty + i]);
}

// ---------------------------------------------------------------------------
// Exact top-16 per row + edge-count accumulation (fused CSR count).
// ---------------------------------------------------------------------------
template<int CNT>
__launch_bounds__(64)
__global__ void topk_coeff_kernel(const float* __restrict__ logits,
                                  const float* __restrict__ state,
                                  int* __restrict__ idx_out, float* __restrict__ c_out,
                                  int* __restrict__ cnt, int nsLog, int Nd)
{
    long row = blockIdx.x;
    int lane = threadIdx.x;
    const float* L = logits + row * Nd;
    float vreg[CNT];
#pragma unroll
    for (int tt = 0; tt < CNT; ++tt) vreg[tt] = L[lane + (tt << 6)];

    float m = 0.f, sum = 0.f;
    float myv = 0.f; int myi = 0;
#pragma unroll
    for (int it = 0; it < 16; ++it) {
        float best = -INFINITY; int bidx = 0x7fffffff;
#pragma unroll
        for (int tt = 0; tt < CNT; ++tt) {
            if (vreg[tt] > best) { best = vreg[tt]; bidx = lane + (tt << 6); }
        }
#pragma unroll
        for (int off = 32; off; off >>= 1) {
            float ov = __shfl_down(best, off);
            int   oi = __shfl_down(bidx, off);
            if (ov > best || (ov == best && oi < bidx)) { best = ov; bidx = oi; }
        }
        best = __shfl(best, 0);
        bidx = __shfl(bidx, 0);
        if (it == lane) { myv = best; myi = bidx; }
        float ab = fabsf(best);
        float nm = fmaxf(m, ab);
        sum = sum * expf(m - nm) + expf(ab - nm);
        m = nm;
#pragma unroll
        for (int tt = 0; tt < CNT; ++tt)
            if (lane + (tt << 6) == bidx) vreg[tt] = -INFINITY;
    }
    if (lane < 16) {
        float st = state[row];
        float sp = fmaxf(st, 0.f) + log1pf(expf(-fabsf(st)));
        float sgn = (myv > 0.f) ? 1.f : ((myv < 0.f) ? -1.f : 0.f);
        float w = expf(fabsf(myv) - m) / sum;
        c_out[row * 16 + lane] = sgn * w * sp;
        idx_out[row * 16 + lane] = myi;
        int b = (int)(row >> nsLog);
        atomicAdd(&cnt[b * Nd + myi], 1);
    }
}

// Single-block exclusive scan over N entries (N multiple of 256, N <= 4096).
__launch_bounds__(256)
__global__ void scan_kernel(const int* __restrict__ cnt, int* __restrict__ offs, int N)
{
    __shared__ int sums[256];
    int t = threadIdx.x;
    int chunk = N >> 8;
    int base = t * chunk;
    int s = 0;
    for (int i = 0; i < chunk; ++i) s += cnt[base + i];
    sums[t] = s;
    __syncthreads();
    for (int off = 1; off < 256; off <<= 1) {
        int v = (t >= off) ? sums[t - off] : 0;
        __syncthreads();
        sums[t] += v;
        __syncthreads();
    }
    int run = sums[t] - s;
    for (int i = 0; i < chunk; ++i) {
        offs[base + i] = run;
        run += cnt[base + i];
    }
    if (t == 255) offs[N] = run;
}

__launch_bounds__(256)
__global__ void fill_edges_kernel(const int* __restrict__ idx, const int* __restrict__ offs,
                                  int* __restrict__ cursor, int* __restrict__ elist,
                                  int nsShift, int Nd, int E)
{
    int e = blockIdx.x * 256 + threadIdx.x;
    if (e >= E) return;
    int b = e >> nsShift;
    int d = b * Nd + idx[e];
    int pos = offs[d] + atomicAdd(&cursor[d], 1);
    elist[pos] = e;
}

// ---------------------------------------------------------------------------
// Gather dv[row] = sum_e c[e]*src[src_row(e)]; ds[row] = sum_e c[e].
// ---------------------------------------------------------------------------
#define ECHUNK 512
__launch_bounds__(256)
__global__ void gather_dv_kernel(const float* __restrict__ src_val, const float* __restrict__ c,
                                 const int* __restrict__ elist, const int* __restrict__ offs,
                                 float* __restrict__ dv, float* __restrict__ ds, int nsShift)
{
    __shared__ float sc[ECHUNK];
    __shared__ int   srow[ECHUNK];
    __shared__ float part[4][512];
    __shared__ float pcs[4];
    long row = blockIdx.x;
    int t = threadIdx.x, w = t >> 6, lane = t & 63;
    int e0 = offs[row], e1 = offs[row + 1];
    int mask = (1 << nsShift) - 1;
    int cb = lane * 8;
    float a[8] = {};
    float cs = 0.f;

    for (int cstart = e0; cstart < e1; cstart += ECHUNK) {
        int cnt = min(e1 - cstart, ECHUNK);
        for (int i = t; i < cnt; i += 256) {
            int e = elist[cstart + i];
            sc[i] = c[e];
            int b = e >> nsShift;
            int s = (e & mask) >> 4;
            srow[i] = (b << (nsShift - 4)) + s;
        }
        __syncthreads();
        int j = w;
        for (; j + 12 < cnt; j += 16) {
            float c0 = sc[j], c1 = sc[j + 4], c2 = sc[j + 8], c3 = sc[j + 12];
            const float* p0 = src_val + ((long)srow[j]      << 9) + cb;
            const float* p1 = src_val + ((long)srow[j + 4]  << 9) + cb;
            const float* p2 = src_val + ((long)srow[j + 8]  << 9) + cb;
            const float* p3 = src_val + ((long)srow[j + 12] << 9) + cb;
            float4 x00 = *(const float4*)p0,       x01 = *(const float4*)(p0 + 4);
            float4 x10 = *(const float4*)p1,       x11 = *(const float4*)(p1 + 4);
            float4 x20 = *(const float4*)p2,       x21 = *(const float4*)(p2 + 4);
            float4 x30 = *(const float4*)p3,       x31 = *(const float4*)(p3 + 4);
            a[0] += c0 * x00.x + c1 * x10.x + c2 * x20.x + c3 * x30.x;
            a[1] += c0 * x00.y + c1 * x10.y + c2 * x20.y + c3 * x30.y;
            a[2] += c0 * x00.z + c1 * x10.z + c2 * x20.z + c3 * x30.z;
            a[3] += c0 * x00.w + c1 * x10.w + c2 * x20.w + c3 * x30.w;
            a[4] += c0 * x01.x + c1 * x11.x + c2 * x21.x + c3 * x31.x;
            a[5] += c0 * x01.y + c1 * x11.y + c2 * x21.y + c3 * x31.y;
            a[6] += c0 * x01.z + c1 * x11.z + c2 * x21.z + c3 * x31.z;
            a[7] += c0 * x01.w + c1 * x11.w + c2 * x21.w + c3 * x31.w;
            cs += c0 + c1 + c2 + c3;
        }
        for (; j < cnt; j += 4) {
            float cv = sc[j];
            const float* p = src_val + ((long)srow[j] << 9) + cb;
            float4 x0 = *(const float4*)p, x1 = *(const float4*)(p + 4);
            a[0] += cv * x0.x; a[1] += cv * x0.y; a[2] += cv * x0.z; a[3] += cv * x0.w;
            a[4] += cv * x1.x; a[5] += cv * x1.y; a[6] += cv * x1.z; a[7] += cv * x1.w;
            cs += cv;
        }
        __syncthreads();
    }
#pragma unroll
    for (int i = 0; i < 8; ++i) part[w][cb + i] = a[i];
    if (lane == 0) pcs[w] = cs;
    __syncthreads();
    float r0 = part[0][t] + part[1][t] + part[2][t] + part[3][t];
    float r1 = part[0][t + 256] + part[1][t + 256] + part[2][t + 256] + part[3][t + 256];
    dv[(row << 9) + t]       = r0;
    dv[(row << 9) + t + 256] = r1;
    if (t == 0) ds[row] = pcs[0] + pcs[1] + pcs[2] + pcs[3];
}

// ---------------------------------------------------------------------------
// state' = sign(x)*softmax(|x|), x = s + gate*ds. One block per batch.
// ---------------------------------------------------------------------------
__launch_bounds__(256)
__global__ void apply_state_kernel(const float* __restrict__ s_in, const float* __restrict__ ds,
                                   float* __restrict__ s_out, int Nd,
                                   const float* __restrict__ gatePtr, int gateIdx)
{
    __shared__ float sh[1024];
    __shared__ float red[4];
    int b = blockIdx.x, t = threadIdx.x;
    float gate = 1.f;
    if (gatePtr) gate = 1.f / (1.f + expf(-gatePtr[gateIdx]));
    float lmax = 0.f;
    for (int i = t; i < Nd; i += 256) {
        float x = s_in[b * Nd + i] + gate * ds[b * Nd + i];
        sh[i] = x;
        lmax = fmaxf(lmax, fabsf(x));
    }
    for (int off = 32; off; off >>= 1) lmax = fmaxf(lmax, __shfl_down(lmax, off));
    if ((t & 63) == 0) red[t >> 6] = lmax;
    __syncthreads();
    float bmax = fmaxf(fmaxf(red[0], red[1]), fmaxf(red[2], red[3]));
    float lsum = 0.f;
    for (int i = t; i < Nd; i += 256) lsum += expf(fabsf(sh[i]) - bmax);
    for (int off = 32; off; off >>= 1) lsum += __shfl_down(lsum, off);
    __syncthreads();
    if ((t & 63) == 0) red[t >> 6] = lsum;
    __syncthreads();
    float inv = 1.f / (red[0] + red[1] + red[2] + red[3]);
    for (int i = t; i < Nd; i += 256) {
        float x = sh[i];
        float sgn = (x > 0.f) ? 1.f : ((x < 0.f) ? -1.f : 0.f);
        s_out[b * Nd + i] = sgn * expf(fabsf(x) - bmax) * inv;
    }
}

// ---------------------------------------------------------------------------
// val' = LayerNorm(v + gate*dv) * gamma + beta.
// ---------------------------------------------------------------------------
__launch_bounds__(256)
__global__ void apply_ln_kernel(const float* __restrict__ v_in, const float* __restrict__ dv,
                                float* __restrict__ v_out, const float* __restrict__ gamma,
                                const float* __restrict__ beta,
                                const float* __restrict__ gatePtr, int gateIdx)
{
    __shared__ float red[4];
    long row = blockIdx.x;
    int t = threadIdx.x;
    float gate = 1.f;
    if (gatePtr) gate = 1.f / (1.f + expf(-gatePtr[gateIdx]));
    const float* vi  = v_in + (row << 9);
    const float* dvi = dv   + (row << 9);
    float x0 = vi[t]       + gate * dvi[t];
    float x1 = vi[t + 256] + gate * dvi[t + 256];
    float s = x0 + x1;
    for (int off = 32; off; off >>= 1) s += __shfl_down(s, off);
    if ((t & 63) == 0) red[t >> 6] = s;
    __syncthreads();
    float mean = (red[0] + red[1] + red[2] + red[3]) * (1.f / 512.f);
    float d0 = x0 - mean, d1 = x1 - mean;
    float ss = d0 * d0 + d1 * d1;
    for (int off = 32; off; off >>= 1) ss += __shfl_down(ss, off);
    __syncthreads();
    if ((t & 63) == 0) red[t >> 6] = ss;
    __syncthreads();
    float var = (red[0] + red[1] + red[2] + red[3]) * (1.f / 512.f);
    float rstd = rsqrtf(var + 1e-5f);
    float* vo = v_out + (row << 9);
    vo[t]       = d0 * rstd * gamma[t]       + beta[t];
    vo[t + 256] = d1 * rstd * gamma[t + 256] + beta[t + 256];
}

// ---------------------------------------------------------------------------
// Plain softmax over rows, in place.
// ---------------------------------------------------------------------------
__launch_bounds__(256)
__global__ void softmax_rows_kernel(float* __restrict__ logits, int Nd)
{
    __shared__ float red[4];
    long row = blockIdx.x;
    int t = threadIdx.x;
    float* L = logits + row * (long)Nd;
    float lmax = -INFINITY;
    for (int i = t; i < Nd; i += 256) lmax = fmaxf(lmax, L[i]);
    for (int off = 32; off; off >>= 1) lmax = fmaxf(lmax, __shfl_down(lmax, off));
    if ((t & 63) == 0) red[t >> 6] = lmax;
    __syncthreads();
    float bmax = fmaxf(fmaxf(red[0], red[1]), fmaxf(red[2], red[3]));
    float lsum = 0.f;
    for (int i = t; i < Nd; i += 256) lsum += expf(L[i] - bmax);
    for (int off = 32; off; off >>= 1) lsum += __shfl_down(lsum, off);
    __syncthreads();
    if ((t & 63) == 0) red[t >> 6] = lsum;
    __syncthreads();
    float inv = 1.f / (red[0] + red[1] + red[2] + red[3]);
    for (int i = t; i < Nd; i += 256) L[i] = expf(L[i] - bmax) * inv;
}

// ---------------------------------------------------------------------------
extern "C" void kernel_launch(void* const* d_in, const int* in_sizes, int n_in,
                              void* d_out, int out_size, void* d_ws, size_t ws_size,
                              hipStream_t stream)
{
    const int Bn = 4, T = 1024, D = 512, R = 64;
    const int S0 = 1024, S1 = 256, S2 = 64;
    const long RT = (long)D * R;

    const float* tok_val    = (const float*)d_in[0];
    const float* tok_state  = (const float*)d_in[1];
    const float* mem_state0 = (const float*)d_in[2];
    const float* mem_val0   = (const float*)d_in[3];
    const float* mem_state1 = (const float*)d_in[4];
    const float* mem_val1   = (const float*)d_in[5];
    const float* mem_state2 = (const float*)d_in[6];
    const float* mem_val2   = (const float*)d_in[7];
    const float* write_route= (const float*)d_in[8];
    const float* prop_route = (const float*)d_in[9];
    const float* level_route= (const float*)d_in[10];
    const float* skip_route = (const float*)d_in[11];
    const float* skip_gates = (const float*)d_in[12];
    const float* ln_gamma   = (const float*)d_in[13];
    const float* ln_beta    = (const float*)d_in[14];
    const float* read_route = (const float*)d_in[15];
    const float* read_proj  = (const float*)d_in[16];
    const float* read_gates = (const float*)d_in[17];
    float* out = (float*)d_out;

    // workspace carve
    float* p = (float*)d_ws;
    float* v0 = p;  p += (long)Bn * S0 * D;
    float* s0 = p;  p += Bn * S0;
    float* v1 = p;  p += (long)Bn * S1 * D;
    float* s1 = p;  p += Bn * S1;
    float* v2 = p;  p += (long)Bn * S2 * D;
    float* s2 = p;  p += Bn * S2;
    float* qb = p;  p += (long)Bn * T * R;
    float* kb = p;  p += (long)Bn * S0 * R;
    float* lb = p;  p += (long)Bn * T * S0;
    float* cb = p;  p += (long)Bn * T * 16;
    int*   ib = (int*)p; p += (long)Bn * T * 16;
    float* dvb = p; p += (long)Bn * S0 * D;
    float* dsb = p; p += Bn * S0;
    float* rb = p;  p += (long)Bn * T * D;
    int* cntb  = (int*)p; p += Bn * S0;
    int* curb  = (int*)p; p += Bn * S0;
    int* offsb = (int*)p; p += Bn * S0 + 1;
    int* elistb= (int*)p; p += (long)Bn * T * 16;
    unsigned short* projT = (unsigned short*)p; p += (3 * (long)D * D) / 2 + 4;
    float* partb = p; p += 8L * Bn * (T + S0) * R;      // split-K partials (16.8 MB max)
    unsigned short* mvT = (unsigned short*)dvb;          // reuse dvb in read phase

    auto proj = [&](const float* Aq, const float* Ak, const float* Wq, const float* Wk,
                    int Mq, int Mk, long sAq, long sAk, float* qout, float* kout) {
        proj_splitk_kernel<<<dim3((Mq + Mk) / 64, 8, Bn), 256, 0, stream>>>(
            Aq, Ak, Wq, Wk, partb, Mq, Mk, sAq, sAk, Bn);
        int total4 = Bn * (Mq + Mk) * 16;
        proj_reduce_kernel<<<(total4 + 255) / 256, 256, 0, stream>>>(
            partb, qout, kout, Mq, Mk, Bn);
    };

    auto trans = [&](const float* sv, const float* ss, const float* dval,
                     const float* W, int Ns, int Nd) {
        proj(sv, dval, W, W + RT, Ns, Nd, (long)Ns * D, (long)Nd * D, qb, kb);
        gemm_f32_kernel<true><<<dim3(Ns / 64, Nd / 64, Bn), 256, 0, stream>>>(
            qb, kb, lb, Ns, Nd, R, (long)Ns * R, (long)Nd * R, (long)Ns * Nd, 0.125f);
        int nsLog = 31 - __builtin_clz((unsigned)Ns);
        int nsShift = nsLog + 4;
        hipMemsetAsync(cntb, 0, (size_t)2 * Bn * S0 * sizeof(int), stream); // cnt+cursor
        if (Nd == 1024)
            topk_coeff_kernel<16><<<Bn * Ns, 64, 0, stream>>>(lb, ss, ib, cb, cntb, nsLog, Nd);
        else if (Nd == 256)
            topk_coeff_kernel<4><<<Bn * Ns, 64, 0, stream>>>(lb, ss, ib, cb, cntb, nsLog, Nd);
        else
            topk_coeff_kernel<1><<<Bn * Ns, 64, 0, stream>>>(lb, ss, ib, cb, cntb, nsLog, Nd);
        int E = Bn * Ns * 16;
        scan_kernel<<<1, 256, 0, stream>>>(cntb, offsb, Bn * Nd);
        fill_edges_kernel<<<(E + 255) / 256, 256, 0, stream>>>(ib, offsb, curb, elistb,
                                                               nsShift, Nd, E);
        gather_dv_kernel<<<Bn * Nd, 256, 0, stream>>>(sv, cb, elistb, offsb, dvb, dsb,
                                                      nsShift);
    };
    auto apply = [&](const float* sin, float* sout, const float* vin, float* vout,
                     int Nd, int lvl, const float* gptr, int gidx) {
        apply_state_kernel<<<Bn, 256, 0, stream>>>(sin, dsb, sout, Nd, gptr, gidx);
        apply_ln_kernel<<<Bn * Nd, 256, 0, stream>>>(vin, dvb, vout,
            ln_gamma + lvl * D, ln_beta + lvl * D, gptr, gidx);
    };

    // ---- level 0 ----
    trans(tok_val, tok_state, mem_val0, write_route, T, S0);
    apply(mem_state0, s0, mem_val0, v0, S0, 0, nullptr, 0);
    trans(v0, s0, v0, prop_route + 0 * 2 * RT, S0, S0);
    apply(s0, s0, v0, v0, S0, 0, nullptr, 0);

    // ---- level 1 ----
    trans(v0, s0, mem_val1, level_route + 0 * 2 * RT, S0, S1);
    apply(mem_state1, s1, mem_val1, v1, S1, 1, nullptr, 0);
    trans(tok_val, tok_state, v1, skip_route + 0 * 2 * RT, T, S1);
    apply(s1, s1, v1, v1, S1, 1, skip_gates, 0);
    trans(v1, s1, v1, prop_route + 1 * 2 * RT, S1, S1);
    apply(s1, s1, v1, v1, S1, 1, nullptr, 0);

    // ---- level 2 ----
    trans(v1, s1, mem_val2, level_route + 1 * 2 * RT, S1, S2);
    apply(mem_state2, s2, mem_val2, v2, S2, 2, nullptr, 0);
    trans(v0, s0, v2, skip_route + 1 * 2 * RT, S0, S2);
    apply(s2, s2, v2, v2, S2, 2, skip_gates, 1);
    trans(v2, s2, v2, prop_route + 2 * 2 * RT, S2, S2);
    apply(s2, s2, v2, v2, S2, 2, nullptr, 0);

    // ---- read phase ----
    hipMemcpyAsync(out, tok_val, (size_t)Bn * T * D * sizeof(float),
                   hipMemcpyDeviceToDevice, stream);
    transpose_bf16_kernel<<<dim3(D / 32, D / 32, 3), dim3(32, 8), 0, stream>>>(
        read_proj, projT, D, D, (long)D * D, (long)D * D);
    const float* mvs[3] = { v0, v1, v2 };
    const int nds[3] = { S0, S1, S2 };
    for (int l = 0; l < 3; ++l) {
        const float* mv = mvs[l];
        int Nd = nds[l];
        proj(tok_val, mv, read_route + (long)l * 2 * RT, read_route + (long)l * 2 * RT + RT,
             T, Nd, (long)T * D, (long)Nd * D, qb, kb);
        gemm_f32_kernel<true><<<dim3(T / 64, Nd / 64, Bn), 256, 0, stream>>>(
            qb, kb, lb, T, Nd, R, (long)T * R, (long)Nd * R, (long)T * Nd, 0.125f);
        softmax_rows_kernel<<<Bn * T, 256, 0, stream>>>(lb, Nd);
        transpose_bf16_kernel<<<dim3(D / 32, Nd / 32, Bn), dim3(32, 8), 0, stream>>>(
            mv, mvT, Nd, D, (long)Nd * D, (long)D * Nd);
        gemm_mfma_kernel<<<dim3(T / 64, D / 64, Bn), 256, 0, stream>>>(
            lb, mvT, rb, T, D, Nd, (long)T * Nd, (long)D * Nd, (long)T * D,
            1.f, nullptr, 0, 0.f);
        gemm_mfma_kernel<<<dim3(T / 64, D / 64, Bn), 256, 0, stream>>>(
            rb, projT + (long)l * D * D, out, T, D, D,
            (long)T * D, 0, (long)T * D, 1.f, read_gates, l, 1.f);
    }
}

// Round 7
// 952.283 us; speedup vs baseline: 3.8719x; 1.0545x over previous
//
#include <hip/hip_runtime.h>
#include <math.h>

typedef __attribute__((ext_vector_type(8))) short short8;
typedef __attribute__((ext_vector_type(4))) float floatx4;

static __device__ __forceinline__ short f2bf(float f) {
    union { float f; unsigned u; } c; c.f = f;
    unsigned r = c.u + 0x7FFF + ((c.u >> 16) & 1);   // RNE
    return (short)(r >> 16);
}

// ---------------------------------------------------------------------------
// fp32 GEMM v2: C[b] = alpha * A[b](M,K) x B[b](K,N | N,K if TRANSB)
// 64x64 tile, 256 thr, 4x4 micro-tile, K-step 32. fp32-exact path (logits).
// ---------------------------------------------------------------------------
template<bool TRANSB>
__launch_bounds__(256)
__global__ void gemm_f32_kernel(const float* __restrict__ A, const float* __restrict__ B,
                                float* __restrict__ C, int M, int N, int K,
                                long sA, long sB, long sC, float alpha)
{
    __shared__ float As[32][68];   // [k][m]
    __shared__ float Bs[32][68];   // [k][n]
    const float* Ab = A + (long)blockIdx.z * sA;
    const float* Bb = B + (long)blockIdx.z * sB;
    float* Cb = C + (long)blockIdx.z * sC;
    int m0 = blockIdx.x * 64, n0 = blockIdx.y * 64;
    int t = threadIdx.x;
    int tx = t & 15, ty = t >> 4;
    float acc[4][4] = {};

    for (int k0 = 0; k0 < K; k0 += 32) {
        {   // A: [m][k] -> As[k][m]
            int m = t >> 3;
            int kk = (t & 7) * 4;
#pragma unroll
            for (int h = 0; h < 2; ++h) {
                float4 v = *(const float4*)&Ab[(long)(m0 + m + 32 * h) * K + k0 + kk];
                As[kk + 0][m + 32 * h] = v.x; As[kk + 1][m + 32 * h] = v.y;
                As[kk + 2][m + 32 * h] = v.z; As[kk + 3][m + 32 * h] = v.w;
            }
        }
        if (!TRANSB) {
            int kk = t >> 3;
            int nn = (t & 7) * 8;
            float4 v0 = *(const float4*)&Bb[(long)(k0 + kk) * N + n0 + nn];
            float4 v1 = *(const float4*)&Bb[(long)(k0 + kk) * N + n0 + nn + 4];
            *(float4*)&Bs[kk][nn] = v0;
            *(float4*)&Bs[kk][nn + 4] = v1;
        } else {
            int n = t >> 3;
            int kk = (t & 7) * 4;
#pragma unroll
            for (int h = 0; h < 2; ++h) {
                float4 v = *(const float4*)&Bb[(long)(n0 + n + 32 * h) * K + k0 + kk];
                Bs[kk + 0][n + 32 * h] = v.x; Bs[kk + 1][n + 32 * h] = v.y;
                Bs[kk + 2][n + 32 * h] = v.z; Bs[kk + 3][n + 32 * h] = v.w;
            }
        }
        __syncthreads();
#pragma unroll 4
        for (int k = 0; k < 32; ++k) {
            float4 a = *(const float4*)&As[k][ty * 4];
            float4 b = *(const float4*)&Bs[k][tx * 4];
            float av[4] = { a.x, a.y, a.z, a.w };
            float bv[4] = { b.x, b.y, b.z, b.w };
#pragma unroll
            for (int i = 0; i < 4; ++i)
#pragma unroll
                for (int j = 0; j < 4; ++j) acc[i][j] += av[i] * bv[j];
        }
        __syncthreads();
    }
#pragma unroll
    for (int i = 0; i < 4; ++i) {
        float4 r;
        r.x = alpha * acc[i][0]; r.y = alpha * acc[i][1];
        r.z = alpha * acc[i][2]; r.w = alpha * acc[i][3];
        *(float4*)&Cb[(long)(m0 + ty * 4 + i) * N + n0 + tx * 4] = r;
    }
}

// ---------------------------------------------------------------------------
// Split-K q/k projection, fused (q and k in one launch), partials + reduce.
// ---------------------------------------------------------------------------
__launch_bounds__(256)
__global__ void proj_splitk_kernel(const float* __restrict__ Aq, const float* __restrict__ Ak,
                                   const float* __restrict__ Wq, const float* __restrict__ Wk,
                                   float* __restrict__ part,
                                   int Mq, int Mk, long sAq, long sAk, int Bn)
{
    __shared__ float As[32][68];
    __shared__ float Bs[32][68];
    int mqT = Mq >> 6;
    int xt = blockIdx.x, s = blockIdx.y, b = blockIdx.z;
    const float* A; const float* W; int row0, orow;
    if (xt < mqT) { A = Aq + (long)b * sAq; W = Wq; row0 = xt * 64; orow = row0; }
    else { A = Ak + (long)b * sAk; W = Wk; row0 = (xt - mqT) * 64; orow = Mq + row0; }
    int t = threadIdx.x, tx = t & 15, ty = t >> 4;
    float acc[4][4] = {};
    int kbase = s * 64;

    for (int k0 = kbase; k0 < kbase + 64; k0 += 32) {
        {
            int m = t >> 3;
            int kk = (t & 7) * 4;
#pragma unroll
            for (int h = 0; h < 2; ++h) {
                float4 v = *(const float4*)&A[(long)(row0 + m + 32 * h) * 512 + k0 + kk];
                As[kk + 0][m + 32 * h] = v.x; As[kk + 1][m + 32 * h] = v.y;
                As[kk + 2][m + 32 * h] = v.z; As[kk + 3][m + 32 * h] = v.w;
            }
        }
        {
            int kk = t >> 3;
            int nn = (t & 7) * 8;
            float4 v0 = *(const float4*)&W[(long)(k0 + kk) * 64 + nn];
            float4 v1 = *(const float4*)&W[(long)(k0 + kk) * 64 + nn + 4];
            *(float4*)&Bs[kk][nn] = v0;
            *(float4*)&Bs[kk][nn + 4] = v1;
        }
        __syncthreads();
#pragma unroll 4
        for (int k = 0; k < 32; ++k) {
            float4 a = *(const float4*)&As[k][ty * 4];
            float4 b2 = *(const float4*)&Bs[k][tx * 4];
            float av[4] = { a.x, a.y, a.z, a.w };
            float bv[4] = { b2.x, b2.y, b2.z, b2.w };
#pragma unroll
            for (int i = 0; i < 4; ++i)
#pragma unroll
                for (int j = 0; j < 4; ++j) acc[i][j] += av[i] * bv[j];
        }
        __syncthreads();
    }
    long base = ((long)(s * Bn + b) * (Mq + Mk) + orow) * 64;
#pragma unroll
    for (int i = 0; i < 4; ++i)
        *(float4*)&part[base + (long)(ty * 4 + i) * 64 + tx * 4] =
            make_float4(acc[i][0], acc[i][1], acc[i][2], acc[i][3]);
}

__launch_bounds__(256)
__global__ void proj_reduce_kernel(const float* __restrict__ part,
                                   float* __restrict__ qout, float* __restrict__ kout,
                                   int Mq, int Mk, int Bn)
{
    int idx = blockIdx.x * 256 + threadIdx.x;
    int size4b = (Mq + Mk) * 16;
    int total4 = Bn * size4b;
    if (idx >= total4) return;
    const float4* p4 = (const float4*)part;
    long stride4 = (long)total4;
    float4 s = p4[idx];
#pragma unroll
    for (int ss = 1; ss < 8; ++ss) {
        float4 v = p4[ss * stride4 + idx];
        s.x += v.x; s.y += v.y; s.z += v.z; s.w += v.w;
    }
    int b = idx / size4b;
    int rem = idx - b * size4b;
    int r = rem >> 4;
    int c4 = rem & 15;
    if (r < Mq) ((float4*)qout)[((long)b * Mq + r) * 16 + c4] = s;
    else        ((float4*)kout)[((long)b * Mk + (r - Mq)) * 16 + c4] = s;
}

// ---------------------------------------------------------------------------
// bf16 MFMA GEMM: C[b](M,N) = alpha' * A[b](M,K,fp32) x Bt[b](N,K,bf16) + beta*C
// ---------------------------------------------------------------------------
__launch_bounds__(256)
__global__ void gemm_mfma_kernel(const float* __restrict__ A, const unsigned short* __restrict__ Bt,
                                 float* __restrict__ C, int M, int N, int K,
                                 long sA, long sBt, long sC,
                                 float alpha, const float* __restrict__ gate, int gateIdx,
                                 float beta)
{
    __shared__ short As[2048];
    __shared__ short Bs[2048];
    const float* Ab = A + (long)blockIdx.z * sA;
    const unsigned short* Bb = Bt + (long)blockIdx.z * sBt;
    float* Cb = C + (long)blockIdx.z * sC;
    int m0 = blockIdx.x * 64, n0 = blockIdx.y * 64;
    int t = threadIdx.x, wave = t >> 6, lane = t & 63;
    int sr = wave * 16 + (lane & 15);
    int sk = (lane >> 4) * 8;
    floatx4 acc[4] = {};

    for (int k0 = 0; k0 < K; k0 += 32) {
        const float* ap = &Ab[(long)(m0 + sr) * K + k0 + sk];
        float4 f0 = *(const float4*)ap;
        float4 f1 = *(const float4*)(ap + 4);
        short8 av;
        av[0] = f2bf(f0.x); av[1] = f2bf(f0.y); av[2] = f2bf(f0.z); av[3] = f2bf(f0.w);
        av[4] = f2bf(f1.x); av[5] = f2bf(f1.y); av[6] = f2bf(f1.z); av[7] = f2bf(f1.w);
        short8 bv = *(const short8*)&Bb[(long)(n0 + sr) * K + k0 + sk];
        ((short8*)As)[t] = av;
        ((short8*)Bs)[t] = bv;
        __syncthreads();
        short8 bf = ((short8*)Bs)[wave * 64 + lane];
#pragma unroll
        for (int mt = 0; mt < 4; ++mt) {
            short8 af = ((short8*)As)[mt * 64 + lane];
            acc[mt] = __builtin_amdgcn_mfma_f32_16x16x32_bf16(af, bf, acc[mt], 0, 0, 0);
        }
        __syncthreads();
    }
    float a = alpha;
    if (gate) a *= 1.f / (1.f + expf(-gate[gateIdx]));
    int col = n0 + wave * 16 + (lane & 15);
#pragma unroll
    for (int mt = 0; mt < 4; ++mt) {
#pragma unroll
        for (int r = 0; r < 4; ++r) {
            int row = m0 + mt * 16 + (lane >> 4) * 4 + r;
            long off = (long)row * N + col;
            float v = a * acc[mt][r];
            if (beta != 0.f) v += Cb[off];
            Cb[off] = v;
        }
    }
}

// ---------------------------------------------------------------------------
// Transpose + bf16 convert: out[c][r] = bf16(in[r][c]).
// ---------------------------------------------------------------------------
__global__ void transpose_bf16_kernel(const float* __restrict__ in, unsigned short* __restrict__ out,
                                      int Rr, int Cc, long sIn, long sOut)
{
    __shared__ float tile[32][33];
    const float* I = in + (long)blockIdx.z * sIn;
    unsigned short* O = out + (long)blockIdx.z * sOut;
    int c0 = blockIdx.x * 32, r0 = blockIdx.y * 32;
    int tx = threadIdx.x, ty = threadIdx.y;
#pragma unroll
    for (int i = 0; i < 32; i += 8)
        tile[ty + i][tx] = I[(long)(r0 + ty + i) * Cc + c0 + tx];
    __syncthreads();
#pragma unroll
    for (int i = 0; i < 32; i += 8)
        O[(long)(c0 + ty + i) * Rr + r0 + tx] = (unsigned short)f2bf(tile[tx][ty + i]);
}

// ---------------------------------------------------------------------------
// Exact top-16 per row + edge-count accumulation. v2:
//  - 256-thr blocks, 4 rows/block (one wave per row) -> ~2.5x occupancy
//  - lane owns CONTIGUOUS slice L[lane*CNT .. lane*CNT+CNT-1] -> float4 loads
//  Tie-break (lowest index) preserved: ascending-tt strict '>' within lane,
//  explicit (val,idx) compare in the butterfly across lanes.
// ---------------------------------------------------------------------------
template<int CNT>
__launch_bounds__(256)
__global__ void topk_coeff_kernel(const float* __restrict__ logits,
                                  const float* __restrict__ state,
                                  int* __restrict__ idx_out, float* __restrict__ c_out,
                                  int* __restrict__ cnt, int nsLog, int Nd)
{
    int wave = threadIdx.x >> 6, lane = threadIdx.x & 63;
    long row = (long)blockIdx.x * 4 + wave;
    const float* L = logits + row * Nd;
    float vreg[CNT];
    if (CNT >= 4) {
#pragma unroll
        for (int q = 0; q < CNT / 4; ++q) {
            float4 v = *(const float4*)&L[lane * CNT + q * 4];
            vreg[q * 4 + 0] = v.x; vreg[q * 4 + 1] = v.y;
            vreg[q * 4 + 2] = v.z; vreg[q * 4 + 3] = v.w;
        }
    } else {
#pragma unroll
        for (int tt = 0; tt < CNT; ++tt) vreg[tt] = L[lane * CNT + tt];
    }

    float m = 0.f, sum = 0.f;
    float myv = 0.f; int myi = 0;
#pragma unroll
    for (int it = 0; it < 16; ++it) {
        float best = -INFINITY; int bidx = 0x7fffffff;
#pragma unroll
        for (int tt = 0; tt < CNT; ++tt) {
            if (vreg[tt] > best) { best = vreg[tt]; bidx = lane * CNT + tt; }
        }
#pragma unroll
        for (int off = 32; off; off >>= 1) {
            float ov = __shfl_down(best, off);
            int   oi = __shfl_down(bidx, off);
            if (ov > best || (ov == best && oi < bidx)) { best = ov; bidx = oi; }
        }
        best = __shfl(best, 0);
        bidx = __shfl(bidx, 0);
        if (it == lane) { myv = best; myi = bidx; }
        float ab = fabsf(best);
        float nm = fmaxf(m, ab);
        sum = sum * expf(m - nm) + expf(ab - nm);
        m = nm;
#pragma unroll
        for (int tt = 0; tt < CNT; ++tt)
            if (lane * CNT + tt == bidx) vreg[tt] = -INFINITY;
    }
    if (lane < 16) {
        float st = state[row];
        float sp = fmaxf(st, 0.f) + log1pf(expf(-fabsf(st)));
        float sgn = (myv > 0.f) ? 1.f : ((myv < 0.f) ? -1.f : 0.f);
        float w = expf(fabsf(myv) - m) / sum;
        c_out[row * 16 + lane] = sgn * w * sp;
        idx_out[row * 16 + lane] = myi;
        int b = (int)(row >> nsLog);
        atomicAdd(&cnt[b * Nd + myi], 1);
    }
}

// Single-block exclusive scan over N entries (N multiple of 256, N <= 4096).
__launch_bounds__(256)
__global__ void scan_kernel(const int* __restrict__ cnt, int* __restrict__ offs, int N)
{
    __shared__ int sums[256];
    int t = threadIdx.x;
    int chunk = N >> 8;
    int base = t * chunk;
    int s = 0;
    for (int i = 0; i < chunk; ++i) s += cnt[base + i];
    sums[t] = s;
    __syncthreads();
    for (int off = 1; off < 256; off <<= 1) {
        int v = (t >= off) ? sums[t - off] : 0;
        __syncthreads();
        sums[t] += v;
        __syncthreads();
    }
    int run = sums[t] - s;
    for (int i = 0; i < chunk; ++i) {
        offs[base + i] = run;
        run += cnt[base + i];
    }
    if (t == 255) offs[N] = run;
}

__launch_bounds__(256)
__global__ void fill_edges_kernel(const int* __restrict__ idx, const int* __restrict__ offs,
                                  int* __restrict__ cursor, int* __restrict__ elist,
                                  int nsShift, int Nd, int E)
{
    int e = blockIdx.x * 256 + threadIdx.x;
    if (e >= E) return;
    int b = e >> nsShift;
    int d = b * Nd + idx[e];
    int pos = offs[d] + atomicAdd(&cursor[d], 1);
    elist[pos] = e;
}

// ---------------------------------------------------------------------------
// Gather dv[row] = sum_e c[e]*src[src_row(e)]; ds[row] = sum_e c[e].
// ---------------------------------------------------------------------------
#define ECHUNK 512
__launch_bounds__(256)
__global__ void gather_dv_kernel(const float* __restrict__ src_val, const float* __restrict__ c,
                                 const int* __restrict__ elist, const int* __restrict__ offs,
                                 float* __restrict__ dv, float* __restrict__ ds, int nsShift)
{
    __shared__ float sc[ECHUNK];
    __shared__ int   srow[ECHUNK];
    __shared__ float part[4][512];
    __shared__ float pcs[4];
    long row = blockIdx.x;
    int t = threadIdx.x, w = t >> 6, lane = t & 63;
    int e0 = offs[row], e1 = offs[row + 1];
    int mask = (1 << nsShift) - 1;
    int cb = lane * 8;
    float a[8] = {};
    float cs = 0.f;

    for (int cstart = e0; cstart < e1; cstart += ECHUNK) {
        int cnt = min(e1 - cstart, ECHUNK);
        for (int i = t; i < cnt; i += 256) {
            int e = elist[cstart + i];
            sc[i] = c[e];
            int b = e >> nsShift;
            int s = (e & mask) >> 4;
            srow[i] = (b << (nsShift - 4)) + s;
        }
        __syncthreads();
        int j = w;
        for (; j + 12 < cnt; j += 16) {
            float c0 = sc[j], c1 = sc[j + 4], c2 = sc[j + 8], c3 = sc[j + 12];
            const float* p0 = src_val + ((long)srow[j]      << 9) + cb;
            const float* p1 = src_val + ((long)srow[j + 4]  << 9) + cb;
            const float* p2 = src_val + ((long)srow[j + 8]  << 9) + cb;
            const float* p3 = src_val + ((long)srow[j + 12] << 9) + cb;
            float4 x00 = *(const float4*)p0,       x01 = *(const float4*)(p0 + 4);
            float4 x10 = *(const float4*)p1,       x11 = *(const float4*)(p1 + 4);
            float4 x20 = *(const float4*)p2,       x21 = *(const float4*)(p2 + 4);
            float4 x30 = *(const float4*)p3,       x31 = *(const float4*)(p3 + 4);
            a[0] += c0 * x00.x + c1 * x10.x + c2 * x20.x + c3 * x30.x;
            a[1] += c0 * x00.y + c1 * x10.y + c2 * x20.y + c3 * x30.y;
            a[2] += c0 * x00.z + c1 * x10.z + c2 * x20.z + c3 * x30.z;
            a[3] += c0 * x00.w + c1 * x10.w + c2 * x20.w + c3 * x30.w;
            a[4] += c0 * x01.x + c1 * x11.x + c2 * x21.x + c3 * x31.x;
            a[5] += c0 * x01.y + c1 * x11.y + c2 * x21.y + c3 * x31.y;
            a[6] += c0 * x01.z + c1 * x11.z + c2 * x21.z + c3 * x31.z;
            a[7] += c0 * x01.w + c1 * x11.w + c2 * x21.w + c3 * x31.w;
            cs += c0 + c1 + c2 + c3;
        }
        for (; j < cnt; j += 4) {
            float cv = sc[j];
            const float* p = src_val + ((long)srow[j] << 9) + cb;
            float4 x0 = *(const float4*)p, x1 = *(const float4*)(p + 4);
            a[0] += cv * x0.x; a[1] += cv * x0.y; a[2] += cv * x0.z; a[3] += cv * x0.w;
            a[4] += cv * x1.x; a[5] += cv * x1.y; a[6] += cv * x1.z; a[7] += cv * x1.w;
            cs += cv;
        }
        __syncthreads();
    }
#pragma unroll
    for (int i = 0; i < 8; ++i) part[w][cb + i] = a[i];
    if (lane == 0) pcs[w] = cs;
    __syncthreads();
    float r0 = part[0][t] + part[1][t] + part[2][t] + part[3][t];
    float r1 = part[0][t + 256] + part[1][t + 256] + part[2][t + 256] + part[3][t + 256];
    dv[(row << 9) + t]       = r0;
    dv[(row << 9) + t + 256] = r1;
    if (t == 0) ds[row] = pcs[0] + pcs[1] + pcs[2] + pcs[3];
}

// ---------------------------------------------------------------------------
// state' = sign(x)*softmax(|x|), x = s + gate*ds. One block per batch.
// ---------------------------------------------------------------------------
__launch_bounds__(256)
__global__ void apply_state_kernel(const float* __restrict__ s_in, const float* __restrict__ ds,
                                   float* __restrict__ s_out, int Nd,
                                   const float* __restrict__ gatePtr, int gateIdx)
{
    __shared__ float sh[1024];
    __shared__ float red[4];
    int b = blockIdx.x, t = threadIdx.x;
    float gate = 1.f;
    if (gatePtr) gate = 1.f / (1.f + expf(-gatePtr[gateIdx]));
    float lmax = 0.f;
    for (int i = t; i < Nd; i += 256) {
        float x = s_in[b * Nd + i] + gate * ds[b * Nd + i];
        sh[i] = x;
        lmax = fmaxf(lmax, fabsf(x));
    }
    for (int off = 32; off; off >>= 1) lmax = fmaxf(lmax, __shfl_down(lmax, off));
    if ((t & 63) == 0) red[t >> 6] = lmax;
    __syncthreads();
    float bmax = fmaxf(fmaxf(red[0], red[1]), fmaxf(red[2], red[3]));
    float lsum = 0.f;
    for (int i = t; i < Nd; i += 256) lsum += expf(fabsf(sh[i]) - bmax);
    for (int off = 32; off; off >>= 1) lsum += __shfl_down(lsum, off);
    __syncthreads();
    if ((t & 63) == 0) red[t >> 6] = lsum;
    __syncthreads();
    float inv = 1.f / (red[0] + red[1] + red[2] + red[3]);
    for (int i = t; i < Nd; i += 256) {
        float x = sh[i];
        float sgn = (x > 0.f) ? 1.f : ((x < 0.f) ? -1.f : 0.f);
        s_out[b * Nd + i] = sgn * expf(fabsf(x) - bmax) * inv;
    }
}

// ---------------------------------------------------------------------------
// val' = LayerNorm(v + gate*dv) * gamma + beta.
// ---------------------------------------------------------------------------
__launch_bounds__(256)
__global__ void apply_ln_kernel(const float* __restrict__ v_in, const float* __restrict__ dv,
                                float* __restrict__ v_out, const float* __restrict__ gamma,
                                const float* __restrict__ beta,
                                const float* __restrict__ gatePtr, int gateIdx)
{
    __shared__ float red[4];
    long row = blockIdx.x;
    int t = threadIdx.x;
    float gate = 1.f;
    if (gatePtr) gate = 1.f / (1.f + expf(-gatePtr[gateIdx]));
    const float* vi  = v_in + (row << 9);
    const float* dvi = dv   + (row << 9);
    float x0 = vi[t]       + gate * dvi[t];
    float x1 = vi[t + 256] + gate * dvi[t + 256];
    float s = x0 + x1;
    for (int off = 32; off; off >>= 1) s += __shfl_down(s, off);
    if ((t & 63) == 0) red[t >> 6] = s;
    __syncthreads();
    float mean = (red[0] + red[1] + red[2] + red[3]) * (1.f / 512.f);
    float d0 = x0 - mean, d1 = x1 - mean;
    float ss = d0 * d0 + d1 * d1;
    for (int off = 32; off; off >>= 1) ss += __shfl_down(ss, off);
    __syncthreads();
    if ((t & 63) == 0) red[t >> 6] = ss;
    __syncthreads();
    float var = (red[0] + red[1] + red[2] + red[3]) * (1.f / 512.f);
    float rstd = rsqrtf(var + 1e-5f);
    float* vo = v_out + (row << 9);
    vo[t]       = d0 * rstd * gamma[t]       + beta[t];
    vo[t + 256] = d1 * rstd * gamma[t + 256] + beta[t + 256];
}

// ---------------------------------------------------------------------------
// Plain softmax over rows, in place.
// ---------------------------------------------------------------------------
__launch_bounds__(256)
__global__ void softmax_rows_kernel(float* __restrict__ logits, int Nd)
{
    __shared__ float red[4];
    long row = blockIdx.x;
    int t = threadIdx.x;
    float* L = logits + row * (long)Nd;
    float lmax = -INFINITY;
    for (int i = t; i < Nd; i += 256) lmax = fmaxf(lmax, L[i]);
    for (int off = 32; off; off >>= 1) lmax = fmaxf(lmax, __shfl_down(lmax, off));
    if ((t & 63) == 0) red[t >> 6] = lmax;
    __syncthreads();
    float bmax = fmaxf(fmaxf(red[0], red[1]), fmaxf(red[2], red[3]));
    float lsum = 0.f;
    for (int i = t; i < Nd; i += 256) lsum += expf(L[i] - bmax);
    for (int off = 32; off; off >>= 1) lsum += __shfl_down(lsum, off);
    __syncthreads();
    if ((t & 63) == 0) red[t >> 6] = lsum;
    __syncthreads();
    float inv = 1.f / (red[0] + red[1] + red[2] + red[3]);
    for (int i = t; i < Nd; i += 256) L[i] = expf(L[i] - bmax) * inv;
}

// ---------------------------------------------------------------------------
extern "C" void kernel_launch(void* const* d_in, const int* in_sizes, int n_in,
                              void* d_out, int out_size, void* d_ws, size_t ws_size,
                              hipStream_t stream)
{
    const int Bn = 4, T = 1024, D = 512, R = 64;
    const int S0 = 1024, S1 = 256, S2 = 64;
    const long RT = (long)D * R;

    const float* tok_val    = (const float*)d_in[0];
    const float* tok_state  = (const float*)d_in[1];
    const float* mem_state0 = (const float*)d_in[2];
    const float* mem_val0   = (const float*)d_in[3];
    const float* mem_state1 = (const float*)d_in[4];
    const float* mem_val1   = (const float*)d_in[5];
    const float* mem_state2 = (const float*)d_in[6];
    const float* mem_val2   = (const float*)d_in[7];
    const float* write_route= (const float*)d_in[8];
    const float* prop_route = (const float*)d_in[9];
    const float* level_route= (const float*)d_in[10];
    const float* skip_route = (const float*)d_in[11];
    const float* skip_gates = (const float*)d_in[12];
    const float* ln_gamma   = (const float*)d_in[13];
    const float* ln_beta    = (const float*)d_in[14];
    const float* read_route = (const float*)d_in[15];
    const float* read_proj  = (const float*)d_in[16];
    const float* read_gates = (const float*)d_in[17];
    float* out = (float*)d_out;

    // workspace carve
    float* p = (float*)d_ws;
    float* v0 = p;  p += (long)Bn * S0 * D;
    float* s0 = p;  p += Bn * S0;
    float* v1 = p;  p += (long)Bn * S1 * D;
    float* s1 = p;  p += Bn * S1;
    float* v2 = p;  p += (long)Bn * S2 * D;
    float* s2 = p;  p += Bn * S2;
    float* qb = p;  p += (long)Bn * T * R;
    float* kb = p;  p += (long)Bn * S0 * R;
    float* lb = p;  p += (long)Bn * T * S0;
    float* cb = p;  p += (long)Bn * T * 16;
    int*   ib = (int*)p; p += (long)Bn * T * 16;
    float* dvb = p; p += (long)Bn * S0 * D;
    float* dsb = p; p += Bn * S0;
    float* rb = p;  p += (long)Bn * T * D;
    int* cntb  = (int*)p; p += Bn * S0;
    int* curb  = (int*)p; p += Bn * S0;
    int* offsb = (int*)p; p += Bn * S0 + 1;
    int* elistb= (int*)p; p += (long)Bn * T * 16;
    unsigned short* projT = (unsigned short*)p; p += (3 * (long)D * D) / 2 + 4;
    float* partb = p; p += 8L * Bn * (T + S0) * R;      // split-K partials
    unsigned short* mvT = (unsigned short*)dvb;          // reuse dvb in read phase

    auto proj = [&](const float* Aq, const float* Ak, const float* Wq, const float* Wk,
                    int Mq, int Mk, long sAq, long sAk, float* qout, float* kout) {
        proj_splitk_kernel<<<dim3((Mq + Mk) / 64, 8, Bn), 256, 0, stream>>>(
            Aq, Ak, Wq, Wk, partb, Mq, Mk, sAq, sAk, Bn);
        int total4 = Bn * (Mq + Mk) * 16;
        proj_reduce_kernel<<<(total4 + 255) / 256, 256, 0, stream>>>(
            partb, qout, kout, Mq, Mk, Bn);
    };

    auto trans = [&](const float* sv, const float* ss, const float* dval,
                     const float* W, int Ns, int Nd) {
        proj(sv, dval, W, W + RT, Ns, Nd, (long)Ns * D, (long)Nd * D, qb, kb);
        gemm_f32_kernel<true><<<dim3(Ns / 64, Nd / 64, Bn), 256, 0, stream>>>(
            qb, kb, lb, Ns, Nd, R, (long)Ns * R, (long)Nd * R, (long)Ns * Nd, 0.125f);
        int nsLog = 31 - __builtin_clz((unsigned)Ns);
        int nsShift = nsLog + 4;
        hipMemsetAsync(cntb, 0, (size_t)2 * Bn * S0 * sizeof(int), stream); // cnt+cursor
        int rowBlocks = Bn * Ns / 4;
        if (Nd == 1024)
            topk_coeff_kernel<16><<<rowBlocks, 256, 0, stream>>>(lb, ss, ib, cb, cntb, nsLog, Nd);
        else if (Nd == 256)
            topk_coeff_kernel<4><<<rowBlocks, 256, 0, stream>>>(lb, ss, ib, cb, cntb, nsLog, Nd);
        else
            topk_coeff_kernel<1><<<rowBlocks, 256, 0, stream>>>(lb, ss, ib, cb, cntb, nsLog, Nd);
        int E = Bn * Ns * 16;
        scan_kernel<<<1, 256, 0, stream>>>(cntb, offsb, Bn * Nd);
        fill_edges_kernel<<<(E + 255) / 256, 256, 0, stream>>>(ib, offsb, curb, elistb,
                                                               nsShift, Nd, E);
        gather_dv_kernel<<<Bn * Nd, 256, 0, stream>>>(sv, cb, elistb, offsb, dvb, dsb,
                                                      nsShift);
    };
    auto apply = [&](const float* sin, float* sout, const float* vin, float* vout,
                     int Nd, int lvl, const float* gptr, int gidx) {
        apply_state_kernel<<<Bn, 256, 0, stream>>>(sin, dsb, sout, Nd, gptr, gidx);
        apply_ln_kernel<<<Bn * Nd, 256, 0, stream>>>(vin, dvb, vout,
            ln_gamma + lvl * D, ln_beta + lvl * D, gptr, gidx);
    };

    // ---- level 0 ----
    trans(tok_val, tok_state, mem_val0, write_route, T, S0);
    apply(mem_state0, s0, mem_val0, v0, S0, 0, nullptr, 0);
    trans(v0, s0, v0, prop_route + 0 * 2 * RT, S0, S0);
    apply(s0, s0, v0, v0, S0, 0, nullptr, 0);

    // ---- level 1 ----
    trans(v0, s0, mem_val1, level_route + 0 * 2 * RT, S0, S1);
    apply(mem_state1, s1, mem_val1, v1, S1, 1, nullptr, 0);
    trans(tok_val, tok_state, v1, skip_route + 0 * 2 * RT, T, S1);
    apply(s1, s1, v1, v1, S1, 1, skip_gates, 0);
    trans(v1, s1, v1, prop_route + 1 * 2 * RT, S1, S1);
    apply(s1, s1, v1, v1, S1, 1, nullptr, 0);

    // ---- level 2 ----
    trans(v1, s1, mem_val2, level_route + 1 * 2 * RT, S1, S2);
    apply(mem_state2, s2, mem_val2, v2, S2, 2, nullptr, 0);
    trans(v0, s0, v2, skip_route + 1 * 2 * RT, S0, S2);
    apply(s2, s2, v2, v2, S2, 2, skip_gates, 1);
    trans(v2, s2, v2, prop_route + 2 * 2 * RT, S2, S2);
    apply(s2, s2, v2, v2, S2, 2, nullptr, 0);

    // ---- read phase ----
    hipMemcpyAsync(out, tok_val, (size_t)Bn * T * D * sizeof(float),
                   hipMemcpyDeviceToDevice, stream);
    transpose_bf16_kernel<<<dim3(D / 32, D / 32, 3), dim3(32, 8), 0, stream>>>(
        read_proj, projT, D, D, (long)D * D, (long)D * D);
    const float* mvs[3] = { v0, v1, v2 };
    const int nds[3] = { S0, S1, S2 };
    for (int l = 0; l < 3; ++l) {
        const float* mv = mvs[l];
        int Nd = nds[l];
        proj(tok_val, mv, read_route + (long)l * 2 * RT, read_route + (long)l * 2 * RT + RT,
             T, Nd, (long)T * D, (long)Nd * D, qb, kb);
        gemm_f32_kernel<true><<<dim3(T / 64, Nd / 64, Bn), 256, 0, stream>>>(
            qb, kb, lb, T, Nd, R, (long)T * R, (long)Nd * R, (long)T * Nd, 0.125f);
        softmax_rows_kernel<<<Bn * T, 256, 0, stream>>>(lb, Nd);
        transpose_bf16_kernel<<<dim3(D / 32, Nd / 32, Bn), dim3(32, 8), 0, stream>>>(
            mv, mvT, Nd, D, (long)Nd * D, (long)D * Nd);
        gemm_mfma_kernel<<<dim3(T / 64, D / 64, Bn), 256, 0, stream>>>(
            lb, mvT, rb, T, D, Nd, (long)T * Nd, (long)D * Nd, (long)T * D,
            1.f, nullptr, 0, 0.f);
        gemm_mfma_kernel<<<dim3(T / 64, D / 64, Bn), 256, 0, stream>>>(
            rb, projT + (long)l * D * D, out, T, D, D,
            (long)T * D, 0, (long)T * D, 1.f, read_gates, l, 1.f);
    }
}

// Round 8
// 930.384 us; speedup vs baseline: 3.9631x; 1.0235x over previous
//
#include <hip/hip_runtime.h>
#include <math.h>

typedef __attribute__((ext_vector_type(8))) short short8;
typedef __attribute__((ext_vector_type(4))) float floatx4;

static __device__ __forceinline__ short f2bf(float f) {
    union { float f; unsigned u; } c; c.f = f;
    unsigned r = c.u + 0x7FFF + ((c.u >> 16) & 1);   // RNE
    return (short)(r >> 16);
}

// ---------------------------------------------------------------------------
// fp32 GEMM: C[b] = alpha * A[b](M,K) x B[b](N,K)^T. 64x64 tile, 4x4 micro.
// fp32-exact path (logits feed exact top-k).
// ---------------------------------------------------------------------------
__launch_bounds__(256)
__global__ void gemm_f32_nt_kernel(const float* __restrict__ A, const float* __restrict__ B,
                                   float* __restrict__ C, int M, int N, int K,
                                   long sA, long sB, long sC, float alpha)
{
    __shared__ float As[32][68];   // [k][m]
    __shared__ float Bs[32][68];   // [k][n]
    const float* Ab = A + (long)blockIdx.z * sA;
    const float* Bb = B + (long)blockIdx.z * sB;
    float* Cb = C + (long)blockIdx.z * sC;
    int m0 = blockIdx.x * 64, n0 = blockIdx.y * 64;
    int t = threadIdx.x;
    int tx = t & 15, ty = t >> 4;
    float acc[4][4] = {};

    for (int k0 = 0; k0 < K; k0 += 32) {
        {
            int m = t >> 3;
            int kk = (t & 7) * 4;
#pragma unroll
            for (int h = 0; h < 2; ++h) {
                float4 v = *(const float4*)&Ab[(long)(m0 + m + 32 * h) * K + k0 + kk];
                As[kk + 0][m + 32 * h] = v.x; As[kk + 1][m + 32 * h] = v.y;
                As[kk + 2][m + 32 * h] = v.z; As[kk + 3][m + 32 * h] = v.w;
            }
        }
        {
            int n = t >> 3;
            int kk = (t & 7) * 4;
#pragma unroll
            for (int h = 0; h < 2; ++h) {
                float4 v = *(const float4*)&Bb[(long)(n0 + n + 32 * h) * K + k0 + kk];
                Bs[kk + 0][n + 32 * h] = v.x; Bs[kk + 1][n + 32 * h] = v.y;
                Bs[kk + 2][n + 32 * h] = v.z; Bs[kk + 3][n + 32 * h] = v.w;
            }
        }
        __syncthreads();
#pragma unroll 4
        for (int k = 0; k < 32; ++k) {
            float4 a = *(const float4*)&As[k][ty * 4];
            float4 b = *(const float4*)&Bs[k][tx * 4];
            float av[4] = { a.x, a.y, a.z, a.w };
            float bv[4] = { b.x, b.y, b.z, b.w };
#pragma unroll
            for (int i = 0; i < 4; ++i)
#pragma unroll
                for (int j = 0; j < 4; ++j) acc[i][j] += av[i] * bv[j];
        }
        __syncthreads();
    }
#pragma unroll
    for (int i = 0; i < 4; ++i) {
        float4 r;
        r.x = alpha * acc[i][0]; r.y = alpha * acc[i][1];
        r.z = alpha * acc[i][2]; r.w = alpha * acc[i][3];
        *(float4*)&Cb[(long)(m0 + ty * 4 + i) * N + n0 + tx * 4] = r;
    }
}

// ---------------------------------------------------------------------------
// Split-K q/k projection, fused (q and k in one launch), partials + reduce.
// ---------------------------------------------------------------------------
__launch_bounds__(256)
__global__ void proj_splitk_kernel(const float* __restrict__ Aq, const float* __restrict__ Ak,
                                   const float* __restrict__ Wq, const float* __restrict__ Wk,
                                   float* __restrict__ part,
                                   int Mq, int Mk, long sAq, long sAk, int Bn)
{
    __shared__ float As[32][68];
    __shared__ float Bs[32][68];
    int mqT = Mq >> 6;
    int xt = blockIdx.x, s = blockIdx.y, b = blockIdx.z;
    const float* A; const float* W; int row0, orow;
    if (xt < mqT) { A = Aq + (long)b * sAq; W = Wq; row0 = xt * 64; orow = row0; }
    else { A = Ak + (long)b * sAk; W = Wk; row0 = (xt - mqT) * 64; orow = Mq + row0; }
    int t = threadIdx.x, tx = t & 15, ty = t >> 4;
    float acc[4][4] = {};
    int kbase = s * 64;

    for (int k0 = kbase; k0 < kbase + 64; k0 += 32) {
        {
            int m = t >> 3;
            int kk = (t & 7) * 4;
#pragma unroll
            for (int h = 0; h < 2; ++h) {
                float4 v = *(const float4*)&A[(long)(row0 + m + 32 * h) * 512 + k0 + kk];
                As[kk + 0][m + 32 * h] = v.x; As[kk + 1][m + 32 * h] = v.y;
                As[kk + 2][m + 32 * h] = v.z; As[kk + 3][m + 32 * h] = v.w;
            }
        }
        {
            int kk = t >> 3;
            int nn = (t & 7) * 8;
            float4 v0 = *(const float4*)&W[(long)(k0 + kk) * 64 + nn];
            float4 v1 = *(const float4*)&W[(long)(k0 + kk) * 64 + nn + 4];
            *(float4*)&Bs[kk][nn] = v0;
            *(float4*)&Bs[kk][nn + 4] = v1;
        }
        __syncthreads();
#pragma unroll 4
        for (int k = 0; k < 32; ++k) {
            float4 a = *(const float4*)&As[k][ty * 4];
            float4 b2 = *(const float4*)&Bs[k][tx * 4];
            float av[4] = { a.x, a.y, a.z, a.w };
            float bv[4] = { b2.x, b2.y, b2.z, b2.w };
#pragma unroll
            for (int i = 0; i < 4; ++i)
#pragma unroll
                for (int j = 0; j < 4; ++j) acc[i][j] += av[i] * bv[j];
        }
        __syncthreads();
    }
    long base = ((long)(s * Bn + b) * (Mq + Mk) + orow) * 64;
#pragma unroll
    for (int i = 0; i < 4; ++i)
        *(float4*)&part[base + (long)(ty * 4 + i) * 64 + tx * 4] =
            make_float4(acc[i][0], acc[i][1], acc[i][2], acc[i][3]);
}

__launch_bounds__(256)
__global__ void proj_reduce_kernel(const float* __restrict__ part,
                                   float* __restrict__ qout, float* __restrict__ kout,
                                   int Mq, int Mk, int Bn)
{
    int idx = blockIdx.x * 256 + threadIdx.x;
    int size4b = (Mq + Mk) * 16;
    int total4 = Bn * size4b;
    if (idx >= total4) return;
    const float4* p4 = (const float4*)part;
    long stride4 = (long)total4;
    float4 s = p4[idx];
#pragma unroll
    for (int ss = 1; ss < 8; ++ss) {
        float4 v = p4[ss * stride4 + idx];
        s.x += v.x; s.y += v.y; s.z += v.z; s.w += v.w;
    }
    int b = idx / size4b;
    int rem = idx - b * size4b;
    int r = rem >> 4;
    int c4 = rem & 15;
    if (r < Mq) ((float4*)qout)[((long)b * Mq + r) * 16 + c4] = s;
    else        ((float4*)kout)[((long)b * Mk + (r - Mq)) * 16 + c4] = s;
}

// ---------------------------------------------------------------------------
// bf16 MFMA GEMM: C[b](M,N) = alpha' * A[b](M,K,fp32) x Bt[b](N,K,bf16) (+ C | + initC)
// ---------------------------------------------------------------------------
__launch_bounds__(256)
__global__ void gemm_mfma_kernel(const float* __restrict__ A, const unsigned short* __restrict__ Bt,
                                 float* __restrict__ C, int M, int N, int K,
                                 long sA, long sBt, long sC,
                                 float alpha, const float* __restrict__ gate, int gateIdx,
                                 float beta, const float* __restrict__ initC)
{
    __shared__ short As[2048];
    __shared__ short Bs[2048];
    const float* Ab = A + (long)blockIdx.z * sA;
    const unsigned short* Bb = Bt + (long)blockIdx.z * sBt;
    float* Cb = C + (long)blockIdx.z * sC;
    const float* Ib = initC ? initC + (long)blockIdx.z * sC : nullptr;
    int m0 = blockIdx.x * 64, n0 = blockIdx.y * 64;
    int t = threadIdx.x, wave = t >> 6, lane = t & 63;
    int sr = wave * 16 + (lane & 15);
    int sk = (lane >> 4) * 8;
    floatx4 acc[4] = {};

    for (int k0 = 0; k0 < K; k0 += 32) {
        const float* ap = &Ab[(long)(m0 + sr) * K + k0 + sk];
        float4 f0 = *(const float4*)ap;
        float4 f1 = *(const float4*)(ap + 4);
        short8 av;
        av[0] = f2bf(f0.x); av[1] = f2bf(f0.y); av[2] = f2bf(f0.z); av[3] = f2bf(f0.w);
        av[4] = f2bf(f1.x); av[5] = f2bf(f1.y); av[6] = f2bf(f1.z); av[7] = f2bf(f1.w);
        short8 bv = *(const short8*)&Bb[(long)(n0 + sr) * K + k0 + sk];
        ((short8*)As)[t] = av;
        ((short8*)Bs)[t] = bv;
        __syncthreads();
        short8 bf = ((short8*)Bs)[wave * 64 + lane];
#pragma unroll
        for (int mt = 0; mt < 4; ++mt) {
            short8 af = ((short8*)As)[mt * 64 + lane];
            acc[mt] = __builtin_amdgcn_mfma_f32_16x16x32_bf16(af, bf, acc[mt], 0, 0, 0);
        }
        __syncthreads();
    }
    float a = alpha;
    if (gate) a *= 1.f / (1.f + expf(-gate[gateIdx]));
    int col = n0 + wave * 16 + (lane & 15);
#pragma unroll
    for (int mt = 0; mt < 4; ++mt) {
#pragma unroll
        for (int r = 0; r < 4; ++r) {
            int row = m0 + mt * 16 + (lane >> 4) * 4 + r;
            long off = (long)row * N + col;
            float v = a * acc[mt][r];
            if (Ib) v += Ib[off];
            else if (beta != 0.f) v += Cb[off];
            Cb[off] = v;
        }
    }
}

// ---------------------------------------------------------------------------
// Transpose + bf16 convert: out[c][r] = bf16(in[r][c]).
// ---------------------------------------------------------------------------
__global__ void transpose_bf16_kernel(const float* __restrict__ in, unsigned short* __restrict__ out,
                                      int Rr, int Cc, long sIn, long sOut)
{
    __shared__ float tile[32][33];
    const float* I = in + (long)blockIdx.z * sIn;
    unsigned short* O = out + (long)blockIdx.z * sOut;
    int c0 = blockIdx.x * 32, r0 = blockIdx.y * 32;
    int tx = threadIdx.x, ty = threadIdx.y;
#pragma unroll
    for (int i = 0; i < 32; i += 8)
        tile[ty + i][tx] = I[(long)(r0 + ty + i) * Cc + c0 + tx];
    __syncthreads();
#pragma unroll
    for (int i = 0; i < 32; i += 8)
        O[(long)(c0 + ty + i) * Rr + r0 + tx] = (unsigned short)f2bf(tile[tx][ty + i]);
}

// ---------------------------------------------------------------------------
// Exact top-16 per row + fused CSR count. 4 rows/block, contiguous lane slices.
// ---------------------------------------------------------------------------
template<int CNT>
__launch_bounds__(256)
__global__ void topk_coeff_kernel(const float* __restrict__ logits,
                                  const float* __restrict__ state,
                                  int* __restrict__ idx_out, float* __restrict__ c_out,
                                  int* __restrict__ cnt, int nsLog, int Nd)
{
    int wave = threadIdx.x >> 6, lane = threadIdx.x & 63;
    long row = (long)blockIdx.x * 4 + wave;
    const float* L = logits + row * Nd;
    float vreg[CNT];
    if (CNT >= 4) {
#pragma unroll
        for (int q = 0; q < CNT / 4; ++q) {
            float4 v = *(const float4*)&L[lane * CNT + q * 4];
            vreg[q * 4 + 0] = v.x; vreg[q * 4 + 1] = v.y;
            vreg[q * 4 + 2] = v.z; vreg[q * 4 + 3] = v.w;
        }
    } else {
#pragma unroll
        for (int tt = 0; tt < CNT; ++tt) vreg[tt] = L[lane * CNT + tt];
    }

    float m = 0.f, sum = 0.f;
    float myv = 0.f; int myi = 0;
#pragma unroll
    for (int it = 0; it < 16; ++it) {
        float best = -INFINITY; int bidx = 0x7fffffff;
#pragma unroll
        for (int tt = 0; tt < CNT; ++tt) {
            if (vreg[tt] > best) { best = vreg[tt]; bidx = lane * CNT + tt; }
        }
#pragma unroll
        for (int off = 32; off; off >>= 1) {
            float ov = __shfl_down(best, off);
            int   oi = __shfl_down(bidx, off);
            if (ov > best || (ov == best && oi < bidx)) { best = ov; bidx = oi; }
        }
        best = __shfl(best, 0);
        bidx = __shfl(bidx, 0);
        if (it == lane) { myv = best; myi = bidx; }
        float ab = fabsf(best);
        float nm = fmaxf(m, ab);
        sum = sum * expf(m - nm) + expf(ab - nm);
        m = nm;
#pragma unroll
        for (int tt = 0; tt < CNT; ++tt)
            if (lane * CNT + tt == bidx) vreg[tt] = -INFINITY;
    }
    if (lane < 16) {
        float st = state[row];
        float sp = fmaxf(st, 0.f) + log1pf(expf(-fabsf(st)));
        float sgn = (myv > 0.f) ? 1.f : ((myv < 0.f) ? -1.f : 0.f);
        float w = expf(fabsf(myv) - m) / sum;
        c_out[row * 16 + lane] = sgn * w * sp;
        idx_out[row * 16 + lane] = myi;
        int b = (int)(row >> nsLog);
        atomicAdd(&cnt[b * Nd + myi], 1);
    }
}

// Single-block exclusive scan over N entries (N mult of 256, <=4096).
// Self-zeroes cnt after consuming it (next transition's Nd is <= current).
__launch_bounds__(256)
__global__ void scan_kernel(int* __restrict__ cnt, int* __restrict__ offs, int N)
{
    __shared__ int sums[256];
    int t = threadIdx.x;
    int chunk = N >> 8;           // <= 16
    int base = t * chunk;
    int lc[16];
    int s = 0;
    for (int i = 0; i < chunk; ++i) { lc[i] = cnt[base + i]; s += lc[i]; }
    sums[t] = s;
    __syncthreads();
    for (int off = 1; off < 256; off <<= 1) {
        int v = (t >= off) ? sums[t - off] : 0;
        __syncthreads();
        sums[t] += v;
        __syncthreads();
    }
    int run = sums[t] - s;
    for (int i = 0; i < chunk; ++i) {
        offs[base + i] = run;
        run += lc[i];
        cnt[base + i] = 0;        // ready for next transition
    }
    if (t == 255) offs[N] = run;
}

__launch_bounds__(256)
__global__ void fill_edges_kernel(const int* __restrict__ idx, const int* __restrict__ offs,
                                  int* __restrict__ cursor, int* __restrict__ elist,
                                  int nsShift, int Nd, int E)
{
    int e = blockIdx.x * 256 + threadIdx.x;
    if (e >= E) return;
    int b = e >> nsShift;
    int d = b * Nd + idx[e];
    int pos = offs[d] + atomicAdd(&cursor[d], 1);
    elist[pos] = e;
}

// ---------------------------------------------------------------------------
// Gather dv[row] = sum_e c[e]*src[src_row(e)]; ds[row] = sum_e c[e].
// Also zeroes cursor[row] for the next transition.
// ---------------------------------------------------------------------------
#define ECHUNK 512
__launch_bounds__(256)
__global__ void gather_dv_kernel(const float* __restrict__ src_val, const float* __restrict__ c,
                                 const int* __restrict__ elist, const int* __restrict__ offs,
                                 float* __restrict__ dv, float* __restrict__ ds,
                                 int* __restrict__ cursor, int nsShift)
{
    __shared__ float sc[ECHUNK];
    __shared__ int   srow[ECHUNK];
    __shared__ float part[4][512];
    __shared__ float pcs[4];
    long row = blockIdx.x;
    int t = threadIdx.x, w = t >> 6, lane = t & 63;
    int e0 = offs[row], e1 = offs[row + 1];
    int mask = (1 << nsShift) - 1;
    int cb = lane * 8;
    float a[8] = {};
    float cs = 0.f;

    for (int cstart = e0; cstart < e1; cstart += ECHUNK) {
        int cnt = min(e1 - cstart, ECHUNK);
        for (int i = t; i < cnt; i += 256) {
            int e = elist[cstart + i];
            sc[i] = c[e];
            int b = e >> nsShift;
            int s = (e & mask) >> 4;
            srow[i] = (b << (nsShift - 4)) + s;
        }
        __syncthreads();
        int j = w;
        for (; j + 12 < cnt; j += 16) {
            float c0 = sc[j], c1 = sc[j + 4], c2 = sc[j + 8], c3 = sc[j + 12];
            const float* p0 = src_val + ((long)srow[j]      << 9) + cb;
            const float* p1 = src_val + ((long)srow[j + 4]  << 9) + cb;
            const float* p2 = src_val + ((long)srow[j + 8]  << 9) + cb;
            const float* p3 = src_val + ((long)srow[j + 12] << 9) + cb;
            float4 x00 = *(const float4*)p0,       x01 = *(const float4*)(p0 + 4);
            float4 x10 = *(const float4*)p1,       x11 = *(const float4*)(p1 + 4);
            float4 x20 = *(const float4*)p2,       x21 = *(const float4*)(p2 + 4);
            float4 x30 = *(const float4*)p3,       x31 = *(const float4*)(p3 + 4);
            a[0] += c0 * x00.x + c1 * x10.x + c2 * x20.x + c3 * x30.x;
            a[1] += c0 * x00.y + c1 * x10.y + c2 * x20.y + c3 * x30.y;
            a[2] += c0 * x00.z + c1 * x10.z + c2 * x20.z + c3 * x30.z;
            a[3] += c0 * x00.w + c1 * x10.w + c2 * x20.w + c3 * x30.w;
            a[4] += c0 * x01.x + c1 * x11.x + c2 * x21.x + c3 * x31.x;
            a[5] += c0 * x01.y + c1 * x11.y + c2 * x21.y + c3 * x31.y;
            a[6] += c0 * x01.z + c1 * x11.z + c2 * x21.z + c3 * x31.z;
            a[7] += c0 * x01.w + c1 * x11.w + c2 * x21.w + c3 * x31.w;
            cs += c0 + c1 + c2 + c3;
        }
        for (; j < cnt; j += 4) {
            float cv = sc[j];
            const float* p = src_val + ((long)srow[j] << 9) + cb;
            float4 x0 = *(const float4*)p, x1 = *(const float4*)(p + 4);
            a[0] += cv * x0.x; a[1] += cv * x0.y; a[2] += cv * x0.z; a[3] += cv * x0.w;
            a[4] += cv * x1.x; a[5] += cv * x1.y; a[6] += cv * x1.z; a[7] += cv * x1.w;
            cs += cv;
        }
        __syncthreads();
    }
#pragma unroll
    for (int i = 0; i < 8; ++i) part[w][cb + i] = a[i];
    if (lane == 0) pcs[w] = cs;
    __syncthreads();
    float r0 = part[0][t] + part[1][t] + part[2][t] + part[3][t];
    float r1 = part[0][t + 256] + part[1][t + 256] + part[2][t + 256] + part[3][t + 256];
    dv[(row << 9) + t]       = r0;
    dv[(row << 9) + t + 256] = r1;
    if (t == 0) { ds[row] = pcs[0] + pcs[1] + pcs[2] + pcs[3]; cursor[row] = 0; }
}

// ---------------------------------------------------------------------------
// Fused apply: grid = Bn*Nd (LayerNorm rows) + Bn (state softmax blocks).
// ---------------------------------------------------------------------------
__launch_bounds__(256)
__global__ void apply_fused_kernel(const float* __restrict__ s_in, const float* __restrict__ ds,
                                   float* __restrict__ s_out,
                                   const float* __restrict__ v_in, const float* __restrict__ dv,
                                   float* __restrict__ v_out,
                                   const float* __restrict__ gamma, const float* __restrict__ beta,
                                   int Nd, int Bn,
                                   const float* __restrict__ gatePtr, int gateIdx)
{
    __shared__ float sh[1024];
    __shared__ float red[4];
    int t = threadIdx.x;
    float gate = 1.f;
    if (gatePtr) gate = 1.f / (1.f + expf(-gatePtr[gateIdx]));
    int nLN = gridDim.x - Bn;

    if ((int)blockIdx.x < nLN) {
        // ---- LayerNorm path ----
        long row = blockIdx.x;
        const float* vi  = v_in + (row << 9);
        const float* dvi = dv   + (row << 9);
        float x0 = vi[t]       + gate * dvi[t];
        float x1 = vi[t + 256] + gate * dvi[t + 256];
        float s = x0 + x1;
        for (int off = 32; off; off >>= 1) s += __shfl_down(s, off);
        if ((t & 63) == 0) red[t >> 6] = s;
        __syncthreads();
        float mean = (red[0] + red[1] + red[2] + red[3]) * (1.f / 512.f);
        float d0 = x0 - mean, d1 = x1 - mean;
        float ss = d0 * d0 + d1 * d1;
        for (int off = 32; off; off >>= 1) ss += __shfl_down(ss, off);
        __syncthreads();
        if ((t & 63) == 0) red[t >> 6] = ss;
        __syncthreads();
        float var = (red[0] + red[1] + red[2] + red[3]) * (1.f / 512.f);
        float rstd = rsqrtf(var + 1e-5f);
        float* vo = v_out + (row << 9);
        vo[t]       = d0 * rstd * gamma[t]       + beta[t];
        vo[t + 256] = d1 * rstd * gamma[t + 256] + beta[t + 256];
    } else {
        // ---- state signed-softmax path ----
        int b = blockIdx.x - nLN;
        float lmax = 0.f;
        for (int i = t; i < Nd; i += 256) {
            float x = s_in[b * Nd + i] + gate * ds[b * Nd + i];
            sh[i] = x;
            lmax = fmaxf(lmax, fabsf(x));
        }
        for (int off = 32; off; off >>= 1) lmax = fmaxf(lmax, __shfl_down(lmax, off));
        if ((t & 63) == 0) red[t >> 6] = lmax;
        __syncthreads();
        float bmax = fmaxf(fmaxf(red[0], red[1]), fmaxf(red[2], red[3]));
        float lsum = 0.f;
        for (int i = t; i < Nd; i += 256) lsum += expf(fabsf(sh[i]) - bmax);
        for (int off = 32; off; off >>= 1) lsum += __shfl_down(lsum, off);
        __syncthreads();
        if ((t & 63) == 0) red[t >> 6] = lsum;
        __syncthreads();
        float inv = 1.f / (red[0] + red[1] + red[2] + red[3]);
        for (int i = t; i < Nd; i += 256) {
            float x = sh[i];
            float sgn = (x > 0.f) ? 1.f : ((x < 0.f) ? -1.f : 0.f);
            s_out[b * Nd + i] = sgn * expf(fabsf(x) - bmax) * inv;
        }
    }
}

// ---------------------------------------------------------------------------
// Plain softmax over rows, in place.
// ---------------------------------------------------------------------------
__launch_bounds__(256)
__global__ void softmax_rows_kernel(float* __restrict__ logits, int Nd)
{
    __shared__ float red[4];
    long row = blockIdx.x;
    int t = threadIdx.x;
    float* L = logits + row * (long)Nd;
    float lmax = -INFINITY;
    for (int i = t; i < Nd; i += 256) lmax = fmaxf(lmax, L[i]);
    for (int off = 32; off; off >>= 1) lmax = fmaxf(lmax, __shfl_down(lmax, off));
    if ((t & 63) == 0) red[t >> 6] = lmax;
    __syncthreads();
    float bmax = fmaxf(fmaxf(red[0], red[1]), fmaxf(red[2], red[3]));
    float lsum = 0.f;
    for (int i = t; i < Nd; i += 256) lsum += expf(L[i] - bmax);
    for (int off = 32; off; off >>= 1) lsum += __shfl_down(lsum, off);
    __syncthreads();
    if ((t & 63) == 0) red[t >> 6] = lsum;
    __syncthreads();
    float inv = 1.f / (red[0] + red[1] + red[2] + red[3]);
    for (int i = t; i < Nd; i += 256) L[i] = expf(L[i] - bmax) * inv;
}

// ---------------------------------------------------------------------------
extern "C" void kernel_launch(void* const* d_in, const int* in_sizes, int n_in,
                              void* d_out, int out_size, void* d_ws, size_t ws_size,
                              hipStream_t stream)
{
    const int Bn = 4, T = 1024, D = 512, R = 64;
    const int S0 = 1024, S1 = 256, S2 = 64;
    const long RT = (long)D * R;

    const float* tok_val    = (const float*)d_in[0];
    const float* tok_state  = (const float*)d_in[1];
    const float* mem_state0 = (const float*)d_in[2];
    const float* mem_val0   = (const float*)d_in[3];
    const float* mem_state1 = (const float*)d_in[4];
    const float* mem_val1   = (const float*)d_in[5];
    const float* mem_state2 = (const float*)d_in[6];
    const float* mem_val2   = (const float*)d_in[7];
    const float* write_route= (const float*)d_in[8];
    const float* prop_route = (const float*)d_in[9];
    const float* level_route= (const float*)d_in[10];
    const float* skip_route = (const float*)d_in[11];
    const float* skip_gates = (const float*)d_in[12];
    const float* ln_gamma   = (const float*)d_in[13];
    const float* ln_beta    = (const float*)d_in[14];
    const float* read_route = (const float*)d_in[15];
    const float* read_proj  = (const float*)d_in[16];
    const float* read_gates = (const float*)d_in[17];
    float* out = (float*)d_out;

    // workspace carve
    float* p = (float*)d_ws;
    float* v0 = p;  p += (long)Bn * S0 * D;
    float* s0 = p;  p += Bn * S0;
    float* v1 = p;  p += (long)Bn * S1 * D;
    float* s1 = p;  p += Bn * S1;
    float* v2 = p;  p += (long)Bn * S2 * D;
    float* s2 = p;  p += Bn * S2;
    float* qb = p;  p += (long)Bn * T * R;
    float* kb = p;  p += (long)Bn * S0 * R;
    float* lb = p;  p += (long)Bn * T * S0;
    float* cb = p;  p += (long)Bn * T * 16;
    int*   ib = (int*)p; p += (long)Bn * T * 16;
    float* dvb = p; p += (long)Bn * S0 * D;
    float* dsb = p; p += Bn * S0;
    float* rb = p;  p += (long)Bn * T * D;
    int* cntb  = (int*)p; p += Bn * S0;
    int* curb  = (int*)p; p += Bn * S0;
    int* offsb = (int*)p; p += Bn * S0 + 1;
    int* elistb= (int*)p; p += (long)Bn * T * 16;
    unsigned short* projT = (unsigned short*)p; p += (3 * (long)D * D) / 2 + 4;
    float* partb = p; p += 8L * Bn * (T + S0) * R;      // split-K partials
    unsigned short* mvT = (unsigned short*)dvb;          // reuse dvb in read phase

    auto proj = [&](const float* Aq, const float* Ak, const float* Wq, const float* Wk,
                    int Mq, int Mk, long sAq, long sAk, float* qout, float* kout) {
        proj_splitk_kernel<<<dim3((Mq + Mk) / 64, 8, Bn), 256, 0, stream>>>(
            Aq, Ak, Wq, Wk, partb, Mq, Mk, sAq, sAk, Bn);
        int total4 = Bn * (Mq + Mk) * 16;
        proj_reduce_kernel<<<(total4 + 255) / 256, 256, 0, stream>>>(
            partb, qout, kout, Mq, Mk, Bn);
    };

    // one-time zero of cnt + cursor (workspace is re-poisoned before every call)
    hipMemsetAsync(cntb, 0, (size_t)2 * Bn * S0 * sizeof(int), stream);

    auto trans = [&](const float* sv, const float* ss, const float* dval,
                     const float* W, int Ns, int Nd) {
        proj(sv, dval, W, W + RT, Ns, Nd, (long)Ns * D, (long)Nd * D, qb, kb);
        gemm_f32_nt_kernel<<<dim3(Ns / 64, Nd / 64, Bn), 256, 0, stream>>>(
            qb, kb, lb, Ns, Nd, R, (long)Ns * R, (long)Nd * R, (long)Ns * Nd, 0.125f);
        int nsLog = 31 - __builtin_clz((unsigned)Ns);
        int nsShift = nsLog + 4;
        int rowBlocks = Bn * Ns / 4;
        if (Nd == 1024)
            topk_coeff_kernel<16><<<rowBlocks, 256, 0, stream>>>(lb, ss, ib, cb, cntb, nsLog, Nd);
        else if (Nd == 256)
            topk_coeff_kernel<4><<<rowBlocks, 256, 0, stream>>>(lb, ss, ib, cb, cntb, nsLog, Nd);
        else
            topk_coeff_kernel<1><<<rowBlocks, 256, 0, stream>>>(lb, ss, ib, cb, cntb, nsLog, Nd);
        int E = Bn * Ns * 16;
        scan_kernel<<<1, 256, 0, stream>>>(cntb, offsb, Bn * Nd);
        fill_edges_kernel<<<(E + 255) / 256, 256, 0, stream>>>(ib, offsb, curb, elistb,
                                                               nsShift, Nd, E);
        gather_dv_kernel<<<Bn * Nd, 256, 0, stream>>>(sv, cb, elistb, offsb, dvb, dsb,
                                                      curb, nsShift);
    };
    auto apply = [&](const float* sin, float* sout, const float* vin, float* vout,
                     int Nd, int lvl, const float* gptr, int gidx) {
        apply_fused_kernel<<<Bn * Nd + Bn, 256, 0, stream>>>(
            sin, dsb, sout, vin, dvb, vout,
            ln_gamma + lvl * D, ln_beta + lvl * D, Nd, Bn, gptr, gidx);
    };

    // ---- level 0 ----
    trans(tok_val, tok_state, mem_val0, write_route, T, S0);
    apply(mem_state0, s0, mem_val0, v0, S0, 0, nullptr, 0);
    trans(v0, s0, v0, prop_route + 0 * 2 * RT, S0, S0);
    apply(s0, s0, v0, v0, S0, 0, nullptr, 0);

    // ---- level 1 ----
    trans(v0, s0, mem_val1, level_route + 0 * 2 * RT, S0, S1);
    apply(mem_state1, s1, mem_val1, v1, S1, 1, nullptr, 0);
    trans(tok_val, tok_state, v1, skip_route + 0 * 2 * RT, T, S1);
    apply(s1, s1, v1, v1, S1, 1, skip_gates, 0);
    trans(v1, s1, v1, prop_route + 1 * 2 * RT, S1, S1);
    apply(s1, s1, v1, v1, S1, 1, nullptr, 0);

    // ---- level 2 ----
    trans(v1, s1, mem_val2, level_route + 1 * 2 * RT, S1, S2);
    apply(mem_state2, s2, mem_val2, v2, S2, 2, nullptr, 0);
    trans(v0, s0, v2, skip_route + 1 * 2 * RT, S0, S2);
    apply(s2, s2, v2, v2, S2, 2, skip_gates, 1);
    trans(v2, s2, v2, prop_route + 2 * 2 * RT, S2, S2);
    apply(s2, s2, v2, v2, S2, 2, nullptr, 0);

    // ---- read phase ----
    transpose_bf16_kernel<<<dim3(D / 32, D / 32, 3), dim3(32, 8), 0, stream>>>(
        read_proj, projT, D, D, (long)D * D, (long)D * D);
    const float* mvs[3] = { v0, v1, v2 };
    const int nds[3] = { S0, S1, S2 };
    for (int l = 0; l < 3; ++l) {
        const float* mv = mvs[l];
        int Nd = nds[l];
        proj(tok_val, mv, read_route + (long)l * 2 * RT, read_route + (long)l * 2 * RT + RT,
             T, Nd, (long)T * D, (long)Nd * D, qb, kb);
        gemm_f32_nt_kernel<<<dim3(T / 64, Nd / 64, Bn), 256, 0, stream>>>(
            qb, kb, lb, T, Nd, R, (long)T * R, (long)Nd * R, (long)T * Nd, 0.125f);
        softmax_rows_kernel<<<Bn * T, 256, 0, stream>>>(lb, Nd);
        transpose_bf16_kernel<<<dim3(D / 32, Nd / 32, Bn), dim3(32, 8), 0, stream>>>(
            mv, mvT, Nd, D, (long)Nd * D, (long)D * Nd);
        gemm_mfma_kernel<<<dim3(T / 64, D / 64, Bn), 256, 0, stream>>>(
            lb, mvT, rb, T, D, Nd, (long)T * Nd, (long)D * Nd, (long)T * D,
            1.f, nullptr, 0, 0.f, nullptr);
        // out = (l==0 ? tok_val : out) + sigmoid(gate_l) * r x proj_l
        gemm_mfma_kernel<<<dim3(T / 64, D / 64, Bn), 256, 0, stream>>>(
            rb, projT + (long)l * D * D, out, T, D, D,
            (long)T * D, 0, (long)T * D, 1.f, read_gates, l,
            1.f, (l == 0) ? tok_val : nullptr);
    }
}